// Round 8
// baseline (537.386 us; speedup 1.0000x reference)
//
#include <hip/hip_runtime.h>
#include <cstdint>

typedef __attribute__((ext_vector_type(8))) short bf16x8;
typedef __attribute__((ext_vector_type(4))) short bf16x4;
typedef __attribute__((ext_vector_type(4))) float f32x4;

#define S_LEN 4096
#define CDIM  640
#define NPROJ 5760

// K=16 bf16 MFMA (v_mfma_f32_16x16x16_bf16, gfx950-valid per ISA §10).
__device__ __forceinline__ f32x4 mfma16(bf16x4 a, bf16x4 b, f32x4 c){
#if defined(__HIP_DEVICE_COMPILE__) && __HIP_DEVICE_COMPILE__
  return __builtin_amdgcn_mfma_f32_16x16x16bf16_1k(a, b, c, 0, 0, 0);
#else
  (void)a; (void)b;
  return c;
#endif
}

// async global->LDS, 16B per lane; LDS dest must be wave-uniform base + lane*16
__device__ __forceinline__ void gload_lds(const unsigned short* g, unsigned short* l){
#if defined(__HIP_DEVICE_COMPILE__) && __HIP_DEVICE_COMPILE__
  __builtin_amdgcn_global_load_lds((const __attribute__((address_space(1))) unsigned int*)g,
                                   (__attribute__((address_space(3))) unsigned int*)l, 16, 0, 0);
#else
  (void)g; (void)l;
#endif
}

__device__ __forceinline__ unsigned short f2bf(float f){
  union { float f; uint32_t u; } v; v.f = f;
  uint32_t u = v.u;
  return (unsigned short)((u + 0x7fffu + ((u >> 16) & 1u)) >> 16);
}
__device__ __forceinline__ float b2f(unsigned short h){
  union { uint32_t u; float f; } v; v.u = ((uint32_t)h) << 16;
  return v.f;
}

// ---------------- labels: nearest-resize 512x512 -> 64x64, pack m | (im==0)<<8
__global__ void k_labels(const int* __restrict__ mask, const int* __restrict__ inp,
                         int* __restrict__ labels){
  int s = blockIdx.x * 256 + threadIdx.x;
  if (s >= S_LEN) return;
  int y = s >> 6, x = s & 63;
  int off = (y * 8) * 512 + x * 8;
  int m = mask[off] & 0xff;
  int o = (inp[off] == 0) ? 0x100 : 0;
  labels[s] = m | o;
}

// ---------------- bucket sort by label value (4 buckets)
__global__ void k_hist(const int* __restrict__ labels, int* __restrict__ boff, int* __restrict__ cnt){
  __shared__ int h[4];
  if (threadIdx.x < 4) h[threadIdx.x] = 0;
  __syncthreads();
  for (int s = threadIdx.x; s < S_LEN; s += 256) atomicAdd(&h[labels[s] & 3], 1);
  __syncthreads();
  if (threadIdx.x == 0){
    int a = 0;
    for (int c = 0; c < 4; c++){ boff[c] = a; a += h[c]; }
    boff[4] = a;
  }
  if (threadIdx.x < 4) cnt[threadIdx.x] = 0;
}

__global__ void k_perm(const int* __restrict__ labels, const int* __restrict__ boff,
                       int* __restrict__ cnt, int* __restrict__ perm,
                       int* __restrict__ inv, int* __restrict__ labP){
  int s = blockIdx.x * 256 + threadIdx.x;
  if (s >= S_LEN) return;
  int lab = labels[s];
  int c = lab & 3;
  int pos = boff[c] + atomicAdd(&cnt[c], 1);
  perm[pos] = s; inv[s] = pos; labP[pos] = lab;
}

// per 128-tile key ranges (shared by attn80 and entity); zero rowsum
__global__ void k_tiles(const int* __restrict__ labP, const int* __restrict__ boff,
                        int4* __restrict__ qtinfo, float* __restrict__ rowsum){
  int t = threadIdx.x;
  __shared__ int nkt[32];
  if (t < 32){
    int c0 = labP[t * 128] & 3, c1 = labP[t * 128 + 127] & 3;
    int lo = boff[c0] & ~127, hi = (boff[c1 + 1] + 127) & ~127;
    qtinfo[t].x = lo; qtinfo[t].y = hi; qtinfo[t].w = 0;
    nkt[t] = (hi - lo) >> 7;
  }
  __syncthreads();
  if (t == 0){
    int a = 0;
    for (int i = 0; i < 32; i++){ qtinfo[i].z = a; a += nkt[i]; }
  }
  for (int s = t; s < S_LEN; s += 256) rowsum[s] = 0.f;
}

// ---------------- f32 -> bf16 converts
__global__ void k_cvt_hs(const float* __restrict__ src, unsigned short* __restrict__ dst, int n){
  int idx = (blockIdx.x * 256 + threadIdx.x) * 4;
  if (idx >= n) return;
  float4 v = *(const float4*)(src + idx);
  ushort4 o;
  o.x = f2bf(v.x); o.y = f2bf(v.y); o.z = f2bf(v.z); o.w = f2bf(v.w);
  *(ushort4*)(dst + idx) = o;
}

struct WPtrs { const float* w[10]; };

__global__ void k_cvt_w(WPtrs p, unsigned short* __restrict__ dst){
  int e = (blockIdx.x * 256 + threadIdx.x) * 4;
  if (e >= 10 * 409600) return;
  int a = e / 409600, r = e % 409600;
  float sc = (a == 0 || a == 6) ? 0.11180339887498948f   // 1/sqrt(80)
           : (a == 3 ? 0.03952847075210474f : 1.0f);     // 1/sqrt(640)
  float4 v = *(const float4*)(p.w[a] + r);
  ushort4 o;
  o.x = f2bf(v.x * sc); o.y = f2bf(v.y * sc); o.z = f2bf(v.z * sc); o.w = f2bf(v.w * sc);
  *(ushort4*)(dst + e) = o;
}

// ---------------- 128x128 MFMA GEMM
// BK=64 (m97's proven K-step), pitch-64 LDS, 4x gload_lds per array per
// tile, 2 K-substeps of MFMA per stage -> half the barriers per unit K vs BK=32.
template<int EPI>
__global__ __launch_bounds__(256) void k_gemm(const unsigned short* __restrict__ A,
                                              const unsigned short* __restrict__ B,
                                              int M, int N, int K, int ldc,
                                              const int* __restrict__ rowmap,
                                              unsigned short* __restrict__ Cb,
                                              float* __restrict__ Cf,
                                              const float* __restrict__ resid){
  __shared__ __align__(16) unsigned short As[128 * 64];
  __shared__ __align__(16) unsigned short Bs[128 * 64];
  int m0 = blockIdx.y * 128, n0 = blockIdx.x * 128;
  int tid = threadIdx.x;
  int wid = tid >> 6, lane = tid & 63;
  int quad = lane >> 4, l16 = lane & 15;
  int wm = (wid >> 1) * 64, wn = (wid & 1) * 64;
  f32x4 acc[4][4];
#pragma unroll
  for (int i = 0; i < 4; i++)
#pragma unroll
    for (int j = 0; j < 4; j++) acc[i][j] = f32x4{0.f, 0.f, 0.f, 0.f};

  for (int k0 = 0; k0 < K; k0 += 64){
    __syncthreads();
#pragma unroll
    for (int u = 0; u < 4; u++){
      int c = tid + u * 256;
      int row = c >> 3, off = (c & 7) * 8;
      gload_lds(&A[(size_t)(m0 + row) * K + k0 + off], &As[c * 8]);
      gload_lds(&B[(size_t)(n0 + row) * K + k0 + off], &Bs[c * 8]);
    }
    __syncthreads();
#pragma unroll
    for (int ks = 0; ks < 2; ks++){
      bf16x8 af[4], bfr[4];
#pragma unroll
      for (int t = 0; t < 4; t++){
        af[t]  = *(const bf16x8*)(&As[(wm + t * 16 + l16) * 64 + ks * 32 + quad * 8]);
        bfr[t] = *(const bf16x8*)(&Bs[(wn + t * 16 + l16) * 64 + ks * 32 + quad * 8]);
      }
#pragma unroll
      for (int mt = 0; mt < 4; mt++)
#pragma unroll
        for (int nt = 0; nt < 4; nt++)
          acc[mt][nt] = __builtin_amdgcn_mfma_f32_16x16x32_bf16(af[mt], bfr[nt], acc[mt][nt], 0, 0, 0);
    }
  }
#pragma unroll
  for (int mt = 0; mt < 4; mt++)
#pragma unroll
    for (int nt = 0; nt < 4; nt++)
#pragma unroll
      for (int r = 0; r < 4; r++){
        int row = m0 + wm + mt * 16 + quad * 4 + r;
        int col = n0 + wn + nt * 16 + l16;
        float v = acc[mt][nt][r];
        if (EPI == 0){
          Cb[(size_t)rowmap[row] * ldc + col] = f2bf(v);
        } else {
          int ro = rowmap[row];
          Cf[(size_t)ro * ldc + col] = v + resid[(size_t)ro * ldc + col];
        }
      }
}

// ---------------- transpose the three V projections: vT[z][c][s] (permuted key index)
__global__ void k_transpose_v(const unsigned short* __restrict__ proj, unsigned short* __restrict__ vT){
  __shared__ unsigned short T[64][65];
  int z = blockIdx.z;
  int s0 = blockIdx.x * 64, c0 = blockIdx.y * 64;
  int colbase = 1280 + z * 1920 + c0;   // v:1280  v_e:3200  v_o:5120
  unsigned short* dst = vT + (size_t)z * CDIM * S_LEN;
  int tid = threadIdx.x;
  for (int i = tid; i < 64 * 64; i += 256){
    int r = i >> 6, c = i & 63;
    T[r][c] = proj[(size_t)(s0 + r) * NPROJ + colbase + c];
  }
  __syncthreads();
  for (int i = tid; i < 64 * 64; i += 256){
    int c = i >> 6, r = i & 63;
    dst[(size_t)(c0 + c) * S_LEN + s0 + r] = T[r][c];
  }
}

// ---------------- flash attention, d=80, z=0: orig, z=1: outside
// R18: 256-query tiles via 8-wave (512-thread) blocks -- each staged K/V tile
// now serves 2x the queries, halving TOTAL staging volume (the R11/R15/R17
// ladder showed dur ~ staging volume). Waves 0-3 stage K, waves 4-7 stage V
// (wave-uniform roles, 5 uint2/thread). Per-wave compute/barrier/epilogue
// unchanged (proven R13 structure). Key-range split kept (grid 32x8x2).
#define KP 84
#define VP 76
__global__ __launch_bounds__(512, 4) void k_attn80(const unsigned short* __restrict__ proj,
                                                   const unsigned short* __restrict__ vT,
                                                   const int* __restrict__ labP,
                                                   const int4* __restrict__ qtinfo,
                                                   unsigned short* __restrict__ opart,
                                                   float* __restrict__ lpP){
  __shared__ __align__(16) unsigned short Ks[2][64 * KP];
  __shared__ __align__(16) unsigned short Vt[2][80 * VP];
  __shared__ __align__(16) int labk[2][64];
  int tid = threadIdx.x, wid = tid >> 6, lane = tid & 63;
  int quad = lane >> 4, l16 = lane & 15;
  int qt = blockIdx.x >> 1, half = blockIdx.x & 1;
  int q0 = qt * 256;
  int h  = blockIdx.y;
  bool OUTSIDE = (blockIdx.z == 1);
  int qc = (OUTSIDE ? 3840 : 0) + h * 80;
  int kc = (OUTSIDE ? 4480 : 640) + h * 80;
  const unsigned short* vTb = vT + (size_t)(OUTSIDE ? 2 : 0) * CDIM * S_LEN;
  int4 qa = qtinfo[qt * 2], qb = qtinfo[qt * 2 + 1];
  int lo = min(qa.x, qb.x), hi = max(qa.y, qb.y);
  int t0 = lo >> 6, t1 = hi >> 6;
  int nt = t1 - t0;
  int mid = t0 + ((nt + 1) >> 1);
  int ta = half ? mid : t0;
  int tb = half ? t1 : mid;

  // two query sets per wave (B-operand layout: lane n=l16 is the query, k=quad*4+j)
  int qrow0 = q0 + wid * 32 + l16;
  int qrow1 = qrow0 + 16;
  bf16x4 qf0[5], qf1[5];
#pragma unroll
  for (int dc = 0; dc < 5; dc++){
    qf0[dc] = *(const bf16x4*)&proj[(size_t)qrow0 * NPROJ + qc + dc * 16 + quad * 4];
    qf1[dc] = *(const bf16x4*)&proj[(size_t)qrow1 * NPROJ + qc + dc * 16 + quad * 4];
  }
  int lq0 = labP[qrow0] & 0xff, lq1 = labP[qrow1] & 0xff;

  float lp0 = 0.f, lp1 = 0.f;
  f32x4 Oc0[5], Oc1[5];
#pragma unroll
  for (int t = 0; t < 5; t++){ Oc0[t] = f32x4{0.f,0.f,0.f,0.f}; Oc1[t] = f32x4{0.f,0.f,0.f,0.f}; }

  // staging roles: waves 0-3 stage the K tile (64 rows x 20 uint2), waves 4-7
  // stage the V tile (80 rows x 16 uint2). 1280 uint2 per role over 256
  // threads = 5 units/thread; unit c = t5 + u*256. All tile-invariant.
  const bool ISK = (tid < 256);
  const int t5 = ISK ? tid : (tid - 256);
  const unsigned short* gb = ISK ? proj : vTb;
  const int km = ISK ? NPROJ : 1;                    // per-tile offset multiplier
  int ga0, ga1, ga2, ga3, ga4, ls0, ls1, ls2, ls3, ls4;
  {
    const int c0_ = t5, c1_ = t5 + 256, c2_ = t5 + 512, c3_ = t5 + 768, c4_ = t5 + 1024;
    if (ISK){
      ga0 = (c0_ / 20) * NPROJ + kc + (c0_ % 20) * 4;
      ga1 = (c1_ / 20) * NPROJ + kc + (c1_ % 20) * 4;
      ga2 = (c2_ / 20) * NPROJ + kc + (c2_ % 20) * 4;
      ga3 = (c3_ / 20) * NPROJ + kc + (c3_ % 20) * 4;
      ga4 = (c4_ / 20) * NPROJ + kc + (c4_ % 20) * 4;
      ls0 = (c0_ / 20) * KP + (c0_ % 20) * 4;
      ls1 = (c1_ / 20) * KP + (c1_ % 20) * 4;
      ls2 = (c2_ / 20) * KP + (c2_ % 20) * 4;
      ls3 = (c3_ / 20) * KP + (c3_ % 20) * 4;
      ls4 = (c4_ / 20) * KP + (c4_ % 20) * 4;
    } else {
      ga0 = (h * 80 + (c0_ >> 4)) * S_LEN + (c0_ & 15) * 4;
      ga1 = (h * 80 + (c1_ >> 4)) * S_LEN + (c1_ & 15) * 4;
      ga2 = (h * 80 + (c2_ >> 4)) * S_LEN + (c2_ & 15) * 4;
      ga3 = (h * 80 + (c3_ >> 4)) * S_LEN + (c3_ & 15) * 4;
      ga4 = (h * 80 + (c4_ >> 4)) * S_LEN + (c4_ & 15) * 4;
      ls0 = (c0_ >> 4) * VP + (c0_ & 15) * 4;
      ls1 = (c1_ >> 4) * VP + (c1_ & 15) * 4;
      ls2 = (c2_ >> 4) * VP + (c2_ & 15) * 4;
      ls3 = (c3_ >> 4) * VP + (c3_ & 15) * 4;
      ls4 = (c4_ >> 4) * VP + (c4_ & 15) * 4;
    }
  }

  uint2 r0, r1, r2, r3, r4;
  int lreg = 0;

#define LOADT(kt_) do {                                              \
    size_t _ob = (size_t)((kt_) * 64) * (size_t)km;                  \
    r0 = *(const uint2*)&gb[_ob + ga0];                              \
    r1 = *(const uint2*)&gb[_ob + ga1];                              \
    r2 = *(const uint2*)&gb[_ob + ga2];                              \
    r3 = *(const uint2*)&gb[_ob + ga3];                              \
    r4 = *(const uint2*)&gb[_ob + ga4];                              \
    if (tid < 64) lreg = labP[(kt_) * 64 + tid];                     \
  } while (0)

#define WRITET(b) do {                                               \
    unsigned short* _lb = ISK ? Ks[b] : Vt[b];                       \
    *(uint2*)&_lb[ls0] = r0;                                         \
    *(uint2*)&_lb[ls1] = r1;                                         \
    *(uint2*)&_lb[ls2] = r2;                                         \
    *(uint2*)&_lb[ls3] = r3;                                         \
    *(uint2*)&_lb[ls4] = r4;                                         \
    if (tid < 64) labk[b][tid] = lreg;                               \
  } while (0)

  // prologue: stage tile ta into buf0, issue loads for ta+1
  LOADT(ta);
  WRITET(0);
  if (ta + 1 < tb) LOADT(ta + 1);
  __syncthreads();

  int cur = 0;
  for (int kt = ta; kt < tb; kt++){
    int nxt = cur ^ 1;
    // regs hold tile kt+1: write it to the other buffer (its readers finished
    // at the barrier that ended iteration kt-1), then issue loads for kt+2.
    if (kt + 1 < tb){
      WRITET(nxt);
      if (kt + 2 < tb) LOADT(kt + 2);
    }

#pragma unroll
    for (int kg = 0; kg < 4; kg++){
      // S^T(16 keys x 16 queries) = K * Q^T, two query sets share kf
      f32x4 sa0 = f32x4{0.f,0.f,0.f,0.f}, sa1 = f32x4{0.f,0.f,0.f,0.f};
#pragma unroll
      for (int dc = 0; dc < 5; dc++){
        bf16x4 kf = *(const bf16x4*)&Ks[cur][(kg * 16 + l16) * KP + dc * 16 + quad * 4];
        sa0 = mfma16(kf, qf0[dc], sa0);
        sa1 = mfma16(kf, qf1[dc], sa1);
      }
      int4 lk4 = *(const int4*)&labk[cur][kg * 16 + quad * 4];
      bool m0 = !OUTSIDE || (lk4.x & 0x100), m1 = !OUTSIDE || (lk4.y & 0x100);
      bool m2 = !OUTSIDE || (lk4.z & 0x100), m3 = !OUTSIDE || (lk4.w & 0x100);
      int k0l = lk4.x & 0xff, k1l = lk4.y & 0xff, k2l = lk4.z & 0xff, k3l = lk4.w & 0xff;
      bf16x4 pf0, pf1;
      {
        float p0 = (k0l == lq0 && m0) ? __expf(sa0[0]) : 0.f;
        float p1 = (k1l == lq0 && m1) ? __expf(sa0[1]) : 0.f;
        float p2 = (k2l == lq0 && m2) ? __expf(sa0[2]) : 0.f;
        float p3 = (k3l == lq0 && m3) ? __expf(sa0[3]) : 0.f;
        lp0 += (p0 + p1) + (p2 + p3);
        pf0[0] = (short)f2bf(p0); pf0[1] = (short)f2bf(p1);
        pf0[2] = (short)f2bf(p2); pf0[3] = (short)f2bf(p3);
      }
      {
        float p0 = (k0l == lq1 && m0) ? __expf(sa1[0]) : 0.f;
        float p1 = (k1l == lq1 && m1) ? __expf(sa1[1]) : 0.f;
        float p2 = (k2l == lq1 && m2) ? __expf(sa1[2]) : 0.f;
        float p3 = (k3l == lq1 && m3) ? __expf(sa1[3]) : 0.f;
        lp1 += (p0 + p1) + (p2 + p3);
        pf1[0] = (short)f2bf(p0); pf1[1] = (short)f2bf(p1);
        pf1[2] = (short)f2bf(p2); pf1[3] = (short)f2bf(p3);
      }
      // O^T += V^T * P^T, two query sets share vf
#pragma unroll
      for (int dt = 0; dt < 5; dt++){
        bf16x4 vf = *(const bf16x4*)&Vt[cur][(dt * 16 + l16) * VP + kg * 16 + quad * 4];
        Oc0[dt] = mfma16(vf, pf0, Oc0[dt]);
        Oc1[dt] = mfma16(vf, pf1, Oc1[dt]);
      }
    }
    __syncthreads();   // all reads of cur done; writes of nxt visible
    cur = nxt;
  }
#undef LOADT
#undef WRITET
  // row-sums: reduce across quads (same l16); write UNNORMALIZED partials
  lp0 += __shfl_xor(lp0, 16); lp0 += __shfl_xor(lp0, 32);
  lp1 += __shfl_xor(lp1, 16); lp1 += __shfl_xor(lp1, 32);
  int hz = half * 2 + (int)blockIdx.z;
  if (quad == 0){
    lpP[(size_t)(hz * 8 + h) * S_LEN + qrow0] = lp0;
    lpP[(size_t)(hz * 8 + h) * S_LEN + qrow1] = lp1;
  }
  unsigned short* dst = opart + (size_t)hz * S_LEN * CDIM;
#pragma unroll
  for (int dt = 0; dt < 5; dt++){
    ushort4 o;
    o.x = f2bf(Oc0[dt][0]); o.y = f2bf(Oc0[dt][1]);
    o.z = f2bf(Oc0[dt][2]); o.w = f2bf(Oc0[dt][3]);
    *(ushort4*)&dst[(size_t)qrow0 * CDIM + h * 80 + dt * 16 + quad * 4] = o;
    o.x = f2bf(Oc1[dt][0]); o.y = f2bf(Oc1[dt][1]);
    o.z = f2bf(Oc1[dt][2]); o.w = f2bf(Oc1[dt][3]);
    *(ushort4*)&dst[(size_t)qrow1 * CDIM + h * 80 + dt * 16 + quad * 4] = o;
  }
}

// ---------------- combine: planes[z] = (O_half0 + O_half1) / (lp_half0 + lp_half1)
__global__ __launch_bounds__(256) void k_comb(const unsigned short* __restrict__ opart,
                                              const float* __restrict__ lpP,
                                              unsigned short* __restrict__ planes){
  int i = blockIdx.x * 256 + threadIdx.x;          // 4096*160 items per z
  int z = blockIdx.y;
  int qrow = i / 160, c4 = (i % 160) * 4;
  int h = c4 / 80;                                  // 80 % 4 == 0: one h per ushort4
  size_t o0 = ((size_t)(z)     * S_LEN + qrow) * CDIM + c4;   // half0: hz = z
  size_t o1 = ((size_t)(2 + z) * S_LEN + qrow) * CDIM + c4;   // half1: hz = 2+z
  float lp = lpP[(size_t)(z * 8 + h) * S_LEN + qrow]
           + lpP[(size_t)((2 + z) * 8 + h) * S_LEN + qrow];
  float iL = 1.f / lp;
  ushort4 a = *(const ushort4*)&opart[o0];
  ushort4 b = *(const ushort4*)&opart[o1];
  ushort4 o;
  o.x = f2bf((b2f(a.x) + b2f(b.x)) * iL);
  o.y = f2bf((b2f(a.y) + b2f(b.y)) * iL);
  o.z = f2bf((b2f(a.z) + b2f(b.z)) * iL);
  o.w = f2bf((b2f(a.w) + b2f(b.w)) * iL);
  *(ushort4*)&planes[(size_t)z * S_LEN * CDIM + (size_t)qrow * CDIM + c4] = o;
}

// ---------------- entity E1: P = exp(Q_e K_e^T) per (qtile, ktile), bf16, + rowsums
// BK=64 staging (same pattern as k_gemm); __expf kept.
__global__ __launch_bounds__(256) void k_ent_qk(const unsigned short* __restrict__ proj,
                                                const int* __restrict__ labP,
                                                const int4* __restrict__ qtinfo,
                                                unsigned short* __restrict__ Sbuf,
                                                float* __restrict__ rowsum){
  int qt = blockIdx.y;
  int4 qi = qtinfo[qt];
  int nkt = (qi.y - qi.x) >> 7;
  if ((int)blockIdx.x >= nkt) return;
  int m0 = qt * 128, n0 = qi.x + blockIdx.x * 128;
  __shared__ __align__(16) unsigned short As[128 * 64];
  __shared__ __align__(16) unsigned short Bs[128 * 64];
  __shared__ int lQ[128], lK[128];
  int tid = threadIdx.x, wid = tid >> 6, lane = tid & 63;
  int quad = lane >> 4, l16 = lane & 15;
  int wm = (wid >> 1) * 64, wn = (wid & 1) * 64;
  if (tid < 128) lQ[tid] = labP[m0 + tid] & 0xff;
  else           lK[tid - 128] = labP[n0 + tid - 128] & 0xff;
  f32x4 acc[4][4];
#pragma unroll
  for (int i = 0; i < 4; i++)
#pragma unroll
    for (int j = 0; j < 4; j++) acc[i][j] = f32x4{0.f, 0.f, 0.f, 0.f};

  for (int k0 = 0; k0 < 640; k0 += 64){
    __syncthreads();
#pragma unroll
    for (int u = 0; u < 4; u++){
      int c = tid + u * 256;
      int row = c >> 3, off = (c & 7) * 8;
      gload_lds(&proj[(size_t)(m0 + row) * NPROJ + 1920 + k0 + off], &As[c * 8]);
      gload_lds(&proj[(size_t)(n0 + row) * NPROJ + 2560 + k0 + off], &Bs[c * 8]);
    }
    __syncthreads();
#pragma unroll
    for (int ks = 0; ks < 2; ks++){
      bf16x8 af[4], bfr[4];
#pragma unroll
      for (int t = 0; t < 4; t++){
        af[t]  = *(const bf16x8*)(&As[(wm + t * 16 + l16) * 64 + ks * 32 + quad * 8]);
        bfr[t] = *(const bf16x8*)(&Bs[(wn + t * 16 + l16) * 64 + ks * 32 + quad * 8]);
      }
#pragma unroll
      for (int mt = 0; mt < 4; mt++)
#pragma unroll
        for (int nt = 0; nt < 4; nt++)
          acc[mt][nt] = __builtin_amdgcn_mfma_f32_16x16x32_bf16(af[mt], bfr[nt], acc[mt][nt], 0, 0, 0);
    }
  }
  unsigned short* St = Sbuf + ((size_t)(qi.z + blockIdx.x)) * 16384;
#pragma unroll
  for (int mt = 0; mt < 4; mt++)
#pragma unroll
    for (int r = 0; r < 4; r++){
      int lrow = wm + mt * 16 + quad * 4 + r;
      int myq = lQ[lrow];
      float psum = 0.f;
#pragma unroll
      for (int nt = 0; nt < 4; nt++){
        int lcol = wn + nt * 16 + l16;
        float p = (myq == lK[lcol]) ? __expf(acc[mt][nt][r]) : 0.f;
        St[lrow * 128 + lcol] = f2bf(p);
        psum += p;
      }
#pragma unroll
      for (int m = 1; m < 16; m <<= 1) psum += __shfl_xor(psum, m);
      if (l16 == 0) atomicAdd(&rowsum[m0 + lrow], psum);
    }
}

// ---------------- entity E2: attnS = bf16( P·V_e / rowsum + plane0 + plane1 )
__global__ __launch_bounds__(256) void k_ent_pv(const unsigned short* __restrict__ Sbuf,
                                                const unsigned short* __restrict__ veT,
                                                const int4* __restrict__ qtinfo,
                                                const float* __restrict__ rowsum,
                                                const unsigned short* __restrict__ planes,
                                                unsigned short* __restrict__ attnS){
  int qt = blockIdx.y, d0 = blockIdx.x * 128;
  int4 qi = qtinfo[qt];
  int m0 = qt * 128;
  int nk = qi.y - qi.x;
  __shared__ __align__(16) unsigned short As[128 * 32];
  __shared__ __align__(16) unsigned short Bs[128 * 32];
  int tid = threadIdx.x, wid = tid >> 6, lane = tid & 63;
  int quad = lane >> 4, l16 = lane & 15;
  int wm = (wid >> 1) * 64, wn = (wid & 1) * 64;
  f32x4 acc[4][4];
#pragma unroll
  for (int i = 0; i < 4; i++)
#pragma unroll
    for (int j = 0; j < 4; j++) acc[i][j] = f32x4{0.f, 0.f, 0.f, 0.f};

  for (int kk = 0; kk < nk; kk += 32){
    const unsigned short* St = Sbuf + ((size_t)(qi.z + (kk >> 7))) * 16384;
    int kloc = kk & 127;
    __syncthreads();
#pragma unroll
    for (int u = 0; u < 2; u++){
      int c = tid + u * 256;
      int row = c >> 2, off = (c & 3) * 8;
      gload_lds(&St[row * 128 + kloc + off], &As[c * 8]);
      gload_lds(&veT[(size_t)(d0 + row) * S_LEN + qi.x + kk + off], &Bs[c * 8]);
    }
    __syncthreads();
    bf16x8 af[4], bfr[4];
#pragma unroll
    for (int t = 0; t < 4; t++){
      af[t]  = *(const bf16x8*)(&As[(wm + t * 16 + l16) * 32 + quad * 8]);
      bfr[t] = *(const bf16x8*)(&Bs[(wn + t * 16 + l16) * 32 + quad * 8]);
    }
#pragma unroll
    for (int mt = 0; mt < 4; mt++)
#pragma unroll
      for (int nt = 0; nt < 4; nt++)
        acc[mt][nt] = __builtin_amdgcn_mfma_f32_16x16x32_bf16(af[mt], bfr[nt], acc[mt][nt], 0, 0, 0);
  }
#pragma unroll
  for (int mt = 0; mt < 4; mt++)
#pragma unroll
    for (int r = 0; r < 4; r++){
      int row = m0 + wm + mt * 16 + quad * 4 + r;
      float invL = 1.f / rowsum[row];
#pragma unroll
      for (int nt = 0; nt < 4; nt++){
        int col = d0 + wn + nt * 16 + l16;
        size_t idx = (size_t)row * CDIM + col;
        float v = acc[mt][nt][r] * invL + b2f(planes[idx]) + b2f(planes[(size_t)S_LEN * CDIM + idx]);
        attnS[idx] = f2bf(v);
      }
    }
}

extern "C" void kernel_launch(void* const* d_in, const int* in_sizes, int n_in,
                              void* d_out, int out_size, void* d_ws, size_t ws_size,
                              hipStream_t stream){
  const float* hs  = (const float*)d_in[0];
  const int* mask  = (const int*)d_in[1];
  const int* inp   = (const int*)d_in[2];
  char* ws = (char*)d_ws;
  int*            labels  = (int*)(ws + 0);
  int*            boff    = (int*)(ws + 16384);
  int*            cnt     = (int*)(ws + 16640);
  int*            perm    = (int*)(ws + 16896);
  int*            inv     = (int*)(ws + 33280);
  int*            labP    = (int*)(ws + 49664);
  int4*           qtinfo  = (int4*)(ws + 66560);
  float*          rowsum  = (float*)(ws + 67072);
  unsigned short* hsb     = (unsigned short*)(ws + 131072);
  unsigned short* Wall    = (unsigned short*)(ws + 5373952);
  unsigned short* proj    = (unsigned short*)(ws + 13565952);
  unsigned short* vT      = (unsigned short*)(ws + 60751872);
  unsigned short* planes  = (unsigned short*)(ws + 76480512);   // 2 bf16 planes = 10.5 MB
  unsigned short* Sbuf    = (unsigned short*)(ws + 86966272);   // up to 1024 tiles * 32 KB
  unsigned short* attnS   = (unsigned short*)(ws + 120520704);
  unsigned short* Wob     = Wall + 9 * 409600;
  // attn partials live in the Sbuf region (consumed by k_comb BEFORE k_ent_qk
  // overwrites Sbuf): opart = 4 x [4096][640] bf16 (21 MB), lpP = 4x8x4096 f32.
  unsigned short* opart   = Sbuf;
  float*          lpP     = (float*)(ws + 86966272 + 20971520);

  k_labels<<<16, 256, 0, stream>>>(mask, inp, labels);
  k_hist<<<1, 256, 0, stream>>>(labels, boff, cnt);
  k_perm<<<16, 256, 0, stream>>>(labels, boff, cnt, perm, inv, labP);
  k_tiles<<<1, 256, 0, stream>>>(labP, boff, qtinfo, rowsum);
  k_cvt_hs<<<(S_LEN * CDIM / 4 + 255) / 256, 256, 0, stream>>>(hs, hsb, S_LEN * CDIM);
  WPtrs wp;
  for (int i = 0; i < 10; i++) wp.w[i] = (const float*)d_in[3 + i];
  k_cvt_w<<<(10 * 409600 / 4 + 255) / 256, 256, 0, stream>>>(wp, Wall);

  // all 9 projections in one GEMM, rows scattered into bucket-permuted order
  k_gemm<0><<<dim3(45, 32), 256, 0, stream>>>(hsb, Wall, S_LEN, NPROJ, CDIM, NPROJ,
                                              inv, proj, nullptr, nullptr);
  k_transpose_v<<<dim3(64, 10, 3), 256, 0, stream>>>(proj, vT);

  // branches 1+3: 256-query 8-wave blocks + key-range split; partials + combine
  k_attn80<<<dim3(32, 8, 2), 512, 0, stream>>>(proj, vT, labP, qtinfo, opart, lpP);
  k_comb<<<dim3(2560, 2), 256, 0, stream>>>(opart, lpP, planes);

  // branch 2 (entity, d=640): GEMM-ified, P materialized bf16 per bucket
  k_ent_qk<<<dim3(32, 32), 256, 0, stream>>>(proj, labP, qtinfo, Sbuf, rowsum);
  k_ent_pv<<<dim3(5, 32), 256, 0, stream>>>(Sbuf, vT + (size_t)1 * CDIM * S_LEN,
                                            qtinfo, rowsum, planes, attnS);

  // out = attnS @ Wo^T + residual, un-permuted via perm in the epilogue
  k_gemm<1><<<dim3(5, 32), 256, 0, stream>>>(attnS, Wob, S_LEN, CDIM, CDIM, CDIM,
                                             perm, nullptr, (float*)d_out, hs);
}

// Round 9
// 404.334 us; speedup vs baseline: 1.3291x; 1.3291x over previous
//
#include <hip/hip_runtime.h>
#include <cstdint>

typedef __attribute__((ext_vector_type(8))) short bf16x8;
typedef __attribute__((ext_vector_type(4))) short bf16x4;
typedef __attribute__((ext_vector_type(4))) float f32x4;

#define S_LEN 4096
#define CDIM  640
#define NPROJ 5760

// K=16 bf16 MFMA (v_mfma_f32_16x16x16_bf16, gfx950-valid per ISA §10).
__device__ __forceinline__ f32x4 mfma16(bf16x4 a, bf16x4 b, f32x4 c){
#if defined(__HIP_DEVICE_COMPILE__) && __HIP_DEVICE_COMPILE__
  return __builtin_amdgcn_mfma_f32_16x16x16bf16_1k(a, b, c, 0, 0, 0);
#else
  (void)a; (void)b;
  return c;
#endif
}

// async global->LDS, 16B per lane; LDS dest must be wave-uniform base + lane*16
__device__ __forceinline__ void gload_lds(const unsigned short* g, unsigned short* l){
#if defined(__HIP_DEVICE_COMPILE__) && __HIP_DEVICE_COMPILE__
  __builtin_amdgcn_global_load_lds((const __attribute__((address_space(1))) unsigned int*)g,
                                   (__attribute__((address_space(3))) unsigned int*)l, 16, 0, 0);
#else
  (void)g; (void)l;
#endif
}

__device__ __forceinline__ unsigned short f2bf(float f){
  union { float f; uint32_t u; } v; v.f = f;
  uint32_t u = v.u;
  return (unsigned short)((u + 0x7fffu + ((u >> 16) & 1u)) >> 16);
}
__device__ __forceinline__ float b2f(unsigned short h){
  union { uint32_t u; float f; } v; v.u = ((uint32_t)h) << 16;
  return v.f;
}

// ---------------- labels: nearest-resize 512x512 -> 64x64, pack m | (im==0)<<8
__global__ void k_labels(const int* __restrict__ mask, const int* __restrict__ inp,
                         int* __restrict__ labels){
  int s = blockIdx.x * 256 + threadIdx.x;
  if (s >= S_LEN) return;
  int y = s >> 6, x = s & 63;
  int off = (y * 8) * 512 + x * 8;
  int m = mask[off] & 0xff;
  int o = (inp[off] == 0) ? 0x100 : 0;
  labels[s] = m | o;
}

// ---------------- bucket sort by label value (4 buckets)
__global__ void k_hist(const int* __restrict__ labels, int* __restrict__ boff, int* __restrict__ cnt){
  __shared__ int h[4];
  if (threadIdx.x < 4) h[threadIdx.x] = 0;
  __syncthreads();
  for (int s = threadIdx.x; s < S_LEN; s += 256) atomicAdd(&h[labels[s] & 3], 1);
  __syncthreads();
  if (threadIdx.x == 0){
    int a = 0;
    for (int c = 0; c < 4; c++){ boff[c] = a; a += h[c]; }
    boff[4] = a;
  }
  if (threadIdx.x < 4) cnt[threadIdx.x] = 0;
}

__global__ void k_perm(const int* __restrict__ labels, const int* __restrict__ boff,
                       int* __restrict__ cnt, int* __restrict__ perm,
                       int* __restrict__ inv, int* __restrict__ labP){
  int s = blockIdx.x * 256 + threadIdx.x;
  if (s >= S_LEN) return;
  int lab = labels[s];
  int c = lab & 3;
  int pos = boff[c] + atomicAdd(&cnt[c], 1);
  perm[pos] = s; inv[s] = pos; labP[pos] = lab;
}

// per 128-tile key ranges (shared by attn80 and entity); zero rowsum
__global__ void k_tiles(const int* __restrict__ labP, const int* __restrict__ boff,
                        int4* __restrict__ qtinfo, float* __restrict__ rowsum){
  int t = threadIdx.x;
  __shared__ int nkt[32];
  if (t < 32){
    int c0 = labP[t * 128] & 3, c1 = labP[t * 128 + 127] & 3;
    int lo = boff[c0] & ~127, hi = (boff[c1 + 1] + 127) & ~127;
    qtinfo[t].x = lo; qtinfo[t].y = hi; qtinfo[t].w = 0;
    nkt[t] = (hi - lo) >> 7;
  }
  __syncthreads();
  if (t == 0){
    int a = 0;
    for (int i = 0; i < 32; i++){ qtinfo[i].z = a; a += nkt[i]; }
  }
  for (int s = t; s < S_LEN; s += 256) rowsum[s] = 0.f;
}

// ---------------- f32 -> bf16 converts
__global__ void k_cvt_hs(const float* __restrict__ src, unsigned short* __restrict__ dst, int n){
  int idx = (blockIdx.x * 256 + threadIdx.x) * 4;
  if (idx >= n) return;
  float4 v = *(const float4*)(src + idx);
  ushort4 o;
  o.x = f2bf(v.x); o.y = f2bf(v.y); o.z = f2bf(v.z); o.w = f2bf(v.w);
  *(ushort4*)(dst + idx) = o;
}

struct WPtrs { const float* w[10]; };

__global__ void k_cvt_w(WPtrs p, unsigned short* __restrict__ dst){
  int e = (blockIdx.x * 256 + threadIdx.x) * 4;
  if (e >= 10 * 409600) return;
  int a = e / 409600, r = e % 409600;
  float sc = (a == 0 || a == 6) ? 0.11180339887498948f   // 1/sqrt(80)
           : (a == 3 ? 0.03952847075210474f : 1.0f);     // 1/sqrt(640)
  float4 v = *(const float4*)(p.w[a] + r);
  ushort4 o;
  o.x = f2bf(v.x * sc); o.y = f2bf(v.y * sc); o.z = f2bf(v.z * sc); o.w = f2bf(v.w * sc);
  *(ushort4*)(dst + e) = o;
}

// ---------------- 128x128 MFMA GEMM
// BK=64 (m97's proven K-step), pitch-64 LDS, 4x gload_lds per array per
// tile, 2 K-substeps of MFMA per stage -> half the barriers per unit K vs BK=32.
template<int EPI>
__global__ __launch_bounds__(256) void k_gemm(const unsigned short* __restrict__ A,
                                              const unsigned short* __restrict__ B,
                                              int M, int N, int K, int ldc,
                                              const int* __restrict__ rowmap,
                                              unsigned short* __restrict__ Cb,
                                              float* __restrict__ Cf,
                                              const float* __restrict__ resid){
  __shared__ __align__(16) unsigned short As[128 * 64];
  __shared__ __align__(16) unsigned short Bs[128 * 64];
  int m0 = blockIdx.y * 128, n0 = blockIdx.x * 128;
  int tid = threadIdx.x;
  int wid = tid >> 6, lane = tid & 63;
  int quad = lane >> 4, l16 = lane & 15;
  int wm = (wid >> 1) * 64, wn = (wid & 1) * 64;
  f32x4 acc[4][4];
#pragma unroll
  for (int i = 0; i < 4; i++)
#pragma unroll
    for (int j = 0; j < 4; j++) acc[i][j] = f32x4{0.f, 0.f, 0.f, 0.f};

  for (int k0 = 0; k0 < K; k0 += 64){
    __syncthreads();
#pragma unroll
    for (int u = 0; u < 4; u++){
      int c = tid + u * 256;
      int row = c >> 3, off = (c & 7) * 8;
      gload_lds(&A[(size_t)(m0 + row) * K + k0 + off], &As[c * 8]);
      gload_lds(&B[(size_t)(n0 + row) * K + k0 + off], &Bs[c * 8]);
    }
    __syncthreads();
#pragma unroll
    for (int ks = 0; ks < 2; ks++){
      bf16x8 af[4], bfr[4];
#pragma unroll
      for (int t = 0; t < 4; t++){
        af[t]  = *(const bf16x8*)(&As[(wm + t * 16 + l16) * 64 + ks * 32 + quad * 8]);
        bfr[t] = *(const bf16x8*)(&Bs[(wn + t * 16 + l16) * 64 + ks * 32 + quad * 8]);
      }
#pragma unroll
      for (int mt = 0; mt < 4; mt++)
#pragma unroll
        for (int nt = 0; nt < 4; nt++)
          acc[mt][nt] = __builtin_amdgcn_mfma_f32_16x16x32_bf16(af[mt], bfr[nt], acc[mt][nt], 0, 0, 0);
    }
  }
#pragma unroll
  for (int mt = 0; mt < 4; mt++)
#pragma unroll
    for (int nt = 0; nt < 4; nt++)
#pragma unroll
      for (int r = 0; r < 4; r++){
        int row = m0 + wm + mt * 16 + quad * 4 + r;
        int col = n0 + wn + nt * 16 + l16;
        float v = acc[mt][nt][r];
        if (EPI == 0){
          Cb[(size_t)rowmap[row] * ldc + col] = f2bf(v);
        } else {
          int ro = rowmap[row];
          Cf[(size_t)ro * ldc + col] = v + resid[(size_t)ro * ldc + col];
        }
      }
}

// ---------------- transpose the three V projections: vT[z][c][s] (permuted key index)
__global__ void k_transpose_v(const unsigned short* __restrict__ proj, unsigned short* __restrict__ vT){
  __shared__ unsigned short T[64][65];
  int z = blockIdx.z;
  int s0 = blockIdx.x * 64, c0 = blockIdx.y * 64;
  int colbase = 1280 + z * 1920 + c0;   // v:1280  v_e:3200  v_o:5120
  unsigned short* dst = vT + (size_t)z * CDIM * S_LEN;
  int tid = threadIdx.x;
  for (int i = tid; i < 64 * 64; i += 256){
    int r = i >> 6, c = i & 63;
    T[r][c] = proj[(size_t)(s0 + r) * NPROJ + colbase + c];
  }
  __syncthreads();
  for (int i = tid; i < 64 * 64; i += 256){
    int c = i >> 6, r = i & 63;
    dst[(size_t)(c0 + c) * S_LEN + s0 + r] = T[r][c];
  }
}

// ---------------- flash attention, d=80, z=0: orig, z=1: outside
// R19: R18 structure (256-query 8-wave blocks, waves 0-3 stage K / 4-7 stage
// V, halved total staging) with the register budget FIXED:
// __launch_bounds__(512, 2) -> cap 256 VGPR. R18's (512,4) forced VGPR=64 and
// spilled (WRITE 21->178 MB). Kernel needs ~100; if compiler lands <=128,
// HW still fits 2 blocks/CU = 16 waves/CU. WRITE_SIZE ~21 MB = no-spill invariant.
#define KP 84
#define VP 76
__global__ __launch_bounds__(512, 2) void k_attn80(const unsigned short* __restrict__ proj,
                                                   const unsigned short* __restrict__ vT,
                                                   const int* __restrict__ labP,
                                                   const int4* __restrict__ qtinfo,
                                                   unsigned short* __restrict__ opart,
                                                   float* __restrict__ lpP){
  __shared__ __align__(16) unsigned short Ks[2][64 * KP];
  __shared__ __align__(16) unsigned short Vt[2][80 * VP];
  __shared__ __align__(16) int labk[2][64];
  int tid = threadIdx.x, wid = tid >> 6, lane = tid & 63;
  int quad = lane >> 4, l16 = lane & 15;
  int qt = blockIdx.x >> 1, half = blockIdx.x & 1;
  int q0 = qt * 256;
  int h  = blockIdx.y;
  bool OUTSIDE = (blockIdx.z == 1);
  int qc = (OUTSIDE ? 3840 : 0) + h * 80;
  int kc = (OUTSIDE ? 4480 : 640) + h * 80;
  const unsigned short* vTb = vT + (size_t)(OUTSIDE ? 2 : 0) * CDIM * S_LEN;
  int4 qa = qtinfo[qt * 2], qb = qtinfo[qt * 2 + 1];
  int lo = min(qa.x, qb.x), hi = max(qa.y, qb.y);
  int t0 = lo >> 6, t1 = hi >> 6;
  int nt = t1 - t0;
  int mid = t0 + ((nt + 1) >> 1);
  int ta = half ? mid : t0;
  int tb = half ? t1 : mid;

  // two query sets per wave (B-operand layout: lane n=l16 is the query, k=quad*4+j)
  int qrow0 = q0 + wid * 32 + l16;
  int qrow1 = qrow0 + 16;
  bf16x4 qf0[5], qf1[5];
#pragma unroll
  for (int dc = 0; dc < 5; dc++){
    qf0[dc] = *(const bf16x4*)&proj[(size_t)qrow0 * NPROJ + qc + dc * 16 + quad * 4];
    qf1[dc] = *(const bf16x4*)&proj[(size_t)qrow1 * NPROJ + qc + dc * 16 + quad * 4];
  }
  int lq0 = labP[qrow0] & 0xff, lq1 = labP[qrow1] & 0xff;

  float lp0 = 0.f, lp1 = 0.f;
  f32x4 Oc0[5], Oc1[5];
#pragma unroll
  for (int t = 0; t < 5; t++){ Oc0[t] = f32x4{0.f,0.f,0.f,0.f}; Oc1[t] = f32x4{0.f,0.f,0.f,0.f}; }

  // staging roles: waves 0-3 stage the K tile (64 rows x 20 uint2), waves 4-7
  // stage the V tile (80 rows x 16 uint2). 1280 uint2 per role over 256
  // threads = 5 units/thread; unit c = t5 + u*256. All tile-invariant.
  const bool ISK = (tid < 256);
  const int t5 = ISK ? tid : (tid - 256);
  const unsigned short* gb = ISK ? proj : vTb;
  const int km = ISK ? NPROJ : 1;                    // per-tile offset multiplier
  int ga0, ga1, ga2, ga3, ga4, ls0, ls1, ls2, ls3, ls4;
  {
    const int c0_ = t5, c1_ = t5 + 256, c2_ = t5 + 512, c3_ = t5 + 768, c4_ = t5 + 1024;
    if (ISK){
      ga0 = (c0_ / 20) * NPROJ + kc + (c0_ % 20) * 4;
      ga1 = (c1_ / 20) * NPROJ + kc + (c1_ % 20) * 4;
      ga2 = (c2_ / 20) * NPROJ + kc + (c2_ % 20) * 4;
      ga3 = (c3_ / 20) * NPROJ + kc + (c3_ % 20) * 4;
      ga4 = (c4_ / 20) * NPROJ + kc + (c4_ % 20) * 4;
      ls0 = (c0_ / 20) * KP + (c0_ % 20) * 4;
      ls1 = (c1_ / 20) * KP + (c1_ % 20) * 4;
      ls2 = (c2_ / 20) * KP + (c2_ % 20) * 4;
      ls3 = (c3_ / 20) * KP + (c3_ % 20) * 4;
      ls4 = (c4_ / 20) * KP + (c4_ % 20) * 4;
    } else {
      ga0 = (h * 80 + (c0_ >> 4)) * S_LEN + (c0_ & 15) * 4;
      ga1 = (h * 80 + (c1_ >> 4)) * S_LEN + (c1_ & 15) * 4;
      ga2 = (h * 80 + (c2_ >> 4)) * S_LEN + (c2_ & 15) * 4;
      ga3 = (h * 80 + (c3_ >> 4)) * S_LEN + (c3_ & 15) * 4;
      ga4 = (h * 80 + (c4_ >> 4)) * S_LEN + (c4_ & 15) * 4;
      ls0 = (c0_ >> 4) * VP + (c0_ & 15) * 4;
      ls1 = (c1_ >> 4) * VP + (c1_ & 15) * 4;
      ls2 = (c2_ >> 4) * VP + (c2_ & 15) * 4;
      ls3 = (c3_ >> 4) * VP + (c3_ & 15) * 4;
      ls4 = (c4_ >> 4) * VP + (c4_ & 15) * 4;
    }
  }

  uint2 r0, r1, r2, r3, r4;
  int lreg = 0;

#define LOADT(kt_) do {                                              \
    size_t _ob = (size_t)((kt_) * 64) * (size_t)km;                  \
    r0 = *(const uint2*)&gb[_ob + ga0];                              \
    r1 = *(const uint2*)&gb[_ob + ga1];                              \
    r2 = *(const uint2*)&gb[_ob + ga2];                              \
    r3 = *(const uint2*)&gb[_ob + ga3];                              \
    r4 = *(const uint2*)&gb[_ob + ga4];                              \
    if (tid < 64) lreg = labP[(kt_) * 64 + tid];                     \
  } while (0)

#define WRITET(b) do {                                               \
    unsigned short* _lb = ISK ? Ks[b] : Vt[b];                       \
    *(uint2*)&_lb[ls0] = r0;                                         \
    *(uint2*)&_lb[ls1] = r1;                                         \
    *(uint2*)&_lb[ls2] = r2;                                         \
    *(uint2*)&_lb[ls3] = r3;                                         \
    *(uint2*)&_lb[ls4] = r4;                                         \
    if (tid < 64) labk[b][tid] = lreg;                               \
  } while (0)

  // prologue: stage tile ta into buf0, issue loads for ta+1
  LOADT(ta);
  WRITET(0);
  if (ta + 1 < tb) LOADT(ta + 1);
  __syncthreads();

  int cur = 0;
  for (int kt = ta; kt < tb; kt++){
    int nxt = cur ^ 1;
    // regs hold tile kt+1: write it to the other buffer (its readers finished
    // at the barrier that ended iteration kt-1), then issue loads for kt+2.
    if (kt + 1 < tb){
      WRITET(nxt);
      if (kt + 2 < tb) LOADT(kt + 2);
    }

#pragma unroll
    for (int kg = 0; kg < 4; kg++){
      // S^T(16 keys x 16 queries) = K * Q^T, two query sets share kf
      f32x4 sa0 = f32x4{0.f,0.f,0.f,0.f}, sa1 = f32x4{0.f,0.f,0.f,0.f};
#pragma unroll
      for (int dc = 0; dc < 5; dc++){
        bf16x4 kf = *(const bf16x4*)&Ks[cur][(kg * 16 + l16) * KP + dc * 16 + quad * 4];
        sa0 = mfma16(kf, qf0[dc], sa0);
        sa1 = mfma16(kf, qf1[dc], sa1);
      }
      int4 lk4 = *(const int4*)&labk[cur][kg * 16 + quad * 4];
      bool m0 = !OUTSIDE || (lk4.x & 0x100), m1 = !OUTSIDE || (lk4.y & 0x100);
      bool m2 = !OUTSIDE || (lk4.z & 0x100), m3 = !OUTSIDE || (lk4.w & 0x100);
      int k0l = lk4.x & 0xff, k1l = lk4.y & 0xff, k2l = lk4.z & 0xff, k3l = lk4.w & 0xff;
      bf16x4 pf0, pf1;
      {
        float p0 = (k0l == lq0 && m0) ? __expf(sa0[0]) : 0.f;
        float p1 = (k1l == lq0 && m1) ? __expf(sa0[1]) : 0.f;
        float p2 = (k2l == lq0 && m2) ? __expf(sa0[2]) : 0.f;
        float p3 = (k3l == lq0 && m3) ? __expf(sa0[3]) : 0.f;
        lp0 += (p0 + p1) + (p2 + p3);
        pf0[0] = (short)f2bf(p0); pf0[1] = (short)f2bf(p1);
        pf0[2] = (short)f2bf(p2); pf0[3] = (short)f2bf(p3);
      }
      {
        float p0 = (k0l == lq1 && m0) ? __expf(sa1[0]) : 0.f;
        float p1 = (k1l == lq1 && m1) ? __expf(sa1[1]) : 0.f;
        float p2 = (k2l == lq1 && m2) ? __expf(sa1[2]) : 0.f;
        float p3 = (k3l == lq1 && m3) ? __expf(sa1[3]) : 0.f;
        lp1 += (p0 + p1) + (p2 + p3);
        pf1[0] = (short)f2bf(p0); pf1[1] = (short)f2bf(p1);
        pf1[2] = (short)f2bf(p2); pf1[3] = (short)f2bf(p3);
      }
      // O^T += V^T * P^T, two query sets share vf
#pragma unroll
      for (int dt = 0; dt < 5; dt++){
        bf16x4 vf = *(const bf16x4*)&Vt[cur][(dt * 16 + l16) * VP + kg * 16 + quad * 4];
        Oc0[dt] = mfma16(vf, pf0, Oc0[dt]);
        Oc1[dt] = mfma16(vf, pf1, Oc1[dt]);
      }
    }
    __syncthreads();   // all reads of cur done; writes of nxt visible
    cur = nxt;
  }
#undef LOADT
#undef WRITET
  // row-sums: reduce across quads (same l16); write UNNORMALIZED partials
  lp0 += __shfl_xor(lp0, 16); lp0 += __shfl_xor(lp0, 32);
  lp1 += __shfl_xor(lp1, 16); lp1 += __shfl_xor(lp1, 32);
  int hz = half * 2 + (int)blockIdx.z;
  if (quad == 0){
    lpP[(size_t)(hz * 8 + h) * S_LEN + qrow0] = lp0;
    lpP[(size_t)(hz * 8 + h) * S_LEN + qrow1] = lp1;
  }
  unsigned short* dst = opart + (size_t)hz * S_LEN * CDIM;
#pragma unroll
  for (int dt = 0; dt < 5; dt++){
    ushort4 o;
    o.x = f2bf(Oc0[dt][0]); o.y = f2bf(Oc0[dt][1]);
    o.z = f2bf(Oc0[dt][2]); o.w = f2bf(Oc0[dt][3]);
    *(ushort4*)&dst[(size_t)qrow0 * CDIM + h * 80 + dt * 16 + quad * 4] = o;
    o.x = f2bf(Oc1[dt][0]); o.y = f2bf(Oc1[dt][1]);
    o.z = f2bf(Oc1[dt][2]); o.w = f2bf(Oc1[dt][3]);
    *(ushort4*)&dst[(size_t)qrow1 * CDIM + h * 80 + dt * 16 + quad * 4] = o;
  }
}

// ---------------- combine: planes[z] = (O_half0 + O_half1) / (lp_half0 + lp_half1)
__global__ __launch_bounds__(256) void k_comb(const unsigned short* __restrict__ opart,
                                              const float* __restrict__ lpP,
                                              unsigned short* __restrict__ planes){
  int i = blockIdx.x * 256 + threadIdx.x;          // 4096*160 items per z
  int z = blockIdx.y;
  int qrow = i / 160, c4 = (i % 160) * 4;
  int h = c4 / 80;                                  // 80 % 4 == 0: one h per ushort4
  size_t o0 = ((size_t)(z)     * S_LEN + qrow) * CDIM + c4;   // half0: hz = z
  size_t o1 = ((size_t)(2 + z) * S_LEN + qrow) * CDIM + c4;   // half1: hz = 2+z
  float lp = lpP[(size_t)(z * 8 + h) * S_LEN + qrow]
           + lpP[(size_t)((2 + z) * 8 + h) * S_LEN + qrow];
  float iL = 1.f / lp;
  ushort4 a = *(const ushort4*)&opart[o0];
  ushort4 b = *(const ushort4*)&opart[o1];
  ushort4 o;
  o.x = f2bf((b2f(a.x) + b2f(b.x)) * iL);
  o.y = f2bf((b2f(a.y) + b2f(b.y)) * iL);
  o.z = f2bf((b2f(a.z) + b2f(b.z)) * iL);
  o.w = f2bf((b2f(a.w) + b2f(b.w)) * iL);
  *(ushort4*)&planes[(size_t)z * S_LEN * CDIM + (size_t)qrow * CDIM + c4] = o;
}

// ---------------- entity E1: P = exp(Q_e K_e^T) per (qtile, ktile), bf16, + rowsums
// BK=64 staging (same pattern as k_gemm); __expf kept.
__global__ __launch_bounds__(256) void k_ent_qk(const unsigned short* __restrict__ proj,
                                                const int* __restrict__ labP,
                                                const int4* __restrict__ qtinfo,
                                                unsigned short* __restrict__ Sbuf,
                                                float* __restrict__ rowsum){
  int qt = blockIdx.y;
  int4 qi = qtinfo[qt];
  int nkt = (qi.y - qi.x) >> 7;
  if ((int)blockIdx.x >= nkt) return;
  int m0 = qt * 128, n0 = qi.x + blockIdx.x * 128;
  __shared__ __align__(16) unsigned short As[128 * 64];
  __shared__ __align__(16) unsigned short Bs[128 * 64];
  __shared__ int lQ[128], lK[128];
  int tid = threadIdx.x, wid = tid >> 6, lane = tid & 63;
  int quad = lane >> 4, l16 = lane & 15;
  int wm = (wid >> 1) * 64, wn = (wid & 1) * 64;
  if (tid < 128) lQ[tid] = labP[m0 + tid] & 0xff;
  else           lK[tid - 128] = labP[n0 + tid - 128] & 0xff;
  f32x4 acc[4][4];
#pragma unroll
  for (int i = 0; i < 4; i++)
#pragma unroll
    for (int j = 0; j < 4; j++) acc[i][j] = f32x4{0.f, 0.f, 0.f, 0.f};

  for (int k0 = 0; k0 < 640; k0 += 64){
    __syncthreads();
#pragma unroll
    for (int u = 0; u < 4; u++){
      int c = tid + u * 256;
      int row = c >> 3, off = (c & 7) * 8;
      gload_lds(&proj[(size_t)(m0 + row) * NPROJ + 1920 + k0 + off], &As[c * 8]);
      gload_lds(&proj[(size_t)(n0 + row) * NPROJ + 2560 + k0 + off], &Bs[c * 8]);
    }
    __syncthreads();
#pragma unroll
    for (int ks = 0; ks < 2; ks++){
      bf16x8 af[4], bfr[4];
#pragma unroll
      for (int t = 0; t < 4; t++){
        af[t]  = *(const bf16x8*)(&As[(wm + t * 16 + l16) * 64 + ks * 32 + quad * 8]);
        bfr[t] = *(const bf16x8*)(&Bs[(wn + t * 16 + l16) * 64 + ks * 32 + quad * 8]);
      }
#pragma unroll
      for (int mt = 0; mt < 4; mt++)
#pragma unroll
        for (int nt = 0; nt < 4; nt++)
          acc[mt][nt] = __builtin_amdgcn_mfma_f32_16x16x32_bf16(af[mt], bfr[nt], acc[mt][nt], 0, 0, 0);
    }
  }
  unsigned short* St = Sbuf + ((size_t)(qi.z + blockIdx.x)) * 16384;
#pragma unroll
  for (int mt = 0; mt < 4; mt++)
#pragma unroll
    for (int r = 0; r < 4; r++){
      int lrow = wm + mt * 16 + quad * 4 + r;
      int myq = lQ[lrow];
      float psum = 0.f;
#pragma unroll
      for (int nt = 0; nt < 4; nt++){
        int lcol = wn + nt * 16 + l16;
        float p = (myq == lK[lcol]) ? __expf(acc[mt][nt][r]) : 0.f;
        St[lrow * 128 + lcol] = f2bf(p);
        psum += p;
      }
#pragma unroll
      for (int m = 1; m < 16; m <<= 1) psum += __shfl_xor(psum, m);
      if (l16 == 0) atomicAdd(&rowsum[m0 + lrow], psum);
    }
}

// ---------------- entity E2: attnS = bf16( P·V_e / rowsum + plane0 + plane1 )
__global__ __launch_bounds__(256) void k_ent_pv(const unsigned short* __restrict__ Sbuf,
                                                const unsigned short* __restrict__ veT,
                                                const int4* __restrict__ qtinfo,
                                                const float* __restrict__ rowsum,
                                                const unsigned short* __restrict__ planes,
                                                unsigned short* __restrict__ attnS){
  int qt = blockIdx.y, d0 = blockIdx.x * 128;
  int4 qi = qtinfo[qt];
  int m0 = qt * 128;
  int nk = qi.y - qi.x;
  __shared__ __align__(16) unsigned short As[128 * 32];
  __shared__ __align__(16) unsigned short Bs[128 * 32];
  int tid = threadIdx.x, wid = tid >> 6, lane = tid & 63;
  int quad = lane >> 4, l16 = lane & 15;
  int wm = (wid >> 1) * 64, wn = (wid & 1) * 64;
  f32x4 acc[4][4];
#pragma unroll
  for (int i = 0; i < 4; i++)
#pragma unroll
    for (int j = 0; j < 4; j++) acc[i][j] = f32x4{0.f, 0.f, 0.f, 0.f};

  for (int kk = 0; kk < nk; kk += 32){
    const unsigned short* St = Sbuf + ((size_t)(qi.z + (kk >> 7))) * 16384;
    int kloc = kk & 127;
    __syncthreads();
#pragma unroll
    for (int u = 0; u < 2; u++){
      int c = tid + u * 256;
      int row = c >> 2, off = (c & 3) * 8;
      gload_lds(&St[row * 128 + kloc + off], &As[c * 8]);
      gload_lds(&veT[(size_t)(d0 + row) * S_LEN + qi.x + kk + off], &Bs[c * 8]);
    }
    __syncthreads();
    bf16x8 af[4], bfr[4];
#pragma unroll
    for (int t = 0; t < 4; t++){
      af[t]  = *(const bf16x8*)(&As[(wm + t * 16 + l16) * 32 + quad * 8]);
      bfr[t] = *(const bf16x8*)(&Bs[(wn + t * 16 + l16) * 32 + quad * 8]);
    }
#pragma unroll
    for (int mt = 0; mt < 4; mt++)
#pragma unroll
      for (int nt = 0; nt < 4; nt++)
        acc[mt][nt] = __builtin_amdgcn_mfma_f32_16x16x32_bf16(af[mt], bfr[nt], acc[mt][nt], 0, 0, 0);
  }
#pragma unroll
  for (int mt = 0; mt < 4; mt++)
#pragma unroll
    for (int r = 0; r < 4; r++){
      int row = m0 + wm + mt * 16 + quad * 4 + r;
      float invL = 1.f / rowsum[row];
#pragma unroll
      for (int nt = 0; nt < 4; nt++){
        int col = d0 + wn + nt * 16 + l16;
        size_t idx = (size_t)row * CDIM + col;
        float v = acc[mt][nt][r] * invL + b2f(planes[idx]) + b2f(planes[(size_t)S_LEN * CDIM + idx]);
        attnS[idx] = f2bf(v);
      }
    }
}

extern "C" void kernel_launch(void* const* d_in, const int* in_sizes, int n_in,
                              void* d_out, int out_size, void* d_ws, size_t ws_size,
                              hipStream_t stream){
  const float* hs  = (const float*)d_in[0];
  const int* mask  = (const int*)d_in[1];
  const int* inp   = (const int*)d_in[2];
  char* ws = (char*)d_ws;
  int*            labels  = (int*)(ws + 0);
  int*            boff    = (int*)(ws + 16384);
  int*            cnt     = (int*)(ws + 16640);
  int*            perm    = (int*)(ws + 16896);
  int*            inv     = (int*)(ws + 33280);
  int*            labP    = (int*)(ws + 49664);
  int4*           qtinfo  = (int4*)(ws + 66560);
  float*          rowsum  = (float*)(ws + 67072);
  unsigned short* hsb     = (unsigned short*)(ws + 131072);
  unsigned short* Wall    = (unsigned short*)(ws + 5373952);
  unsigned short* proj    = (unsigned short*)(ws + 13565952);
  unsigned short* vT      = (unsigned short*)(ws + 60751872);
  unsigned short* planes  = (unsigned short*)(ws + 76480512);   // 2 bf16 planes = 10.5 MB
  unsigned short* Sbuf    = (unsigned short*)(ws + 86966272);   // up to 1024 tiles * 32 KB
  unsigned short* attnS   = (unsigned short*)(ws + 120520704);
  unsigned short* Wob     = Wall + 9 * 409600;
  // attn partials live in the Sbuf region (consumed by k_comb BEFORE k_ent_qk
  // overwrites Sbuf): opart = 4 x [4096][640] bf16 (21 MB), lpP = 4x8x4096 f32.
  unsigned short* opart   = Sbuf;
  float*          lpP     = (float*)(ws + 86966272 + 20971520);

  k_labels<<<16, 256, 0, stream>>>(mask, inp, labels);
  k_hist<<<1, 256, 0, stream>>>(labels, boff, cnt);
  k_perm<<<16, 256, 0, stream>>>(labels, boff, cnt, perm, inv, labP);
  k_tiles<<<1, 256, 0, stream>>>(labP, boff, qtinfo, rowsum);
  k_cvt_hs<<<(S_LEN * CDIM / 4 + 255) / 256, 256, 0, stream>>>(hs, hsb, S_LEN * CDIM);
  WPtrs wp;
  for (int i = 0; i < 10; i++) wp.w[i] = (const float*)d_in[3 + i];
  k_cvt_w<<<(10 * 409600 / 4 + 255) / 256, 256, 0, stream>>>(wp, Wall);

  // all 9 projections in one GEMM, rows scattered into bucket-permuted order
  k_gemm<0><<<dim3(45, 32), 256, 0, stream>>>(hsb, Wall, S_LEN, NPROJ, CDIM, NPROJ,
                                              inv, proj, nullptr, nullptr);
  k_transpose_v<<<dim3(64, 10, 3), 256, 0, stream>>>(proj, vT);

  // branches 1+3: 256-query 8-wave blocks + key-range split; partials + combine
  k_attn80<<<dim3(32, 8, 2), 512, 0, stream>>>(proj, vT, labP, qtinfo, opart, lpP);
  k_comb<<<dim3(2560, 2), 256, 0, stream>>>(opart, lpP, planes);

  // branch 2 (entity, d=640): GEMM-ified, P materialized bf16 per bucket
  k_ent_qk<<<dim3(32, 32), 256, 0, stream>>>(proj, labP, qtinfo, Sbuf, rowsum);
  k_ent_pv<<<dim3(5, 32), 256, 0, stream>>>(Sbuf, vT + (size_t)1 * CDIM * S_LEN,
                                            qtinfo, rowsum, planes, attnS);

  // out = attnS @ Wo^T + residual, un-permuted via perm in the epilogue
  k_gemm<1><<<dim3(5, 32), 256, 0, stream>>>(attnS, Wob, S_LEN, CDIM, CDIM, CDIM,
                                             perm, nullptr, (float*)d_out, hs);
}

// Round 10
// 402.173 us; speedup vs baseline: 1.3362x; 1.0054x over previous
//
#include <hip/hip_runtime.h>
#include <cstdint>

typedef __attribute__((ext_vector_type(8))) short bf16x8;
typedef __attribute__((ext_vector_type(4))) short bf16x4;
typedef __attribute__((ext_vector_type(4))) float f32x4;

#define S_LEN 4096
#define CDIM  640
#define NPROJ 5760

// K=16 bf16 MFMA (v_mfma_f32_16x16x16_bf16, gfx950-valid per ISA §10).
__device__ __forceinline__ f32x4 mfma16(bf16x4 a, bf16x4 b, f32x4 c){
#if defined(__HIP_DEVICE_COMPILE__) && __HIP_DEVICE_COMPILE__
  return __builtin_amdgcn_mfma_f32_16x16x16bf16_1k(a, b, c, 0, 0, 0);
#else
  (void)a; (void)b;
  return c;
#endif
}

// async global->LDS, 16B per lane; LDS dest must be wave-uniform base + lane*16
__device__ __forceinline__ void gload_lds(const unsigned short* g, unsigned short* l){
#if defined(__HIP_DEVICE_COMPILE__) && __HIP_DEVICE_COMPILE__
  __builtin_amdgcn_global_load_lds((const __attribute__((address_space(1))) unsigned int*)g,
                                   (__attribute__((address_space(3))) unsigned int*)l, 16, 0, 0);
#else
  (void)g; (void)l;
#endif
}

__device__ __forceinline__ unsigned short f2bf(float f){
  union { float f; uint32_t u; } v; v.f = f;
  uint32_t u = v.u;
  return (unsigned short)((u + 0x7fffu + ((u >> 16) & 1u)) >> 16);
}
__device__ __forceinline__ float b2f(unsigned short h){
  union { uint32_t u; float f; } v; v.u = ((uint32_t)h) << 16;
  return v.f;
}

// ---------------- labels: nearest-resize 512x512 -> 64x64, pack m | (im==0)<<8
__global__ void k_labels(const int* __restrict__ mask, const int* __restrict__ inp,
                         int* __restrict__ labels){
  int s = blockIdx.x * 256 + threadIdx.x;
  if (s >= S_LEN) return;
  int y = s >> 6, x = s & 63;
  int off = (y * 8) * 512 + x * 8;
  int m = mask[off] & 0xff;
  int o = (inp[off] == 0) ? 0x100 : 0;
  labels[s] = m | o;
}

// ---------------- bucket sort by label value (4 buckets)
__global__ void k_hist(const int* __restrict__ labels, int* __restrict__ boff, int* __restrict__ cnt){
  __shared__ int h[4];
  if (threadIdx.x < 4) h[threadIdx.x] = 0;
  __syncthreads();
  for (int s = threadIdx.x; s < S_LEN; s += 256) atomicAdd(&h[labels[s] & 3], 1);
  __syncthreads();
  if (threadIdx.x == 0){
    int a = 0;
    for (int c = 0; c < 4; c++){ boff[c] = a; a += h[c]; }
    boff[4] = a;
  }
  if (threadIdx.x < 4) cnt[threadIdx.x] = 0;
}

__global__ void k_perm(const int* __restrict__ labels, const int* __restrict__ boff,
                       int* __restrict__ cnt, int* __restrict__ perm,
                       int* __restrict__ inv, int* __restrict__ labP){
  int s = blockIdx.x * 256 + threadIdx.x;
  if (s >= S_LEN) return;
  int lab = labels[s];
  int c = lab & 3;
  int pos = boff[c] + atomicAdd(&cnt[c], 1);
  perm[pos] = s; inv[s] = pos; labP[pos] = lab;
}

// per 128-tile key ranges (shared by attn80 and entity); zero rowsum
__global__ void k_tiles(const int* __restrict__ labP, const int* __restrict__ boff,
                        int4* __restrict__ qtinfo, float* __restrict__ rowsum){
  int t = threadIdx.x;
  __shared__ int nkt[32];
  if (t < 32){
    int c0 = labP[t * 128] & 3, c1 = labP[t * 128 + 127] & 3;
    int lo = boff[c0] & ~127, hi = (boff[c1 + 1] + 127) & ~127;
    qtinfo[t].x = lo; qtinfo[t].y = hi; qtinfo[t].w = 0;
    nkt[t] = (hi - lo) >> 7;
  }
  __syncthreads();
  if (t == 0){
    int a = 0;
    for (int i = 0; i < 32; i++){ qtinfo[i].z = a; a += nkt[i]; }
  }
  for (int s = t; s < S_LEN; s += 256) rowsum[s] = 0.f;
}

// ---------------- f32 -> bf16 converts
__global__ void k_cvt_hs(const float* __restrict__ src, unsigned short* __restrict__ dst, int n){
  int idx = (blockIdx.x * 256 + threadIdx.x) * 4;
  if (idx >= n) return;
  float4 v = *(const float4*)(src + idx);
  ushort4 o;
  o.x = f2bf(v.x); o.y = f2bf(v.y); o.z = f2bf(v.z); o.w = f2bf(v.w);
  *(ushort4*)(dst + idx) = o;
}

struct WPtrs { const float* w[10]; };

__global__ void k_cvt_w(WPtrs p, unsigned short* __restrict__ dst){
  int e = (blockIdx.x * 256 + threadIdx.x) * 4;
  if (e >= 10 * 409600) return;
  int a = e / 409600, r = e % 409600;
  float sc = (a == 0 || a == 6) ? 0.11180339887498948f   // 1/sqrt(80)
           : (a == 3 ? 0.03952847075210474f : 1.0f);     // 1/sqrt(640)
  float4 v = *(const float4*)(p.w[a] + r);
  ushort4 o;
  o.x = f2bf(v.x * sc); o.y = f2bf(v.y * sc); o.z = f2bf(v.z * sc); o.w = f2bf(v.w * sc);
  *(ushort4*)(dst + e) = o;
}

// ---------------- 128x128 MFMA GEMM
// BK=64 (m97's proven K-step), pitch-64 LDS, 4x gload_lds per array per
// tile, 2 K-substeps of MFMA per stage -> half the barriers per unit K vs BK=32.
template<int EPI>
__global__ __launch_bounds__(256) void k_gemm(const unsigned short* __restrict__ A,
                                              const unsigned short* __restrict__ B,
                                              int M, int N, int K, int ldc,
                                              const int* __restrict__ rowmap,
                                              unsigned short* __restrict__ Cb,
                                              float* __restrict__ Cf,
                                              const float* __restrict__ resid){
  __shared__ __align__(16) unsigned short As[128 * 64];
  __shared__ __align__(16) unsigned short Bs[128 * 64];
  int m0 = blockIdx.y * 128, n0 = blockIdx.x * 128;
  int tid = threadIdx.x;
  int wid = tid >> 6, lane = tid & 63;
  int quad = lane >> 4, l16 = lane & 15;
  int wm = (wid >> 1) * 64, wn = (wid & 1) * 64;
  f32x4 acc[4][4];
#pragma unroll
  for (int i = 0; i < 4; i++)
#pragma unroll
    for (int j = 0; j < 4; j++) acc[i][j] = f32x4{0.f, 0.f, 0.f, 0.f};

  for (int k0 = 0; k0 < K; k0 += 64){
    __syncthreads();
#pragma unroll
    for (int u = 0; u < 4; u++){
      int c = tid + u * 256;
      int row = c >> 3, off = (c & 7) * 8;
      gload_lds(&A[(size_t)(m0 + row) * K + k0 + off], &As[c * 8]);
      gload_lds(&B[(size_t)(n0 + row) * K + k0 + off], &Bs[c * 8]);
    }
    __syncthreads();
#pragma unroll
    for (int ks = 0; ks < 2; ks++){
      bf16x8 af[4], bfr[4];
#pragma unroll
      for (int t = 0; t < 4; t++){
        af[t]  = *(const bf16x8*)(&As[(wm + t * 16 + l16) * 64 + ks * 32 + quad * 8]);
        bfr[t] = *(const bf16x8*)(&Bs[(wn + t * 16 + l16) * 64 + ks * 32 + quad * 8]);
      }
#pragma unroll
      for (int mt = 0; mt < 4; mt++)
#pragma unroll
        for (int nt = 0; nt < 4; nt++)
          acc[mt][nt] = __builtin_amdgcn_mfma_f32_16x16x32_bf16(af[mt], bfr[nt], acc[mt][nt], 0, 0, 0);
    }
  }
#pragma unroll
  for (int mt = 0; mt < 4; mt++)
#pragma unroll
    for (int nt = 0; nt < 4; nt++)
#pragma unroll
      for (int r = 0; r < 4; r++){
        int row = m0 + wm + mt * 16 + quad * 4 + r;
        int col = n0 + wn + nt * 16 + l16;
        float v = acc[mt][nt][r];
        if (EPI == 0){
          Cb[(size_t)rowmap[row] * ldc + col] = f2bf(v);
        } else {
          int ro = rowmap[row];
          Cf[(size_t)ro * ldc + col] = v + resid[(size_t)ro * ldc + col];
        }
      }
}

// ---------------- transpose the three V projections: vT[z][c][s] (permuted key index)
__global__ void k_transpose_v(const unsigned short* __restrict__ proj, unsigned short* __restrict__ vT){
  __shared__ unsigned short T[64][65];
  int z = blockIdx.z;
  int s0 = blockIdx.x * 64, c0 = blockIdx.y * 64;
  int colbase = 1280 + z * 1920 + c0;   // v:1280  v_e:3200  v_o:5120
  unsigned short* dst = vT + (size_t)z * CDIM * S_LEN;
  int tid = threadIdx.x;
  for (int i = tid; i < 64 * 64; i += 256){
    int r = i >> 6, c = i & 63;
    T[r][c] = proj[(size_t)(s0 + r) * NPROJ + colbase + c];
  }
  __syncthreads();
  for (int i = tid; i < 64 * 64; i += 256){
    int c = i >> 6, r = i & 63;
    dst[(size_t)(c0 + c) * S_LEN + s0 + r] = T[r][c];
  }
}

// ---------------- flash attention, d=80, z=0: orig, z=1: outside
// R20: 3-way key split (thirds). Grid 48x8x2 = 768 blocks = 3 blocks/CU
// resident (LDS 139.8/160 KB, VGPR 84 allows 6 waves/SIMD) -> 24 waves/CU,
// +50% latency hiding at UNCHANGED staging volume (ranges partitioned).
// Structure otherwise identical to R19 (256-query 8-wave blocks, waves 0-3
// stage K / 4-7 stage V, scratch-proof named-register staging).
#define KP 84
#define VP 76
__global__ __launch_bounds__(512, 2) void k_attn80(const unsigned short* __restrict__ proj,
                                                   const unsigned short* __restrict__ vT,
                                                   const int* __restrict__ labP,
                                                   const int4* __restrict__ qtinfo,
                                                   unsigned short* __restrict__ opart,
                                                   float* __restrict__ lpP){
  __shared__ __align__(16) unsigned short Ks[2][64 * KP];
  __shared__ __align__(16) unsigned short Vt[2][80 * VP];
  __shared__ __align__(16) int labk[2][64];
  int tid = threadIdx.x, wid = tid >> 6, lane = tid & 63;
  int quad = lane >> 4, l16 = lane & 15;
  int qt = blockIdx.x / 3, third = blockIdx.x % 3;
  int q0 = qt * 256;
  int h  = blockIdx.y;
  bool OUTSIDE = (blockIdx.z == 1);
  int qc = (OUTSIDE ? 3840 : 0) + h * 80;
  int kc = (OUTSIDE ? 4480 : 640) + h * 80;
  const unsigned short* vTb = vT + (size_t)(OUTSIDE ? 2 : 0) * CDIM * S_LEN;
  int4 qa = qtinfo[qt * 2], qb = qtinfo[qt * 2 + 1];
  int lo = min(qa.x, qb.x), hi = max(qa.y, qb.y);
  int t0 = lo >> 6, t1 = hi >> 6;
  int nt = t1 - t0;
  int ta = t0 + (nt * third) / 3;
  int tb = t0 + (nt * (third + 1)) / 3;

  // two query sets per wave (B-operand layout: lane n=l16 is the query, k=quad*4+j)
  int qrow0 = q0 + wid * 32 + l16;
  int qrow1 = qrow0 + 16;
  bf16x4 qf0[5], qf1[5];
#pragma unroll
  for (int dc = 0; dc < 5; dc++){
    qf0[dc] = *(const bf16x4*)&proj[(size_t)qrow0 * NPROJ + qc + dc * 16 + quad * 4];
    qf1[dc] = *(const bf16x4*)&proj[(size_t)qrow1 * NPROJ + qc + dc * 16 + quad * 4];
  }
  int lq0 = labP[qrow0] & 0xff, lq1 = labP[qrow1] & 0xff;

  float lp0 = 0.f, lp1 = 0.f;
  f32x4 Oc0[5], Oc1[5];
#pragma unroll
  for (int t = 0; t < 5; t++){ Oc0[t] = f32x4{0.f,0.f,0.f,0.f}; Oc1[t] = f32x4{0.f,0.f,0.f,0.f}; }

  // staging roles: waves 0-3 stage the K tile (64 rows x 20 uint2), waves 4-7
  // stage the V tile (80 rows x 16 uint2). 1280 uint2 per role over 256
  // threads = 5 units/thread; unit c = t5 + u*256. All tile-invariant.
  const bool ISK = (tid < 256);
  const int t5 = ISK ? tid : (tid - 256);
  const unsigned short* gb = ISK ? proj : vTb;
  const int km = ISK ? NPROJ : 1;                    // per-tile offset multiplier
  int ga0, ga1, ga2, ga3, ga4, ls0, ls1, ls2, ls3, ls4;
  {
    const int c0_ = t5, c1_ = t5 + 256, c2_ = t5 + 512, c3_ = t5 + 768, c4_ = t5 + 1024;
    if (ISK){
      ga0 = (c0_ / 20) * NPROJ + kc + (c0_ % 20) * 4;
      ga1 = (c1_ / 20) * NPROJ + kc + (c1_ % 20) * 4;
      ga2 = (c2_ / 20) * NPROJ + kc + (c2_ % 20) * 4;
      ga3 = (c3_ / 20) * NPROJ + kc + (c3_ % 20) * 4;
      ga4 = (c4_ / 20) * NPROJ + kc + (c4_ % 20) * 4;
      ls0 = (c0_ / 20) * KP + (c0_ % 20) * 4;
      ls1 = (c1_ / 20) * KP + (c1_ % 20) * 4;
      ls2 = (c2_ / 20) * KP + (c2_ % 20) * 4;
      ls3 = (c3_ / 20) * KP + (c3_ % 20) * 4;
      ls4 = (c4_ / 20) * KP + (c4_ % 20) * 4;
    } else {
      ga0 = (h * 80 + (c0_ >> 4)) * S_LEN + (c0_ & 15) * 4;
      ga1 = (h * 80 + (c1_ >> 4)) * S_LEN + (c1_ & 15) * 4;
      ga2 = (h * 80 + (c2_ >> 4)) * S_LEN + (c2_ & 15) * 4;
      ga3 = (h * 80 + (c3_ >> 4)) * S_LEN + (c3_ & 15) * 4;
      ga4 = (h * 80 + (c4_ >> 4)) * S_LEN + (c4_ & 15) * 4;
      ls0 = (c0_ >> 4) * VP + (c0_ & 15) * 4;
      ls1 = (c1_ >> 4) * VP + (c1_ & 15) * 4;
      ls2 = (c2_ >> 4) * VP + (c2_ & 15) * 4;
      ls3 = (c3_ >> 4) * VP + (c3_ & 15) * 4;
      ls4 = (c4_ >> 4) * VP + (c4_ & 15) * 4;
    }
  }

  uint2 r0, r1, r2, r3, r4;
  int lreg = 0;

#define LOADT(kt_) do {                                              \
    size_t _ob = (size_t)((kt_) * 64) * (size_t)km;                  \
    r0 = *(const uint2*)&gb[_ob + ga0];                              \
    r1 = *(const uint2*)&gb[_ob + ga1];                              \
    r2 = *(const uint2*)&gb[_ob + ga2];                              \
    r3 = *(const uint2*)&gb[_ob + ga3];                              \
    r4 = *(const uint2*)&gb[_ob + ga4];                              \
    if (tid < 64) lreg = labP[(kt_) * 64 + tid];                     \
  } while (0)

#define WRITET(b) do {                                               \
    unsigned short* _lb = ISK ? Ks[b] : Vt[b];                       \
    *(uint2*)&_lb[ls0] = r0;                                         \
    *(uint2*)&_lb[ls1] = r1;                                         \
    *(uint2*)&_lb[ls2] = r2;                                         \
    *(uint2*)&_lb[ls3] = r3;                                         \
    *(uint2*)&_lb[ls4] = r4;                                         \
    if (tid < 64) labk[b][tid] = lreg;                               \
  } while (0)

  if (ta < tb){
    // prologue: stage tile ta into buf0, issue loads for ta+1
    LOADT(ta);
    WRITET(0);
    if (ta + 1 < tb) LOADT(ta + 1);
    __syncthreads();

    int cur = 0;
    for (int kt = ta; kt < tb; kt++){
      int nxt = cur ^ 1;
      // regs hold tile kt+1: write it to the other buffer (its readers finished
      // at the barrier that ended iteration kt-1), then issue loads for kt+2.
      if (kt + 1 < tb){
        WRITET(nxt);
        if (kt + 2 < tb) LOADT(kt + 2);
      }

#pragma unroll
      for (int kg = 0; kg < 4; kg++){
        // S^T(16 keys x 16 queries) = K * Q^T, two query sets share kf
        f32x4 sa0 = f32x4{0.f,0.f,0.f,0.f}, sa1 = f32x4{0.f,0.f,0.f,0.f};
#pragma unroll
        for (int dc = 0; dc < 5; dc++){
          bf16x4 kf = *(const bf16x4*)&Ks[cur][(kg * 16 + l16) * KP + dc * 16 + quad * 4];
          sa0 = mfma16(kf, qf0[dc], sa0);
          sa1 = mfma16(kf, qf1[dc], sa1);
        }
        int4 lk4 = *(const int4*)&labk[cur][kg * 16 + quad * 4];
        bool m0 = !OUTSIDE || (lk4.x & 0x100), m1 = !OUTSIDE || (lk4.y & 0x100);
        bool m2 = !OUTSIDE || (lk4.z & 0x100), m3 = !OUTSIDE || (lk4.w & 0x100);
        int k0l = lk4.x & 0xff, k1l = lk4.y & 0xff, k2l = lk4.z & 0xff, k3l = lk4.w & 0xff;
        bf16x4 pf0, pf1;
        {
          float p0 = (k0l == lq0 && m0) ? __expf(sa0[0]) : 0.f;
          float p1 = (k1l == lq0 && m1) ? __expf(sa0[1]) : 0.f;
          float p2 = (k2l == lq0 && m2) ? __expf(sa0[2]) : 0.f;
          float p3 = (k3l == lq0 && m3) ? __expf(sa0[3]) : 0.f;
          lp0 += (p0 + p1) + (p2 + p3);
          pf0[0] = (short)f2bf(p0); pf0[1] = (short)f2bf(p1);
          pf0[2] = (short)f2bf(p2); pf0[3] = (short)f2bf(p3);
        }
        {
          float p0 = (k0l == lq1 && m0) ? __expf(sa1[0]) : 0.f;
          float p1 = (k1l == lq1 && m1) ? __expf(sa1[1]) : 0.f;
          float p2 = (k2l == lq1 && m2) ? __expf(sa1[2]) : 0.f;
          float p3 = (k3l == lq1 && m3) ? __expf(sa1[3]) : 0.f;
          lp1 += (p0 + p1) + (p2 + p3);
          pf1[0] = (short)f2bf(p0); pf1[1] = (short)f2bf(p1);
          pf1[2] = (short)f2bf(p2); pf1[3] = (short)f2bf(p3);
        }
        // O^T += V^T * P^T, two query sets share vf
#pragma unroll
        for (int dt = 0; dt < 5; dt++){
          bf16x4 vf = *(const bf16x4*)&Vt[cur][(dt * 16 + l16) * VP + kg * 16 + quad * 4];
          Oc0[dt] = mfma16(vf, pf0, Oc0[dt]);
          Oc1[dt] = mfma16(vf, pf1, Oc1[dt]);
        }
      }
      __syncthreads();   // all reads of cur done; writes of nxt visible
      cur = nxt;
    }
  }
#undef LOADT
#undef WRITET
  // row-sums: reduce across quads (same l16); write UNNORMALIZED partials
  lp0 += __shfl_xor(lp0, 16); lp0 += __shfl_xor(lp0, 32);
  lp1 += __shfl_xor(lp1, 16); lp1 += __shfl_xor(lp1, 32);
  int hz = third * 2 + (int)blockIdx.z;
  if (quad == 0){
    lpP[(size_t)(hz * 8 + h) * S_LEN + qrow0] = lp0;
    lpP[(size_t)(hz * 8 + h) * S_LEN + qrow1] = lp1;
  }
  unsigned short* dst = opart + (size_t)hz * S_LEN * CDIM;
#pragma unroll
  for (int dt = 0; dt < 5; dt++){
    ushort4 o;
    o.x = f2bf(Oc0[dt][0]); o.y = f2bf(Oc0[dt][1]);
    o.z = f2bf(Oc0[dt][2]); o.w = f2bf(Oc0[dt][3]);
    *(ushort4*)&dst[(size_t)qrow0 * CDIM + h * 80 + dt * 16 + quad * 4] = o;
    o.x = f2bf(Oc1[dt][0]); o.y = f2bf(Oc1[dt][1]);
    o.z = f2bf(Oc1[dt][2]); o.w = f2bf(Oc1[dt][3]);
    *(ushort4*)&dst[(size_t)qrow1 * CDIM + h * 80 + dt * 16 + quad * 4] = o;
  }
}

// ---------------- combine: planes[z] = sum of 3 partial O / sum of 3 partial lp
__global__ __launch_bounds__(256) void k_comb(const unsigned short* __restrict__ opart,
                                              const float* __restrict__ lpP,
                                              unsigned short* __restrict__ planes){
  int i = blockIdx.x * 256 + threadIdx.x;          // 4096*160 items per z
  int z = blockIdx.y;
  int qrow = i / 160, c4 = (i % 160) * 4;
  int h = c4 / 80;                                  // 80 % 4 == 0: one h per ushort4
  size_t base = (size_t)qrow * CDIM + c4;
  size_t pz = (size_t)S_LEN * CDIM;
  float lp = lpP[(size_t)((z)     * 8 + h) * S_LEN + qrow]
           + lpP[(size_t)((z + 2) * 8 + h) * S_LEN + qrow]
           + lpP[(size_t)((z + 4) * 8 + h) * S_LEN + qrow];
  float iL = 1.f / lp;
  ushort4 a = *(const ushort4*)&opart[(size_t)(z)     * pz + base];
  ushort4 b = *(const ushort4*)&opart[(size_t)(z + 2) * pz + base];
  ushort4 c = *(const ushort4*)&opart[(size_t)(z + 4) * pz + base];
  ushort4 o;
  o.x = f2bf((b2f(a.x) + b2f(b.x) + b2f(c.x)) * iL);
  o.y = f2bf((b2f(a.y) + b2f(b.y) + b2f(c.y)) * iL);
  o.z = f2bf((b2f(a.z) + b2f(b.z) + b2f(c.z)) * iL);
  o.w = f2bf((b2f(a.w) + b2f(b.w) + b2f(c.w)) * iL);
  *(ushort4*)&planes[(size_t)z * pz + base] = o;
}

// ---------------- entity E1: P = exp(Q_e K_e^T) per (qtile, ktile), bf16, + rowsums
// BK=64 staging (same pattern as k_gemm); __expf kept.
__global__ __launch_bounds__(256) void k_ent_qk(const unsigned short* __restrict__ proj,
                                                const int* __restrict__ labP,
                                                const int4* __restrict__ qtinfo,
                                                unsigned short* __restrict__ Sbuf,
                                                float* __restrict__ rowsum){
  int qt = blockIdx.y;
  int4 qi = qtinfo[qt];
  int nkt = (qi.y - qi.x) >> 7;
  if ((int)blockIdx.x >= nkt) return;
  int m0 = qt * 128, n0 = qi.x + blockIdx.x * 128;
  __shared__ __align__(16) unsigned short As[128 * 64];
  __shared__ __align__(16) unsigned short Bs[128 * 64];
  __shared__ int lQ[128], lK[128];
  int tid = threadIdx.x, wid = tid >> 6, lane = tid & 63;
  int quad = lane >> 4, l16 = lane & 15;
  int wm = (wid >> 1) * 64, wn = (wid & 1) * 64;
  if (tid < 128) lQ[tid] = labP[m0 + tid] & 0xff;
  else           lK[tid - 128] = labP[n0 + tid - 128] & 0xff;
  f32x4 acc[4][4];
#pragma unroll
  for (int i = 0; i < 4; i++)
#pragma unroll
    for (int j = 0; j < 4; j++) acc[i][j] = f32x4{0.f, 0.f, 0.f, 0.f};

  for (int k0 = 0; k0 < 640; k0 += 64){
    __syncthreads();
#pragma unroll
    for (int u = 0; u < 4; u++){
      int c = tid + u * 256;
      int row = c >> 3, off = (c & 7) * 8;
      gload_lds(&proj[(size_t)(m0 + row) * NPROJ + 1920 + k0 + off], &As[c * 8]);
      gload_lds(&proj[(size_t)(n0 + row) * NPROJ + 2560 + k0 + off], &Bs[c * 8]);
    }
    __syncthreads();
#pragma unroll
    for (int ks = 0; ks < 2; ks++){
      bf16x8 af[4], bfr[4];
#pragma unroll
      for (int t = 0; t < 4; t++){
        af[t]  = *(const bf16x8*)(&As[(wm + t * 16 + l16) * 64 + ks * 32 + quad * 8]);
        bfr[t] = *(const bf16x8*)(&Bs[(wn + t * 16 + l16) * 64 + ks * 32 + quad * 8]);
      }
#pragma unroll
      for (int mt = 0; mt < 4; mt++)
#pragma unroll
        for (int nt = 0; nt < 4; nt++)
          acc[mt][nt] = __builtin_amdgcn_mfma_f32_16x16x32_bf16(af[mt], bfr[nt], acc[mt][nt], 0, 0, 0);
    }
  }
  unsigned short* St = Sbuf + ((size_t)(qi.z + blockIdx.x)) * 16384;
#pragma unroll
  for (int mt = 0; mt < 4; mt++)
#pragma unroll
    for (int r = 0; r < 4; r++){
      int lrow = wm + mt * 16 + quad * 4 + r;
      int myq = lQ[lrow];
      float psum = 0.f;
#pragma unroll
      for (int nt = 0; nt < 4; nt++){
        int lcol = wn + nt * 16 + l16;
        float p = (myq == lK[lcol]) ? __expf(acc[mt][nt][r]) : 0.f;
        St[lrow * 128 + lcol] = f2bf(p);
        psum += p;
      }
#pragma unroll
      for (int m = 1; m < 16; m <<= 1) psum += __shfl_xor(psum, m);
      if (l16 == 0) atomicAdd(&rowsum[m0 + lrow], psum);
    }
}

// ---------------- entity E2: attnS = bf16( P·V_e / rowsum + plane0 + plane1 )
// R20: BK=64 (was BK=32 -- missed in the R15 upgrade; halves barrier count
// over the nk~1088 K-loop). Same proven staging pattern as k_gemm/k_ent_qk.
__global__ __launch_bounds__(256) void k_ent_pv(const unsigned short* __restrict__ Sbuf,
                                                const unsigned short* __restrict__ veT,
                                                const int4* __restrict__ qtinfo,
                                                const float* __restrict__ rowsum,
                                                const unsigned short* __restrict__ planes,
                                                unsigned short* __restrict__ attnS){
  int qt = blockIdx.y, d0 = blockIdx.x * 128;
  int4 qi = qtinfo[qt];
  int m0 = qt * 128;
  int nk = qi.y - qi.x;
  __shared__ __align__(16) unsigned short As[128 * 64];
  __shared__ __align__(16) unsigned short Bs[128 * 64];
  int tid = threadIdx.x, wid = tid >> 6, lane = tid & 63;
  int quad = lane >> 4, l16 = lane & 15;
  int wm = (wid >> 1) * 64, wn = (wid & 1) * 64;
  f32x4 acc[4][4];
#pragma unroll
  for (int i = 0; i < 4; i++)
#pragma unroll
    for (int j = 0; j < 4; j++) acc[i][j] = f32x4{0.f, 0.f, 0.f, 0.f};

  for (int kk = 0; kk < nk; kk += 64){
    const unsigned short* St = Sbuf + ((size_t)(qi.z + (kk >> 7))) * 16384;
    int kloc = kk & 127;
    __syncthreads();
#pragma unroll
    for (int u = 0; u < 4; u++){
      int c = tid + u * 256;
      int row = c >> 3, off = (c & 7) * 8;
      gload_lds(&St[row * 128 + kloc + off], &As[c * 8]);
      gload_lds(&veT[(size_t)(d0 + row) * S_LEN + qi.x + kk + off], &Bs[c * 8]);
    }
    __syncthreads();
#pragma unroll
    for (int ks = 0; ks < 2; ks++){
      bf16x8 af[4], bfr[4];
#pragma unroll
      for (int t = 0; t < 4; t++){
        af[t]  = *(const bf16x8*)(&As[(wm + t * 16 + l16) * 64 + ks * 32 + quad * 8]);
        bfr[t] = *(const bf16x8*)(&Bs[(wn + t * 16 + l16) * 64 + ks * 32 + quad * 8]);
      }
#pragma unroll
      for (int mt = 0; mt < 4; mt++)
#pragma unroll
        for (int nt = 0; nt < 4; nt++)
          acc[mt][nt] = __builtin_amdgcn_mfma_f32_16x16x32_bf16(af[mt], bfr[nt], acc[mt][nt], 0, 0, 0);
    }
  }
#pragma unroll
  for (int mt = 0; mt < 4; mt++)
#pragma unroll
    for (int r = 0; r < 4; r++){
      int row = m0 + wm + mt * 16 + quad * 4 + r;
      float invL = 1.f / rowsum[row];
#pragma unroll
      for (int nt = 0; nt < 4; nt++){
        int col = d0 + wn + nt * 16 + l16;
        size_t idx = (size_t)row * CDIM + col;
        float v = acc[mt][nt][r] * invL + b2f(planes[idx]) + b2f(planes[(size_t)S_LEN * CDIM + idx]);
        attnS[idx] = f2bf(v);
      }
    }
}

extern "C" void kernel_launch(void* const* d_in, const int* in_sizes, int n_in,
                              void* d_out, int out_size, void* d_ws, size_t ws_size,
                              hipStream_t stream){
  const float* hs  = (const float*)d_in[0];
  const int* mask  = (const int*)d_in[1];
  const int* inp   = (const int*)d_in[2];
  char* ws = (char*)d_ws;
  int*            labels  = (int*)(ws + 0);
  int*            boff    = (int*)(ws + 16384);
  int*            cnt     = (int*)(ws + 16640);
  int*            perm    = (int*)(ws + 16896);
  int*            inv     = (int*)(ws + 33280);
  int*            labP    = (int*)(ws + 49664);
  int4*           qtinfo  = (int4*)(ws + 66560);
  float*          rowsum  = (float*)(ws + 67072);
  unsigned short* hsb     = (unsigned short*)(ws + 131072);
  unsigned short* Wall    = (unsigned short*)(ws + 5373952);
  unsigned short* proj    = (unsigned short*)(ws + 13565952);
  unsigned short* vT      = (unsigned short*)(ws + 60751872);
  unsigned short* planes  = (unsigned short*)(ws + 76480512);   // 2 bf16 planes = 10.5 MB
  unsigned short* Sbuf    = (unsigned short*)(ws + 86966272);   // up to 1024 tiles * 32 KB
  unsigned short* attnS   = (unsigned short*)(ws + 120520704);
  unsigned short* Wob     = Wall + 9 * 409600;
  // attn partials live in the Sbuf region (consumed by k_comb BEFORE k_ent_qk
  // overwrites Sbuf): opart = 6 x [4096][640] bf16 (31.5 MB), lpP = 6x8x4096 f32.
  unsigned short* opart   = Sbuf;
  float*          lpP     = (float*)(ws + 86966272 + 31457280);

  k_labels<<<16, 256, 0, stream>>>(mask, inp, labels);
  k_hist<<<1, 256, 0, stream>>>(labels, boff, cnt);
  k_perm<<<16, 256, 0, stream>>>(labels, boff, cnt, perm, inv, labP);
  k_tiles<<<1, 256, 0, stream>>>(labP, boff, qtinfo, rowsum);
  k_cvt_hs<<<(S_LEN * CDIM / 4 + 255) / 256, 256, 0, stream>>>(hs, hsb, S_LEN * CDIM);
  WPtrs wp;
  for (int i = 0; i < 10; i++) wp.w[i] = (const float*)d_in[3 + i];
  k_cvt_w<<<(10 * 409600 / 4 + 255) / 256, 256, 0, stream>>>(wp, Wall);

  // all 9 projections in one GEMM, rows scattered into bucket-permuted order
  k_gemm<0><<<dim3(45, 32), 256, 0, stream>>>(hsb, Wall, S_LEN, NPROJ, CDIM, NPROJ,
                                              inv, proj, nullptr, nullptr);
  k_transpose_v<<<dim3(64, 10, 3), 256, 0, stream>>>(proj, vT);

  // branches 1+3: 256-query 8-wave blocks + 3-way key split; partials + combine
  k_attn80<<<dim3(48, 8, 2), 512, 0, stream>>>(proj, vT, labP, qtinfo, opart, lpP);
  k_comb<<<dim3(2560, 2), 256, 0, stream>>>(opart, lpP, planes);

  // branch 2 (entity, d=640): GEMM-ified, P materialized bf16 per bucket
  k_ent_qk<<<dim3(32, 32), 256, 0, stream>>>(proj, labP, qtinfo, Sbuf, rowsum);
  k_ent_pv<<<dim3(5, 32), 256, 0, stream>>>(Sbuf, vT + (size_t)1 * CDIM * S_LEN,
                                            qtinfo, rowsum, planes, attnS);

  // out = attnS @ Wo^T + residual, un-permuted via perm in the epilogue
  k_gemm<1><<<dim3(5, 32), 256, 0, stream>>>(attnS, Wob, S_LEN, CDIM, CDIM, CDIM,
                                             perm, nullptr, (float*)d_out, hs);
}

// Round 11
// 375.740 us; speedup vs baseline: 1.4302x; 1.0703x over previous
//
#include <hip/hip_runtime.h>
#include <cstdint>

typedef __attribute__((ext_vector_type(8))) short bf16x8;
typedef __attribute__((ext_vector_type(4))) short bf16x4;
typedef __attribute__((ext_vector_type(4))) float f32x4;

#define S_LEN 4096
#define CDIM  640
#define NPROJ 5760

// K=16 bf16 MFMA (v_mfma_f32_16x16x16_bf16, gfx950-valid per ISA §10).
__device__ __forceinline__ f32x4 mfma16(bf16x4 a, bf16x4 b, f32x4 c){
#if defined(__HIP_DEVICE_COMPILE__) && __HIP_DEVICE_COMPILE__
  return __builtin_amdgcn_mfma_f32_16x16x16bf16_1k(a, b, c, 0, 0, 0);
#else
  (void)a; (void)b;
  return c;
#endif
}

// async global->LDS, 16B per lane; LDS dest must be wave-uniform base + lane*16
__device__ __forceinline__ void gload_lds(const unsigned short* g, unsigned short* l){
#if defined(__HIP_DEVICE_COMPILE__) && __HIP_DEVICE_COMPILE__
  __builtin_amdgcn_global_load_lds((const __attribute__((address_space(1))) unsigned int*)g,
                                   (__attribute__((address_space(3))) unsigned int*)l, 16, 0, 0);
#else
  (void)g; (void)l;
#endif
}

__device__ __forceinline__ unsigned short f2bf(float f){
  union { float f; uint32_t u; } v; v.f = f;
  uint32_t u = v.u;
  return (unsigned short)((u + 0x7fffu + ((u >> 16) & 1u)) >> 16);
}
__device__ __forceinline__ float b2f(unsigned short h){
  union { uint32_t u; float f; } v; v.u = ((uint32_t)h) << 16;
  return v.f;
}

// ---------------- R21: fused prologue (was k_labels/k_hist/k_perm/k_tiles).
// One block, 1024 threads; __syncthreads orders the global-memory phases that
// separate launches ordered before. LDS histogram/offsets replace global boff/cnt.
__global__ __launch_bounds__(1024) void k_prep(const int* __restrict__ mask,
                                               const int* __restrict__ inp,
                                               int* __restrict__ labels,
                                               int* __restrict__ perm,
                                               int* __restrict__ inv,
                                               int* __restrict__ labP,
                                               int4* __restrict__ qtinfo,
                                               float* __restrict__ rowsum){
  __shared__ int h[4], base[5], cnt4[4], nkt[32];
  int t = threadIdx.x;
  if (t < 4){ h[t] = 0; cnt4[t] = 0; }
  __syncthreads();
  // labels + histogram
  for (int s = t; s < S_LEN; s += 1024){
    int y = s >> 6, x = s & 63;
    int off = (y * 8) * 512 + x * 8;
    int m = mask[off] & 0xff;
    int o = (inp[off] == 0) ? 0x100 : 0;
    labels[s] = m | o;
    atomicAdd(&h[m & 3], 1);
  }
  __syncthreads();
  if (t == 0){
    int a = 0;
    for (int c = 0; c < 4; c++){ base[c] = a; a += h[c]; }
    base[4] = a;
  }
  __syncthreads();
  // bucket-sort permutation (arrival order within bucket, same as before)
  for (int s = t; s < S_LEN; s += 1024){
    int lab = labels[s];
    int c = lab & 3;
    int pos = base[c] + atomicAdd(&cnt4[c], 1);
    perm[pos] = s; inv[s] = pos; labP[pos] = lab;
  }
  __syncthreads();   // labP globally visible within block
  // per-128-tile key ranges
  if (t < 32){
    int c0 = labP[t * 128] & 3, c1 = labP[t * 128 + 127] & 3;
    int lo = base[c0] & ~127, hi = (base[c1 + 1] + 127) & ~127;
    qtinfo[t].x = lo; qtinfo[t].y = hi; qtinfo[t].w = 0;
    nkt[t] = (hi - lo) >> 7;
  }
  __syncthreads();
  if (t == 0){
    int a = 0;
    for (int i = 0; i < 32; i++){ qtinfo[i].z = a; a += nkt[i]; }
  }
  for (int s = t; s < S_LEN; s += 1024) rowsum[s] = 0.f;
}

// ---------------- f32 -> bf16 converts
__global__ void k_cvt_hs(const float* __restrict__ src, unsigned short* __restrict__ dst, int n){
  int idx = (blockIdx.x * 256 + threadIdx.x) * 4;
  if (idx >= n) return;
  float4 v = *(const float4*)(src + idx);
  ushort4 o;
  o.x = f2bf(v.x); o.y = f2bf(v.y); o.z = f2bf(v.z); o.w = f2bf(v.w);
  *(ushort4*)(dst + idx) = o;
}

struct WPtrs { const float* w[10]; };

__global__ void k_cvt_w(WPtrs p, unsigned short* __restrict__ dst){
  int e = (blockIdx.x * 256 + threadIdx.x) * 4;
  if (e >= 10 * 409600) return;
  int a = e / 409600, r = e % 409600;
  float sc = (a == 0 || a == 6) ? 0.11180339887498948f   // 1/sqrt(80)
           : (a == 3 ? 0.03952847075210474f : 1.0f);     // 1/sqrt(640)
  float4 v = *(const float4*)(p.w[a] + r);
  ushort4 o;
  o.x = f2bf(v.x * sc); o.y = f2bf(v.y * sc); o.z = f2bf(v.z * sc); o.w = f2bf(v.w * sc);
  *(ushort4*)(dst + e) = o;
}

// ---------------- 128x128 MFMA GEMM
// BK=64 (m97's proven K-step), pitch-64 LDS, 4x gload_lds per array per
// tile, 2 K-substeps of MFMA per stage -> half the barriers per unit K vs BK=32.
template<int EPI>
__global__ __launch_bounds__(256) void k_gemm(const unsigned short* __restrict__ A,
                                              const unsigned short* __restrict__ B,
                                              int M, int N, int K, int ldc,
                                              const int* __restrict__ rowmap,
                                              unsigned short* __restrict__ Cb,
                                              float* __restrict__ Cf,
                                              const float* __restrict__ resid){
  __shared__ __align__(16) unsigned short As[128 * 64];
  __shared__ __align__(16) unsigned short Bs[128 * 64];
  int m0 = blockIdx.y * 128, n0 = blockIdx.x * 128;
  int tid = threadIdx.x;
  int wid = tid >> 6, lane = tid & 63;
  int quad = lane >> 4, l16 = lane & 15;
  int wm = (wid >> 1) * 64, wn = (wid & 1) * 64;
  f32x4 acc[4][4];
#pragma unroll
  for (int i = 0; i < 4; i++)
#pragma unroll
    for (int j = 0; j < 4; j++) acc[i][j] = f32x4{0.f, 0.f, 0.f, 0.f};

  for (int k0 = 0; k0 < K; k0 += 64){
    __syncthreads();
#pragma unroll
    for (int u = 0; u < 4; u++){
      int c = tid + u * 256;
      int row = c >> 3, off = (c & 7) * 8;
      gload_lds(&A[(size_t)(m0 + row) * K + k0 + off], &As[c * 8]);
      gload_lds(&B[(size_t)(n0 + row) * K + k0 + off], &Bs[c * 8]);
    }
    __syncthreads();
#pragma unroll
    for (int ks = 0; ks < 2; ks++){
      bf16x8 af[4], bfr[4];
#pragma unroll
      for (int t = 0; t < 4; t++){
        af[t]  = *(const bf16x8*)(&As[(wm + t * 16 + l16) * 64 + ks * 32 + quad * 8]);
        bfr[t] = *(const bf16x8*)(&Bs[(wn + t * 16 + l16) * 64 + ks * 32 + quad * 8]);
      }
#pragma unroll
      for (int mt = 0; mt < 4; mt++)
#pragma unroll
        for (int nt = 0; nt < 4; nt++)
          acc[mt][nt] = __builtin_amdgcn_mfma_f32_16x16x32_bf16(af[mt], bfr[nt], acc[mt][nt], 0, 0, 0);
    }
  }
#pragma unroll
  for (int mt = 0; mt < 4; mt++)
#pragma unroll
    for (int nt = 0; nt < 4; nt++)
#pragma unroll
      for (int r = 0; r < 4; r++){
        int row = m0 + wm + mt * 16 + quad * 4 + r;
        int col = n0 + wn + nt * 16 + l16;
        float v = acc[mt][nt][r];
        if (EPI == 0){
          Cb[(size_t)rowmap[row] * ldc + col] = f2bf(v);
        } else {
          int ro = rowmap[row];
          Cf[(size_t)ro * ldc + col] = v + resid[(size_t)ro * ldc + col];
        }
      }
}

// ---------------- transpose the three V projections: vT[z][c][s]
// R21: uint2-vectorized both sides (was scalar bf16 -- Common-mistake #2).
// Load: 4 bf16 per access along the row; store: pack 4 consecutive rows of one
// column into one 8B write. LDS pitch 68 keeps 8B alignment (136B rows).
__global__ void k_transpose_v(const unsigned short* __restrict__ proj, unsigned short* __restrict__ vT){
  __shared__ unsigned short T[64][68];
  int z = blockIdx.z;
  int s0 = blockIdx.x * 64, c0 = blockIdx.y * 64;
  int colbase = 1280 + z * 1920 + c0;   // v:1280  v_e:3200  v_o:5120
  unsigned short* dst = vT + (size_t)z * CDIM * S_LEN;
  int tid = threadIdx.x;
#pragma unroll
  for (int u = 0; u < 4; u++){
    int i = tid + u * 256;               // 1024 uint2 units: r = i>>4, c4 = (i&15)*4
    int r = i >> 4, c4 = (i & 15) * 4;
    uint2 v = *(const uint2*)&proj[(size_t)(s0 + r) * NPROJ + colbase + c4];
    *(uint2*)&T[r][c4] = v;
  }
  __syncthreads();
#pragma unroll
  for (int u = 0; u < 4; u++){
    int j = tid + u * 256;               // c = j>>4, r4 = (j&15)*4
    int c = j >> 4, r4 = (j & 15) * 4;
    ushort4 o;
    o.x = T[r4 + 0][c]; o.y = T[r4 + 1][c];
    o.z = T[r4 + 2][c]; o.w = T[r4 + 3][c];
    *(ushort4*)&dst[(size_t)(c0 + c) * S_LEN + s0 + r4] = o;
  }
}

// ---------------- flash attention, d=80, z=0: orig, z=1: outside
// R20 config (structural floor per decision rule): 3-way key split, 256-query
// 8-wave blocks, waves 0-3 stage K / 4-7 stage V, scratch-proof staging.
#define KP 84
#define VP 76
__global__ __launch_bounds__(512, 2) void k_attn80(const unsigned short* __restrict__ proj,
                                                   const unsigned short* __restrict__ vT,
                                                   const int* __restrict__ labP,
                                                   const int4* __restrict__ qtinfo,
                                                   unsigned short* __restrict__ opart,
                                                   float* __restrict__ lpP){
  __shared__ __align__(16) unsigned short Ks[2][64 * KP];
  __shared__ __align__(16) unsigned short Vt[2][80 * VP];
  __shared__ __align__(16) int labk[2][64];
  int tid = threadIdx.x, wid = tid >> 6, lane = tid & 63;
  int quad = lane >> 4, l16 = lane & 15;
  int qt = blockIdx.x / 3, third = blockIdx.x % 3;
  int q0 = qt * 256;
  int h  = blockIdx.y;
  bool OUTSIDE = (blockIdx.z == 1);
  int qc = (OUTSIDE ? 3840 : 0) + h * 80;
  int kc = (OUTSIDE ? 4480 : 640) + h * 80;
  const unsigned short* vTb = vT + (size_t)(OUTSIDE ? 2 : 0) * CDIM * S_LEN;
  int4 qa = qtinfo[qt * 2], qb = qtinfo[qt * 2 + 1];
  int lo = min(qa.x, qb.x), hi = max(qa.y, qb.y);
  int t0 = lo >> 6, t1 = hi >> 6;
  int nt = t1 - t0;
  int ta = t0 + (nt * third) / 3;
  int tb = t0 + (nt * (third + 1)) / 3;

  // two query sets per wave (B-operand layout: lane n=l16 is the query, k=quad*4+j)
  int qrow0 = q0 + wid * 32 + l16;
  int qrow1 = qrow0 + 16;
  bf16x4 qf0[5], qf1[5];
#pragma unroll
  for (int dc = 0; dc < 5; dc++){
    qf0[dc] = *(const bf16x4*)&proj[(size_t)qrow0 * NPROJ + qc + dc * 16 + quad * 4];
    qf1[dc] = *(const bf16x4*)&proj[(size_t)qrow1 * NPROJ + qc + dc * 16 + quad * 4];
  }
  int lq0 = labP[qrow0] & 0xff, lq1 = labP[qrow1] & 0xff;

  float lp0 = 0.f, lp1 = 0.f;
  f32x4 Oc0[5], Oc1[5];
#pragma unroll
  for (int t = 0; t < 5; t++){ Oc0[t] = f32x4{0.f,0.f,0.f,0.f}; Oc1[t] = f32x4{0.f,0.f,0.f,0.f}; }

  // staging roles: waves 0-3 stage the K tile (64 rows x 20 uint2), waves 4-7
  // stage the V tile (80 rows x 16 uint2). 1280 uint2 per role over 256
  // threads = 5 units/thread; unit c = t5 + u*256. All tile-invariant.
  const bool ISK = (tid < 256);
  const int t5 = ISK ? tid : (tid - 256);
  const unsigned short* gb = ISK ? proj : vTb;
  const int km = ISK ? NPROJ : 1;                    // per-tile offset multiplier
  int ga0, ga1, ga2, ga3, ga4, ls0, ls1, ls2, ls3, ls4;
  {
    const int c0_ = t5, c1_ = t5 + 256, c2_ = t5 + 512, c3_ = t5 + 768, c4_ = t5 + 1024;
    if (ISK){
      ga0 = (c0_ / 20) * NPROJ + kc + (c0_ % 20) * 4;
      ga1 = (c1_ / 20) * NPROJ + kc + (c1_ % 20) * 4;
      ga2 = (c2_ / 20) * NPROJ + kc + (c2_ % 20) * 4;
      ga3 = (c3_ / 20) * NPROJ + kc + (c3_ % 20) * 4;
      ga4 = (c4_ / 20) * NPROJ + kc + (c4_ % 20) * 4;
      ls0 = (c0_ / 20) * KP + (c0_ % 20) * 4;
      ls1 = (c1_ / 20) * KP + (c1_ % 20) * 4;
      ls2 = (c2_ / 20) * KP + (c2_ % 20) * 4;
      ls3 = (c3_ / 20) * KP + (c3_ % 20) * 4;
      ls4 = (c4_ / 20) * KP + (c4_ % 20) * 4;
    } else {
      ga0 = (h * 80 + (c0_ >> 4)) * S_LEN + (c0_ & 15) * 4;
      ga1 = (h * 80 + (c1_ >> 4)) * S_LEN + (c1_ & 15) * 4;
      ga2 = (h * 80 + (c2_ >> 4)) * S_LEN + (c2_ & 15) * 4;
      ga3 = (h * 80 + (c3_ >> 4)) * S_LEN + (c3_ & 15) * 4;
      ga4 = (h * 80 + (c4_ >> 4)) * S_LEN + (c4_ & 15) * 4;
      ls0 = (c0_ >> 4) * VP + (c0_ & 15) * 4;
      ls1 = (c1_ >> 4) * VP + (c1_ & 15) * 4;
      ls2 = (c2_ >> 4) * VP + (c2_ & 15) * 4;
      ls3 = (c3_ >> 4) * VP + (c3_ & 15) * 4;
      ls4 = (c4_ >> 4) * VP + (c4_ & 15) * 4;
    }
  }

  uint2 r0, r1, r2, r3, r4;
  int lreg = 0;

#define LOADT(kt_) do {                                              \
    size_t _ob = (size_t)((kt_) * 64) * (size_t)km;                  \
    r0 = *(const uint2*)&gb[_ob + ga0];                              \
    r1 = *(const uint2*)&gb[_ob + ga1];                              \
    r2 = *(const uint2*)&gb[_ob + ga2];                              \
    r3 = *(const uint2*)&gb[_ob + ga3];                              \
    r4 = *(const uint2*)&gb[_ob + ga4];                              \
    if (tid < 64) lreg = labP[(kt_) * 64 + tid];                     \
  } while (0)

#define WRITET(b) do {                                               \
    unsigned short* _lb = ISK ? Ks[b] : Vt[b];                       \
    *(uint2*)&_lb[ls0] = r0;                                         \
    *(uint2*)&_lb[ls1] = r1;                                         \
    *(uint2*)&_lb[ls2] = r2;                                         \
    *(uint2*)&_lb[ls3] = r3;                                         \
    *(uint2*)&_lb[ls4] = r4;                                         \
    if (tid < 64) labk[b][tid] = lreg;                               \
  } while (0)

  if (ta < tb){
    // prologue: stage tile ta into buf0, issue loads for ta+1
    LOADT(ta);
    WRITET(0);
    if (ta + 1 < tb) LOADT(ta + 1);
    __syncthreads();

    int cur = 0;
    for (int kt = ta; kt < tb; kt++){
      int nxt = cur ^ 1;
      // regs hold tile kt+1: write it to the other buffer (its readers finished
      // at the barrier that ended iteration kt-1), then issue loads for kt+2.
      if (kt + 1 < tb){
        WRITET(nxt);
        if (kt + 2 < tb) LOADT(kt + 2);
      }

#pragma unroll
      for (int kg = 0; kg < 4; kg++){
        // S^T(16 keys x 16 queries) = K * Q^T, two query sets share kf
        f32x4 sa0 = f32x4{0.f,0.f,0.f,0.f}, sa1 = f32x4{0.f,0.f,0.f,0.f};
#pragma unroll
        for (int dc = 0; dc < 5; dc++){
          bf16x4 kf = *(const bf16x4*)&Ks[cur][(kg * 16 + l16) * KP + dc * 16 + quad * 4];
          sa0 = mfma16(kf, qf0[dc], sa0);
          sa1 = mfma16(kf, qf1[dc], sa1);
        }
        int4 lk4 = *(const int4*)&labk[cur][kg * 16 + quad * 4];
        bool m0 = !OUTSIDE || (lk4.x & 0x100), m1 = !OUTSIDE || (lk4.y & 0x100);
        bool m2 = !OUTSIDE || (lk4.z & 0x100), m3 = !OUTSIDE || (lk4.w & 0x100);
        int k0l = lk4.x & 0xff, k1l = lk4.y & 0xff, k2l = lk4.z & 0xff, k3l = lk4.w & 0xff;
        bf16x4 pf0, pf1;
        {
          float p0 = (k0l == lq0 && m0) ? __expf(sa0[0]) : 0.f;
          float p1 = (k1l == lq0 && m1) ? __expf(sa0[1]) : 0.f;
          float p2 = (k2l == lq0 && m2) ? __expf(sa0[2]) : 0.f;
          float p3 = (k3l == lq0 && m3) ? __expf(sa0[3]) : 0.f;
          lp0 += (p0 + p1) + (p2 + p3);
          pf0[0] = (short)f2bf(p0); pf0[1] = (short)f2bf(p1);
          pf0[2] = (short)f2bf(p2); pf0[3] = (short)f2bf(p3);
        }
        {
          float p0 = (k0l == lq1 && m0) ? __expf(sa1[0]) : 0.f;
          float p1 = (k1l == lq1 && m1) ? __expf(sa1[1]) : 0.f;
          float p2 = (k2l == lq1 && m2) ? __expf(sa1[2]) : 0.f;
          float p3 = (k3l == lq1 && m3) ? __expf(sa1[3]) : 0.f;
          lp1 += (p0 + p1) + (p2 + p3);
          pf1[0] = (short)f2bf(p0); pf1[1] = (short)f2bf(p1);
          pf1[2] = (short)f2bf(p2); pf1[3] = (short)f2bf(p3);
        }
        // O^T += V^T * P^T, two query sets share vf
#pragma unroll
        for (int dt = 0; dt < 5; dt++){
          bf16x4 vf = *(const bf16x4*)&Vt[cur][(dt * 16 + l16) * VP + kg * 16 + quad * 4];
          Oc0[dt] = mfma16(vf, pf0, Oc0[dt]);
          Oc1[dt] = mfma16(vf, pf1, Oc1[dt]);
        }
      }
      __syncthreads();   // all reads of cur done; writes of nxt visible
      cur = nxt;
    }
  }
#undef LOADT
#undef WRITET
  // row-sums: reduce across quads (same l16); write UNNORMALIZED partials
  lp0 += __shfl_xor(lp0, 16); lp0 += __shfl_xor(lp0, 32);
  lp1 += __shfl_xor(lp1, 16); lp1 += __shfl_xor(lp1, 32);
  int hz = third * 2 + (int)blockIdx.z;
  if (quad == 0){
    lpP[(size_t)(hz * 8 + h) * S_LEN + qrow0] = lp0;
    lpP[(size_t)(hz * 8 + h) * S_LEN + qrow1] = lp1;
  }
  unsigned short* dst = opart + (size_t)hz * S_LEN * CDIM;
#pragma unroll
  for (int dt = 0; dt < 5; dt++){
    ushort4 o;
    o.x = f2bf(Oc0[dt][0]); o.y = f2bf(Oc0[dt][1]);
    o.z = f2bf(Oc0[dt][2]); o.w = f2bf(Oc0[dt][3]);
    *(ushort4*)&dst[(size_t)qrow0 * CDIM + h * 80 + dt * 16 + quad * 4] = o;
    o.x = f2bf(Oc1[dt][0]); o.y = f2bf(Oc1[dt][1]);
    o.z = f2bf(Oc1[dt][2]); o.w = f2bf(Oc1[dt][3]);
    *(ushort4*)&dst[(size_t)qrow1 * CDIM + h * 80 + dt * 16 + quad * 4] = o;
  }
}

// ---------------- combine: planes[z] = sum of 3 partial O / sum of 3 partial lp
__global__ __launch_bounds__(256) void k_comb(const unsigned short* __restrict__ opart,
                                              const float* __restrict__ lpP,
                                              unsigned short* __restrict__ planes){
  int i = blockIdx.x * 256 + threadIdx.x;          // 4096*160 items per z
  int z = blockIdx.y;
  int qrow = i / 160, c4 = (i % 160) * 4;
  int h = c4 / 80;                                  // 80 % 4 == 0: one h per ushort4
  size_t base = (size_t)qrow * CDIM + c4;
  size_t pz = (size_t)S_LEN * CDIM;
  float lp = lpP[(size_t)((z)     * 8 + h) * S_LEN + qrow]
           + lpP[(size_t)((z + 2) * 8 + h) * S_LEN + qrow]
           + lpP[(size_t)((z + 4) * 8 + h) * S_LEN + qrow];
  float iL = 1.f / lp;
  ushort4 a = *(const ushort4*)&opart[(size_t)(z)     * pz + base];
  ushort4 b = *(const ushort4*)&opart[(size_t)(z + 2) * pz + base];
  ushort4 c = *(const ushort4*)&opart[(size_t)(z + 4) * pz + base];
  ushort4 o;
  o.x = f2bf((b2f(a.x) + b2f(b.x) + b2f(c.x)) * iL);
  o.y = f2bf((b2f(a.y) + b2f(b.y) + b2f(c.y)) * iL);
  o.z = f2bf((b2f(a.z) + b2f(b.z) + b2f(c.z)) * iL);
  o.w = f2bf((b2f(a.w) + b2f(b.w) + b2f(c.w)) * iL);
  *(ushort4*)&planes[(size_t)z * pz + base] = o;
}

// ---------------- entity E1: P = exp(Q_e K_e^T) per (qtile, ktile), bf16, + rowsums
// BK=64 staging (same pattern as k_gemm); __expf kept.
__global__ __launch_bounds__(256) void k_ent_qk(const unsigned short* __restrict__ proj,
                                                const int* __restrict__ labP,
                                                const int4* __restrict__ qtinfo,
                                                unsigned short* __restrict__ Sbuf,
                                                float* __restrict__ rowsum){
  int qt = blockIdx.y;
  int4 qi = qtinfo[qt];
  int nkt = (qi.y - qi.x) >> 7;
  if ((int)blockIdx.x >= nkt) return;
  int m0 = qt * 128, n0 = qi.x + blockIdx.x * 128;
  __shared__ __align__(16) unsigned short As[128 * 64];
  __shared__ __align__(16) unsigned short Bs[128 * 64];
  __shared__ int lQ[128], lK[128];
  int tid = threadIdx.x, wid = tid >> 6, lane = tid & 63;
  int quad = lane >> 4, l16 = lane & 15;
  int wm = (wid >> 1) * 64, wn = (wid & 1) * 64;
  if (tid < 128) lQ[tid] = labP[m0 + tid] & 0xff;
  else           lK[tid - 128] = labP[n0 + tid - 128] & 0xff;
  f32x4 acc[4][4];
#pragma unroll
  for (int i = 0; i < 4; i++)
#pragma unroll
    for (int j = 0; j < 4; j++) acc[i][j] = f32x4{0.f, 0.f, 0.f, 0.f};

  for (int k0 = 0; k0 < 640; k0 += 64){
    __syncthreads();
#pragma unroll
    for (int u = 0; u < 4; u++){
      int c = tid + u * 256;
      int row = c >> 3, off = (c & 7) * 8;
      gload_lds(&proj[(size_t)(m0 + row) * NPROJ + 1920 + k0 + off], &As[c * 8]);
      gload_lds(&proj[(size_t)(n0 + row) * NPROJ + 2560 + k0 + off], &Bs[c * 8]);
    }
    __syncthreads();
#pragma unroll
    for (int ks = 0; ks < 2; ks++){
      bf16x8 af[4], bfr[4];
#pragma unroll
      for (int t = 0; t < 4; t++){
        af[t]  = *(const bf16x8*)(&As[(wm + t * 16 + l16) * 64 + ks * 32 + quad * 8]);
        bfr[t] = *(const bf16x8*)(&Bs[(wn + t * 16 + l16) * 64 + ks * 32 + quad * 8]);
      }
#pragma unroll
      for (int mt = 0; mt < 4; mt++)
#pragma unroll
        for (int nt = 0; nt < 4; nt++)
          acc[mt][nt] = __builtin_amdgcn_mfma_f32_16x16x32_bf16(af[mt], bfr[nt], acc[mt][nt], 0, 0, 0);
    }
  }
  unsigned short* St = Sbuf + ((size_t)(qi.z + blockIdx.x)) * 16384;
#pragma unroll
  for (int mt = 0; mt < 4; mt++)
#pragma unroll
    for (int r = 0; r < 4; r++){
      int lrow = wm + mt * 16 + quad * 4 + r;
      int myq = lQ[lrow];
      float psum = 0.f;
#pragma unroll
      for (int nt = 0; nt < 4; nt++){
        int lcol = wn + nt * 16 + l16;
        float p = (myq == lK[lcol]) ? __expf(acc[mt][nt][r]) : 0.f;
        St[lrow * 128 + lcol] = f2bf(p);
        psum += p;
      }
#pragma unroll
      for (int m = 1; m < 16; m <<= 1) psum += __shfl_xor(psum, m);
      if (l16 == 0) atomicAdd(&rowsum[m0 + lrow], psum);
    }
}

// ---------------- entity E2: attnS = bf16( P·V_e / rowsum + plane0 + plane1 )
// BK=64 (R20), same proven staging pattern as k_gemm/k_ent_qk.
__global__ __launch_bounds__(256) void k_ent_pv(const unsigned short* __restrict__ Sbuf,
                                                const unsigned short* __restrict__ veT,
                                                const int4* __restrict__ qtinfo,
                                                const float* __restrict__ rowsum,
                                                const unsigned short* __restrict__ planes,
                                                unsigned short* __restrict__ attnS){
  int qt = blockIdx.y, d0 = blockIdx.x * 128;
  int4 qi = qtinfo[qt];
  int m0 = qt * 128;
  int nk = qi.y - qi.x;
  __shared__ __align__(16) unsigned short As[128 * 64];
  __shared__ __align__(16) unsigned short Bs[128 * 64];
  int tid = threadIdx.x, wid = tid >> 6, lane = tid & 63;
  int quad = lane >> 4, l16 = lane & 15;
  int wm = (wid >> 1) * 64, wn = (wid & 1) * 64;
  f32x4 acc[4][4];
#pragma unroll
  for (int i = 0; i < 4; i++)
#pragma unroll
    for (int j = 0; j < 4; j++) acc[i][j] = f32x4{0.f, 0.f, 0.f, 0.f};

  for (int kk = 0; kk < nk; kk += 64){
    const unsigned short* St = Sbuf + ((size_t)(qi.z + (kk >> 7))) * 16384;
    int kloc = kk & 127;
    __syncthreads();
#pragma unroll
    for (int u = 0; u < 4; u++){
      int c = tid + u * 256;
      int row = c >> 3, off = (c & 7) * 8;
      gload_lds(&St[row * 128 + kloc + off], &As[c * 8]);
      gload_lds(&veT[(size_t)(d0 + row) * S_LEN + qi.x + kk + off], &Bs[c * 8]);
    }
    __syncthreads();
#pragma unroll
    for (int ks = 0; ks < 2; ks++){
      bf16x8 af[4], bfr[4];
#pragma unroll
      for (int t = 0; t < 4; t++){
        af[t]  = *(const bf16x8*)(&As[(wm + t * 16 + l16) * 64 + ks * 32 + quad * 8]);
        bfr[t] = *(const bf16x8*)(&Bs[(wn + t * 16 + l16) * 64 + ks * 32 + quad * 8]);
      }
#pragma unroll
      for (int mt = 0; mt < 4; mt++)
#pragma unroll
        for (int nt = 0; nt < 4; nt++)
          acc[mt][nt] = __builtin_amdgcn_mfma_f32_16x16x32_bf16(af[mt], bfr[nt], acc[mt][nt], 0, 0, 0);
    }
  }
#pragma unroll
  for (int mt = 0; mt < 4; mt++)
#pragma unroll
    for (int r = 0; r < 4; r++){
      int row = m0 + wm + mt * 16 + quad * 4 + r;
      float invL = 1.f / rowsum[row];
#pragma unroll
      for (int nt = 0; nt < 4; nt++){
        int col = d0 + wn + nt * 16 + l16;
        size_t idx = (size_t)row * CDIM + col;
        float v = acc[mt][nt][r] * invL + b2f(planes[idx]) + b2f(planes[(size_t)S_LEN * CDIM + idx]);
        attnS[idx] = f2bf(v);
      }
    }
}

extern "C" void kernel_launch(void* const* d_in, const int* in_sizes, int n_in,
                              void* d_out, int out_size, void* d_ws, size_t ws_size,
                              hipStream_t stream){
  const float* hs  = (const float*)d_in[0];
  const int* mask  = (const int*)d_in[1];
  const int* inp   = (const int*)d_in[2];
  char* ws = (char*)d_ws;
  int*            labels  = (int*)(ws + 0);
  int*            perm    = (int*)(ws + 16896);
  int*            inv     = (int*)(ws + 33280);
  int*            labP    = (int*)(ws + 49664);
  int4*           qtinfo  = (int4*)(ws + 66560);
  float*          rowsum  = (float*)(ws + 67072);
  unsigned short* hsb     = (unsigned short*)(ws + 131072);
  unsigned short* Wall    = (unsigned short*)(ws + 5373952);
  unsigned short* proj    = (unsigned short*)(ws + 13565952);
  unsigned short* vT      = (unsigned short*)(ws + 60751872);
  unsigned short* planes  = (unsigned short*)(ws + 76480512);   // 2 bf16 planes = 10.5 MB
  unsigned short* Sbuf    = (unsigned short*)(ws + 86966272);   // up to 1024 tiles * 32 KB
  unsigned short* attnS   = (unsigned short*)(ws + 120520704);
  unsigned short* Wob     = Wall + 9 * 409600;
  // attn partials live in the Sbuf region (consumed by k_comb BEFORE k_ent_qk
  // overwrites Sbuf): opart = 6 x [4096][640] bf16 (31.5 MB), lpP = 6x8x4096 f32.
  unsigned short* opart   = Sbuf;
  float*          lpP     = (float*)(ws + 86966272 + 31457280);

  k_prep<<<1, 1024, 0, stream>>>(mask, inp, labels, perm, inv, labP, qtinfo, rowsum);
  k_cvt_hs<<<(S_LEN * CDIM / 4 + 255) / 256, 256, 0, stream>>>(hs, hsb, S_LEN * CDIM);
  WPtrs wp;
  for (int i = 0; i < 10; i++) wp.w[i] = (const float*)d_in[3 + i];
  k_cvt_w<<<(10 * 409600 / 4 + 255) / 256, 256, 0, stream>>>(wp, Wall);

  // all 9 projections in one GEMM, rows scattered into bucket-permuted order
  k_gemm<0><<<dim3(45, 32), 256, 0, stream>>>(hsb, Wall, S_LEN, NPROJ, CDIM, NPROJ,
                                              inv, proj, nullptr, nullptr);
  k_transpose_v<<<dim3(64, 10, 3), 256, 0, stream>>>(proj, vT);

  // branches 1+3: 256-query 8-wave blocks + 3-way key split; partials + combine
  k_attn80<<<dim3(48, 8, 2), 512, 0, stream>>>(proj, vT, labP, qtinfo, opart, lpP);
  k_comb<<<dim3(2560, 2), 256, 0, stream>>>(opart, lpP, planes);

  // branch 2 (entity, d=640): GEMM-ified, P materialized bf16 per bucket
  k_ent_qk<<<dim3(32, 32), 256, 0, stream>>>(proj, labP, qtinfo, Sbuf, rowsum);
  k_ent_pv<<<dim3(5, 32), 256, 0, stream>>>(Sbuf, vT + (size_t)1 * CDIM * S_LEN,
                                            qtinfo, rowsum, planes, attnS);

  // out = attnS @ Wo^T + residual, un-permuted via perm in the epilogue
  k_gemm<1><<<dim3(5, 32), 256, 0, stream>>>(attnS, Wob, S_LEN, CDIM, CDIM, CDIM,
                                             perm, nullptr, (float*)d_out, hs);
}

// Round 12
// 355.425 us; speedup vs baseline: 1.5120x; 1.0572x over previous
//
#include <hip/hip_runtime.h>
#include <cstdint>

typedef __attribute__((ext_vector_type(8))) short bf16x8;
typedef __attribute__((ext_vector_type(4))) short bf16x4;
typedef __attribute__((ext_vector_type(4))) float f32x4;

#define S_LEN 4096
#define CDIM  640
#define NPROJ 5760

// K=16 bf16 MFMA (v_mfma_f32_16x16x16_bf16, gfx950-valid per ISA §10).
__device__ __forceinline__ f32x4 mfma16(bf16x4 a, bf16x4 b, f32x4 c){
#if defined(__HIP_DEVICE_COMPILE__) && __HIP_DEVICE_COMPILE__
  return __builtin_amdgcn_mfma_f32_16x16x16bf16_1k(a, b, c, 0, 0, 0);
#else
  (void)a; (void)b;
  return c;
#endif
}

// async global->LDS, 16B per lane; LDS dest must be wave-uniform base + lane*16
__device__ __forceinline__ void gload_lds(const unsigned short* g, unsigned short* l){
#if defined(__HIP_DEVICE_COMPILE__) && __HIP_DEVICE_COMPILE__
  __builtin_amdgcn_global_load_lds((const __attribute__((address_space(1))) unsigned int*)g,
                                   (__attribute__((address_space(3))) unsigned int*)l, 16, 0, 0);
#else
  (void)g; (void)l;
#endif
}

__device__ __forceinline__ unsigned short f2bf(float f){
  union { float f; uint32_t u; } v; v.f = f;
  uint32_t u = v.u;
  return (unsigned short)((u + 0x7fffu + ((u >> 16) & 1u)) >> 16);
}
__device__ __forceinline__ float b2f(unsigned short h){
  union { uint32_t u; float f; } v; v.u = ((uint32_t)h) << 16;
  return v.f;
}

// T1 XCD-chunked remap: HW assigns dispatch index d to XCD d%8 round-robin;
// remap so each XCD executes a CONTIGUOUS chunk of original tile ids
// (L2 reuse of shared operand panels). Requires nwg % 8 == 0 (all our grids).
__device__ __forceinline__ int xcd_chunk(int d, int nwg){
  return (d & 7) * (nwg >> 3) + (d >> 3);
}

// ---------------- R21: fused prologue (was k_labels/k_hist/k_perm/k_tiles).
__global__ __launch_bounds__(1024) void k_prep(const int* __restrict__ mask,
                                               const int* __restrict__ inp,
                                               int* __restrict__ labels,
                                               int* __restrict__ perm,
                                               int* __restrict__ inv,
                                               int* __restrict__ labP,
                                               int4* __restrict__ qtinfo,
                                               float* __restrict__ rowsum){
  __shared__ int h[4], base[5], cnt4[4], nkt[32];
  int t = threadIdx.x;
  if (t < 4){ h[t] = 0; cnt4[t] = 0; }
  __syncthreads();
  // labels + histogram
  for (int s = t; s < S_LEN; s += 1024){
    int y = s >> 6, x = s & 63;
    int off = (y * 8) * 512 + x * 8;
    int m = mask[off] & 0xff;
    int o = (inp[off] == 0) ? 0x100 : 0;
    labels[s] = m | o;
    atomicAdd(&h[m & 3], 1);
  }
  __syncthreads();
  if (t == 0){
    int a = 0;
    for (int c = 0; c < 4; c++){ base[c] = a; a += h[c]; }
    base[4] = a;
  }
  __syncthreads();
  // bucket-sort permutation (arrival order within bucket, same as before)
  for (int s = t; s < S_LEN; s += 1024){
    int lab = labels[s];
    int c = lab & 3;
    int pos = base[c] + atomicAdd(&cnt4[c], 1);
    perm[pos] = s; inv[s] = pos; labP[pos] = lab;
  }
  __syncthreads();   // labP globally visible within block
  // per-128-tile key ranges
  if (t < 32){
    int c0 = labP[t * 128] & 3, c1 = labP[t * 128 + 127] & 3;
    int lo = base[c0] & ~127, hi = (base[c1 + 1] + 127) & ~127;
    qtinfo[t].x = lo; qtinfo[t].y = hi; qtinfo[t].w = 0;
    nkt[t] = (hi - lo) >> 7;
  }
  __syncthreads();
  if (t == 0){
    int a = 0;
    for (int i = 0; i < 32; i++){ qtinfo[i].z = a; a += nkt[i]; }
  }
  for (int s = t; s < S_LEN; s += 1024) rowsum[s] = 0.f;
}

// ---------------- f32 -> bf16 converts
__global__ void k_cvt_hs(const float* __restrict__ src, unsigned short* __restrict__ dst, int n){
  int idx = (blockIdx.x * 256 + threadIdx.x) * 4;
  if (idx >= n) return;
  float4 v = *(const float4*)(src + idx);
  ushort4 o;
  o.x = f2bf(v.x); o.y = f2bf(v.y); o.z = f2bf(v.z); o.w = f2bf(v.w);
  *(ushort4*)(dst + idx) = o;
}

struct WPtrs { const float* w[10]; };

__global__ void k_cvt_w(WPtrs p, unsigned short* __restrict__ dst){
  int e = (blockIdx.x * 256 + threadIdx.x) * 4;
  if (e >= 10 * 409600) return;
  int a = e / 409600, r = e % 409600;
  float sc = (a == 0 || a == 6) ? 0.11180339887498948f   // 1/sqrt(80)
           : (a == 3 ? 0.03952847075210474f : 1.0f);     // 1/sqrt(640)
  float4 v = *(const float4*)(p.w[a] + r);
  ushort4 o;
  o.x = f2bf(v.x * sc); o.y = f2bf(v.y * sc); o.z = f2bf(v.z * sc); o.w = f2bf(v.w * sc);
  *(ushort4*)(dst + e) = o;
}

// ---------------- 128x128 MFMA GEMM
// BK=64, pitch-64 LDS, gload_lds staging. R22: T1 XCD-chunked tile remap --
// consecutive tiles (sharing the A row-panel) land on the same XCD's L2.
template<int EPI>
__global__ __launch_bounds__(256) void k_gemm(const unsigned short* __restrict__ A,
                                              const unsigned short* __restrict__ B,
                                              int M, int N, int K, int ldc,
                                              const int* __restrict__ rowmap,
                                              unsigned short* __restrict__ Cb,
                                              float* __restrict__ Cf,
                                              const float* __restrict__ resid){
  __shared__ __align__(16) unsigned short As[128 * 64];
  __shared__ __align__(16) unsigned short Bs[128 * 64];
  int d = blockIdx.y * gridDim.x + blockIdx.x;
  int o = xcd_chunk(d, gridDim.x * gridDim.y);
  int m0 = (o / gridDim.x) * 128, n0 = (o % gridDim.x) * 128;
  int tid = threadIdx.x;
  int wid = tid >> 6, lane = tid & 63;
  int quad = lane >> 4, l16 = lane & 15;
  int wm = (wid >> 1) * 64, wn = (wid & 1) * 64;
  f32x4 acc[4][4];
#pragma unroll
  for (int i = 0; i < 4; i++)
#pragma unroll
    for (int j = 0; j < 4; j++) acc[i][j] = f32x4{0.f, 0.f, 0.f, 0.f};

  for (int k0 = 0; k0 < K; k0 += 64){
    __syncthreads();
#pragma unroll
    for (int u = 0; u < 4; u++){
      int c = tid + u * 256;
      int row = c >> 3, off = (c & 7) * 8;
      gload_lds(&A[(size_t)(m0 + row) * K + k0 + off], &As[c * 8]);
      gload_lds(&B[(size_t)(n0 + row) * K + k0 + off], &Bs[c * 8]);
    }
    __syncthreads();
#pragma unroll
    for (int ks = 0; ks < 2; ks++){
      bf16x8 af[4], bfr[4];
#pragma unroll
      for (int t = 0; t < 4; t++){
        af[t]  = *(const bf16x8*)(&As[(wm + t * 16 + l16) * 64 + ks * 32 + quad * 8]);
        bfr[t] = *(const bf16x8*)(&Bs[(wn + t * 16 + l16) * 64 + ks * 32 + quad * 8]);
      }
#pragma unroll
      for (int mt = 0; mt < 4; mt++)
#pragma unroll
        for (int nt = 0; nt < 4; nt++)
          acc[mt][nt] = __builtin_amdgcn_mfma_f32_16x16x32_bf16(af[mt], bfr[nt], acc[mt][nt], 0, 0, 0);
    }
  }
#pragma unroll
  for (int mt = 0; mt < 4; mt++)
#pragma unroll
    for (int nt = 0; nt < 4; nt++)
#pragma unroll
      for (int r = 0; r < 4; r++){
        int row = m0 + wm + mt * 16 + quad * 4 + r;
        int col = n0 + wn + nt * 16 + l16;
        float v = acc[mt][nt][r];
        if (EPI == 0){
          Cb[(size_t)rowmap[row] * ldc + col] = f2bf(v);
        } else {
          int ro = rowmap[row];
          Cf[(size_t)ro * ldc + col] = v + resid[(size_t)ro * ldc + col];
        }
      }
}

// ---------------- transpose the three V projections: vT[z][c][s]
// uint2-vectorized both sides (R21). Streaming, no inter-block reuse -> no swizzle.
__global__ void k_transpose_v(const unsigned short* __restrict__ proj, unsigned short* __restrict__ vT){
  __shared__ unsigned short T[64][68];
  int z = blockIdx.z;
  int s0 = blockIdx.x * 64, c0 = blockIdx.y * 64;
  int colbase = 1280 + z * 1920 + c0;   // v:1280  v_e:3200  v_o:5120
  unsigned short* dst = vT + (size_t)z * CDIM * S_LEN;
  int tid = threadIdx.x;
#pragma unroll
  for (int u = 0; u < 4; u++){
    int i = tid + u * 256;               // 1024 uint2 units: r = i>>4, c4 = (i&15)*4
    int r = i >> 4, c4 = (i & 15) * 4;
    uint2 v = *(const uint2*)&proj[(size_t)(s0 + r) * NPROJ + colbase + c4];
    *(uint2*)&T[r][c4] = v;
  }
  __syncthreads();
#pragma unroll
  for (int u = 0; u < 4; u++){
    int j = tid + u * 256;               // c = j>>4, r4 = (j&15)*4
    int c = j >> 4, r4 = (j & 15) * 4;
    ushort4 o;
    o.x = T[r4 + 0][c]; o.y = T[r4 + 1][c];
    o.z = T[r4 + 2][c]; o.w = T[r4 + 3][c];
    *(ushort4*)&dst[(size_t)(c0 + c) * S_LEN + s0 + r4] = o;
  }
}

// ---------------- flash attention, d=80, z=0: orig, z=1: outside
// R20 config (structural floor per decision rule): 3-way key split, 256-query
// 8-wave blocks, waves 0-3 stage K / 4-7 stage V, scratch-proof staging.
#define KP 84
#define VP 76
__global__ __launch_bounds__(512, 2) void k_attn80(const unsigned short* __restrict__ proj,
                                                   const unsigned short* __restrict__ vT,
                                                   const int* __restrict__ labP,
                                                   const int4* __restrict__ qtinfo,
                                                   unsigned short* __restrict__ opart,
                                                   float* __restrict__ lpP){
  __shared__ __align__(16) unsigned short Ks[2][64 * KP];
  __shared__ __align__(16) unsigned short Vt[2][80 * VP];
  __shared__ __align__(16) int labk[2][64];
  int tid = threadIdx.x, wid = tid >> 6, lane = tid & 63;
  int quad = lane >> 4, l16 = lane & 15;
  int qt = blockIdx.x / 3, third = blockIdx.x % 3;
  int q0 = qt * 256;
  int h  = blockIdx.y;
  bool OUTSIDE = (blockIdx.z == 1);
  int qc = (OUTSIDE ? 3840 : 0) + h * 80;
  int kc = (OUTSIDE ? 4480 : 640) + h * 80;
  const unsigned short* vTb = vT + (size_t)(OUTSIDE ? 2 : 0) * CDIM * S_LEN;
  int4 qa = qtinfo[qt * 2], qb = qtinfo[qt * 2 + 1];
  int lo = min(qa.x, qb.x), hi = max(qa.y, qb.y);
  int t0 = lo >> 6, t1 = hi >> 6;
  int nt = t1 - t0;
  int ta = t0 + (nt * third) / 3;
  int tb = t0 + (nt * (third + 1)) / 3;

  // two query sets per wave (B-operand layout: lane n=l16 is the query, k=quad*4+j)
  int qrow0 = q0 + wid * 32 + l16;
  int qrow1 = qrow0 + 16;
  bf16x4 qf0[5], qf1[5];
#pragma unroll
  for (int dc = 0; dc < 5; dc++){
    qf0[dc] = *(const bf16x4*)&proj[(size_t)qrow0 * NPROJ + qc + dc * 16 + quad * 4];
    qf1[dc] = *(const bf16x4*)&proj[(size_t)qrow1 * NPROJ + qc + dc * 16 + quad * 4];
  }
  int lq0 = labP[qrow0] & 0xff, lq1 = labP[qrow1] & 0xff;

  float lp0 = 0.f, lp1 = 0.f;
  f32x4 Oc0[5], Oc1[5];
#pragma unroll
  for (int t = 0; t < 5; t++){ Oc0[t] = f32x4{0.f,0.f,0.f,0.f}; Oc1[t] = f32x4{0.f,0.f,0.f,0.f}; }

  // staging roles: waves 0-3 stage the K tile (64 rows x 20 uint2), waves 4-7
  // stage the V tile (80 rows x 16 uint2). 1280 uint2 per role over 256
  // threads = 5 units/thread; unit c = t5 + u*256. All tile-invariant.
  const bool ISK = (tid < 256);
  const int t5 = ISK ? tid : (tid - 256);
  const unsigned short* gb = ISK ? proj : vTb;
  const int km = ISK ? NPROJ : 1;                    // per-tile offset multiplier
  int ga0, ga1, ga2, ga3, ga4, ls0, ls1, ls2, ls3, ls4;
  {
    const int c0_ = t5, c1_ = t5 + 256, c2_ = t5 + 512, c3_ = t5 + 768, c4_ = t5 + 1024;
    if (ISK){
      ga0 = (c0_ / 20) * NPROJ + kc + (c0_ % 20) * 4;
      ga1 = (c1_ / 20) * NPROJ + kc + (c1_ % 20) * 4;
      ga2 = (c2_ / 20) * NPROJ + kc + (c2_ % 20) * 4;
      ga3 = (c3_ / 20) * NPROJ + kc + (c3_ % 20) * 4;
      ga4 = (c4_ / 20) * NPROJ + kc + (c4_ % 20) * 4;
      ls0 = (c0_ / 20) * KP + (c0_ % 20) * 4;
      ls1 = (c1_ / 20) * KP + (c1_ % 20) * 4;
      ls2 = (c2_ / 20) * KP + (c2_ % 20) * 4;
      ls3 = (c3_ / 20) * KP + (c3_ % 20) * 4;
      ls4 = (c4_ / 20) * KP + (c4_ % 20) * 4;
    } else {
      ga0 = (h * 80 + (c0_ >> 4)) * S_LEN + (c0_ & 15) * 4;
      ga1 = (h * 80 + (c1_ >> 4)) * S_LEN + (c1_ & 15) * 4;
      ga2 = (h * 80 + (c2_ >> 4)) * S_LEN + (c2_ & 15) * 4;
      ga3 = (h * 80 + (c3_ >> 4)) * S_LEN + (c3_ & 15) * 4;
      ga4 = (h * 80 + (c4_ >> 4)) * S_LEN + (c4_ & 15) * 4;
      ls0 = (c0_ >> 4) * VP + (c0_ & 15) * 4;
      ls1 = (c1_ >> 4) * VP + (c1_ & 15) * 4;
      ls2 = (c2_ >> 4) * VP + (c2_ & 15) * 4;
      ls3 = (c3_ >> 4) * VP + (c3_ & 15) * 4;
      ls4 = (c4_ >> 4) * VP + (c4_ & 15) * 4;
    }
  }

  uint2 r0, r1, r2, r3, r4;
  int lreg = 0;

#define LOADT(kt_) do {                                              \
    size_t _ob = (size_t)((kt_) * 64) * (size_t)km;                  \
    r0 = *(const uint2*)&gb[_ob + ga0];                              \
    r1 = *(const uint2*)&gb[_ob + ga1];                              \
    r2 = *(const uint2*)&gb[_ob + ga2];                              \
    r3 = *(const uint2*)&gb[_ob + ga3];                              \
    r4 = *(const uint2*)&gb[_ob + ga4];                              \
    if (tid < 64) lreg = labP[(kt_) * 64 + tid];                     \
  } while (0)

#define WRITET(b) do {                                               \
    unsigned short* _lb = ISK ? Ks[b] : Vt[b];                       \
    *(uint2*)&_lb[ls0] = r0;                                         \
    *(uint2*)&_lb[ls1] = r1;                                         \
    *(uint2*)&_lb[ls2] = r2;                                         \
    *(uint2*)&_lb[ls3] = r3;                                         \
    *(uint2*)&_lb[ls4] = r4;                                         \
    if (tid < 64) labk[b][tid] = lreg;                               \
  } while (0)

  if (ta < tb){
    // prologue: stage tile ta into buf0, issue loads for ta+1
    LOADT(ta);
    WRITET(0);
    if (ta + 1 < tb) LOADT(ta + 1);
    __syncthreads();

    int cur = 0;
    for (int kt = ta; kt < tb; kt++){
      int nxt = cur ^ 1;
      // regs hold tile kt+1: write it to the other buffer (its readers finished
      // at the barrier that ended iteration kt-1), then issue loads for kt+2.
      if (kt + 1 < tb){
        WRITET(nxt);
        if (kt + 2 < tb) LOADT(kt + 2);
      }

#pragma unroll
      for (int kg = 0; kg < 4; kg++){
        // S^T(16 keys x 16 queries) = K * Q^T, two query sets share kf
        f32x4 sa0 = f32x4{0.f,0.f,0.f,0.f}, sa1 = f32x4{0.f,0.f,0.f,0.f};
#pragma unroll
        for (int dc = 0; dc < 5; dc++){
          bf16x4 kf = *(const bf16x4*)&Ks[cur][(kg * 16 + l16) * KP + dc * 16 + quad * 4];
          sa0 = mfma16(kf, qf0[dc], sa0);
          sa1 = mfma16(kf, qf1[dc], sa1);
        }
        int4 lk4 = *(const int4*)&labk[cur][kg * 16 + quad * 4];
        bool m0 = !OUTSIDE || (lk4.x & 0x100), m1 = !OUTSIDE || (lk4.y & 0x100);
        bool m2 = !OUTSIDE || (lk4.z & 0x100), m3 = !OUTSIDE || (lk4.w & 0x100);
        int k0l = lk4.x & 0xff, k1l = lk4.y & 0xff, k2l = lk4.z & 0xff, k3l = lk4.w & 0xff;
        bf16x4 pf0, pf1;
        {
          float p0 = (k0l == lq0 && m0) ? __expf(sa0[0]) : 0.f;
          float p1 = (k1l == lq0 && m1) ? __expf(sa0[1]) : 0.f;
          float p2 = (k2l == lq0 && m2) ? __expf(sa0[2]) : 0.f;
          float p3 = (k3l == lq0 && m3) ? __expf(sa0[3]) : 0.f;
          lp0 += (p0 + p1) + (p2 + p3);
          pf0[0] = (short)f2bf(p0); pf0[1] = (short)f2bf(p1);
          pf0[2] = (short)f2bf(p2); pf0[3] = (short)f2bf(p3);
        }
        {
          float p0 = (k0l == lq1 && m0) ? __expf(sa1[0]) : 0.f;
          float p1 = (k1l == lq1 && m1) ? __expf(sa1[1]) : 0.f;
          float p2 = (k2l == lq1 && m2) ? __expf(sa1[2]) : 0.f;
          float p3 = (k3l == lq1 && m3) ? __expf(sa1[3]) : 0.f;
          lp1 += (p0 + p1) + (p2 + p3);
          pf1[0] = (short)f2bf(p0); pf1[1] = (short)f2bf(p1);
          pf1[2] = (short)f2bf(p2); pf1[3] = (short)f2bf(p3);
        }
        // O^T += V^T * P^T, two query sets share vf
#pragma unroll
        for (int dt = 0; dt < 5; dt++){
          bf16x4 vf = *(const bf16x4*)&Vt[cur][(dt * 16 + l16) * VP + kg * 16 + quad * 4];
          Oc0[dt] = mfma16(vf, pf0, Oc0[dt]);
          Oc1[dt] = mfma16(vf, pf1, Oc1[dt]);
        }
      }
      __syncthreads();   // all reads of cur done; writes of nxt visible
      cur = nxt;
    }
  }
#undef LOADT
#undef WRITET
  // row-sums: reduce across quads (same l16); write UNNORMALIZED partials
  lp0 += __shfl_xor(lp0, 16); lp0 += __shfl_xor(lp0, 32);
  lp1 += __shfl_xor(lp1, 16); lp1 += __shfl_xor(lp1, 32);
  int hz = third * 2 + (int)blockIdx.z;
  if (quad == 0){
    lpP[(size_t)(hz * 8 + h) * S_LEN + qrow0] = lp0;
    lpP[(size_t)(hz * 8 + h) * S_LEN + qrow1] = lp1;
  }
  unsigned short* dst = opart + (size_t)hz * S_LEN * CDIM;
#pragma unroll
  for (int dt = 0; dt < 5; dt++){
    ushort4 o;
    o.x = f2bf(Oc0[dt][0]); o.y = f2bf(Oc0[dt][1]);
    o.z = f2bf(Oc0[dt][2]); o.w = f2bf(Oc0[dt][3]);
    *(ushort4*)&dst[(size_t)qrow0 * CDIM + h * 80 + dt * 16 + quad * 4] = o;
    o.x = f2bf(Oc1[dt][0]); o.y = f2bf(Oc1[dt][1]);
    o.z = f2bf(Oc1[dt][2]); o.w = f2bf(Oc1[dt][3]);
    *(ushort4*)&dst[(size_t)qrow1 * CDIM + h * 80 + dt * 16 + quad * 4] = o;
  }
}

// ---------------- combine: planes[z] = sum of 3 partial O / sum of 3 partial lp
__global__ __launch_bounds__(256) void k_comb(const unsigned short* __restrict__ opart,
                                              const float* __restrict__ lpP,
                                              unsigned short* __restrict__ planes){
  int i = blockIdx.x * 256 + threadIdx.x;          // 4096*160 items per z
  int z = blockIdx.y;
  int qrow = i / 160, c4 = (i % 160) * 4;
  int h = c4 / 80;                                  // 80 % 4 == 0: one h per ushort4
  size_t base = (size_t)qrow * CDIM + c4;
  size_t pz = (size_t)S_LEN * CDIM;
  float lp = lpP[(size_t)((z)     * 8 + h) * S_LEN + qrow]
           + lpP[(size_t)((z + 2) * 8 + h) * S_LEN + qrow]
           + lpP[(size_t)((z + 4) * 8 + h) * S_LEN + qrow];
  float iL = 1.f / lp;
  ushort4 a = *(const ushort4*)&opart[(size_t)(z)     * pz + base];
  ushort4 b = *(const ushort4*)&opart[(size_t)(z + 2) * pz + base];
  ushort4 c = *(const ushort4*)&opart[(size_t)(z + 4) * pz + base];
  ushort4 o;
  o.x = f2bf((b2f(a.x) + b2f(b.x) + b2f(c.x)) * iL);
  o.y = f2bf((b2f(a.y) + b2f(b.y) + b2f(c.y)) * iL);
  o.z = f2bf((b2f(a.z) + b2f(b.z) + b2f(c.z)) * iL);
  o.w = f2bf((b2f(a.w) + b2f(b.w) + b2f(c.w)) * iL);
  *(ushort4*)&planes[(size_t)z * pz + base] = o;
}

// ---------------- entity E1: P = exp(Q_e K_e^T) per (qtile, ktile), bf16, + rowsums
// BK=64 staging; R22: T1 XCD-chunked remap (consecutive k-tiles of one qt share
// the Q_e panel -> same XCD L2).
__global__ __launch_bounds__(256) void k_ent_qk(const unsigned short* __restrict__ proj,
                                                const int* __restrict__ labP,
                                                const int4* __restrict__ qtinfo,
                                                unsigned short* __restrict__ Sbuf,
                                                float* __restrict__ rowsum){
  int d = blockIdx.y * gridDim.x + blockIdx.x;
  int o = xcd_chunk(d, gridDim.x * gridDim.y);
  int ktb = o % gridDim.x, qt = o / gridDim.x;
  int4 qi = qtinfo[qt];
  int nkt = (qi.y - qi.x) >> 7;
  if (ktb >= nkt) return;
  int m0 = qt * 128, n0 = qi.x + ktb * 128;
  __shared__ __align__(16) unsigned short As[128 * 64];
  __shared__ __align__(16) unsigned short Bs[128 * 64];
  __shared__ int lQ[128], lK[128];
  int tid = threadIdx.x, wid = tid >> 6, lane = tid & 63;
  int quad = lane >> 4, l16 = lane & 15;
  int wm = (wid >> 1) * 64, wn = (wid & 1) * 64;
  if (tid < 128) lQ[tid] = labP[m0 + tid] & 0xff;
  else           lK[tid - 128] = labP[n0 + tid - 128] & 0xff;
  f32x4 acc[4][4];
#pragma unroll
  for (int i = 0; i < 4; i++)
#pragma unroll
    for (int j = 0; j < 4; j++) acc[i][j] = f32x4{0.f, 0.f, 0.f, 0.f};

  for (int k0 = 0; k0 < 640; k0 += 64){
    __syncthreads();
#pragma unroll
    for (int u = 0; u < 4; u++){
      int c = tid + u * 256;
      int row = c >> 3, off = (c & 7) * 8;
      gload_lds(&proj[(size_t)(m0 + row) * NPROJ + 1920 + k0 + off], &As[c * 8]);
      gload_lds(&proj[(size_t)(n0 + row) * NPROJ + 2560 + k0 + off], &Bs[c * 8]);
    }
    __syncthreads();
#pragma unroll
    for (int ks = 0; ks < 2; ks++){
      bf16x8 af[4], bfr[4];
#pragma unroll
      for (int t = 0; t < 4; t++){
        af[t]  = *(const bf16x8*)(&As[(wm + t * 16 + l16) * 64 + ks * 32 + quad * 8]);
        bfr[t] = *(const bf16x8*)(&Bs[(wn + t * 16 + l16) * 64 + ks * 32 + quad * 8]);
      }
#pragma unroll
      for (int mt = 0; mt < 4; mt++)
#pragma unroll
        for (int nt = 0; nt < 4; nt++)
          acc[mt][nt] = __builtin_amdgcn_mfma_f32_16x16x32_bf16(af[mt], bfr[nt], acc[mt][nt], 0, 0, 0);
    }
  }
  unsigned short* St = Sbuf + ((size_t)(qi.z + ktb)) * 16384;
#pragma unroll
  for (int mt = 0; mt < 4; mt++)
#pragma unroll
    for (int r = 0; r < 4; r++){
      int lrow = wm + mt * 16 + quad * 4 + r;
      int myq = lQ[lrow];
      float psum = 0.f;
#pragma unroll
      for (int nt = 0; nt < 4; nt++){
        int lcol = wn + nt * 16 + l16;
        float p = (myq == lK[lcol]) ? __expf(acc[mt][nt][r]) : 0.f;
        St[lrow * 128 + lcol] = f2bf(p);
        psum += p;
      }
#pragma unroll
      for (int m = 1; m < 16; m <<= 1) psum += __shfl_xor(psum, m);
      if (l16 == 0) atomicAdd(&rowsum[m0 + lrow], psum);
    }
}

// ---------------- entity E2: attnS = bf16( P·V_e / rowsum + plane0 + plane1 )
// BK=64; R22: T1 XCD-chunked remap (the 5 d-blocks of one qt share its P buffer).
__global__ __launch_bounds__(256) void k_ent_pv(const unsigned short* __restrict__ Sbuf,
                                                const unsigned short* __restrict__ veT,
                                                const int4* __restrict__ qtinfo,
                                                const float* __restrict__ rowsum,
                                                const unsigned short* __restrict__ planes,
                                                unsigned short* __restrict__ attnS){
  int d = blockIdx.y * gridDim.x + blockIdx.x;
  int o = xcd_chunk(d, gridDim.x * gridDim.y);
  int qt = o / gridDim.x, d0 = (o % gridDim.x) * 128;
  int4 qi = qtinfo[qt];
  int m0 = qt * 128;
  int nk = qi.y - qi.x;
  __shared__ __align__(16) unsigned short As[128 * 64];
  __shared__ __align__(16) unsigned short Bs[128 * 64];
  int tid = threadIdx.x, wid = tid >> 6, lane = tid & 63;
  int quad = lane >> 4, l16 = lane & 15;
  int wm = (wid >> 1) * 64, wn = (wid & 1) * 64;
  f32x4 acc[4][4];
#pragma unroll
  for (int i = 0; i < 4; i++)
#pragma unroll
    for (int j = 0; j < 4; j++) acc[i][j] = f32x4{0.f, 0.f, 0.f, 0.f};

  for (int kk = 0; kk < nk; kk += 64){
    const unsigned short* St = Sbuf + ((size_t)(qi.z + (kk >> 7))) * 16384;
    int kloc = kk & 127;
    __syncthreads();
#pragma unroll
    for (int u = 0; u < 4; u++){
      int c = tid + u * 256;
      int row = c >> 3, off = (c & 7) * 8;
      gload_lds(&St[row * 128 + kloc + off], &As[c * 8]);
      gload_lds(&veT[(size_t)(d0 + row) * S_LEN + qi.x + kk + off], &Bs[c * 8]);
    }
    __syncthreads();
#pragma unroll
    for (int ks = 0; ks < 2; ks++){
      bf16x8 af[4], bfr[4];
#pragma unroll
      for (int t = 0; t < 4; t++){
        af[t]  = *(const bf16x8*)(&As[(wm + t * 16 + l16) * 64 + ks * 32 + quad * 8]);
        bfr[t] = *(const bf16x8*)(&Bs[(wn + t * 16 + l16) * 64 + ks * 32 + quad * 8]);
      }
#pragma unroll
      for (int mt = 0; mt < 4; mt++)
#pragma unroll
        for (int nt = 0; nt < 4; nt++)
          acc[mt][nt] = __builtin_amdgcn_mfma_f32_16x16x32_bf16(af[mt], bfr[nt], acc[mt][nt], 0, 0, 0);
    }
  }
#pragma unroll
  for (int mt = 0; mt < 4; mt++)
#pragma unroll
    for (int r = 0; r < 4; r++){
      int row = m0 + wm + mt * 16 + quad * 4 + r;
      float invL = 1.f / rowsum[row];
#pragma unroll
      for (int nt = 0; nt < 4; nt++){
        int col = d0 + wn + nt * 16 + l16;
        size_t idx = (size_t)row * CDIM + col;
        float v = acc[mt][nt][r] * invL + b2f(planes[idx]) + b2f(planes[(size_t)S_LEN * CDIM + idx]);
        attnS[idx] = f2bf(v);
      }
    }
}

extern "C" void kernel_launch(void* const* d_in, const int* in_sizes, int n_in,
                              void* d_out, int out_size, void* d_ws, size_t ws_size,
                              hipStream_t stream){
  const float* hs  = (const float*)d_in[0];
  const int* mask  = (const int*)d_in[1];
  const int* inp   = (const int*)d_in[2];
  char* ws = (char*)d_ws;
  int*            labels  = (int*)(ws + 0);
  int*            perm    = (int*)(ws + 16896);
  int*            inv     = (int*)(ws + 33280);
  int*            labP    = (int*)(ws + 49664);
  int4*           qtinfo  = (int4*)(ws + 66560);
  float*          rowsum  = (float*)(ws + 67072);
  unsigned short* hsb     = (unsigned short*)(ws + 131072);
  unsigned short* Wall    = (unsigned short*)(ws + 5373952);
  unsigned short* proj    = (unsigned short*)(ws + 13565952);
  unsigned short* vT      = (unsigned short*)(ws + 60751872);
  unsigned short* planes  = (unsigned short*)(ws + 76480512);   // 2 bf16 planes = 10.5 MB
  unsigned short* Sbuf    = (unsigned short*)(ws + 86966272);   // up to 1024 tiles * 32 KB
  unsigned short* attnS   = (unsigned short*)(ws + 120520704);
  unsigned short* Wob     = Wall + 9 * 409600;
  // attn partials live in the Sbuf region (consumed by k_comb BEFORE k_ent_qk
  // overwrites Sbuf): opart = 6 x [4096][640] bf16 (31.5 MB), lpP = 6x8x4096 f32.
  unsigned short* opart   = Sbuf;
  float*          lpP     = (float*)(ws + 86966272 + 31457280);

  k_prep<<<1, 1024, 0, stream>>>(mask, inp, labels, perm, inv, labP, qtinfo, rowsum);
  k_cvt_hs<<<(S_LEN * CDIM / 4 + 255) / 256, 256, 0, stream>>>(hs, hsb, S_LEN * CDIM);
  WPtrs wp;
  for (int i = 0; i < 10; i++) wp.w[i] = (const float*)d_in[3 + i];
  k_cvt_w<<<(10 * 409600 / 4 + 255) / 256, 256, 0, stream>>>(wp, Wall);

  // all 9 projections in one GEMM, rows scattered into bucket-permuted order
  k_gemm<0><<<dim3(45, 32), 256, 0, stream>>>(hsb, Wall, S_LEN, NPROJ, CDIM, NPROJ,
                                              inv, proj, nullptr, nullptr);
  k_transpose_v<<<dim3(64, 10, 3), 256, 0, stream>>>(proj, vT);

  // branches 1+3: 256-query 8-wave blocks + 3-way key split; partials + combine
  k_attn80<<<dim3(48, 8, 2), 512, 0, stream>>>(proj, vT, labP, qtinfo, opart, lpP);
  k_comb<<<dim3(2560, 2), 256, 0, stream>>>(opart, lpP, planes);

  // branch 2 (entity, d=640): GEMM-ified, P materialized bf16 per bucket
  k_ent_qk<<<dim3(32, 32), 256, 0, stream>>>(proj, labP, qtinfo, Sbuf, rowsum);
  k_ent_pv<<<dim3(5, 32), 256, 0, stream>>>(Sbuf, vT + (size_t)1 * CDIM * S_LEN,
                                            qtinfo, rowsum, planes, attnS);

  // out = attnS @ Wo^T + residual, un-permuted via perm in the epilogue
  k_gemm<1><<<dim3(5, 32), 256, 0, stream>>>(attnS, Wob, S_LEN, CDIM, CDIM, CDIM,
                                             perm, nullptr, (float*)d_out, hs);
}

// Round 13
// 346.351 us; speedup vs baseline: 1.5516x; 1.0262x over previous
//
#include <hip/hip_runtime.h>
#include <cstdint>

typedef __attribute__((ext_vector_type(8))) short bf16x8;
typedef __attribute__((ext_vector_type(4))) short bf16x4;
typedef __attribute__((ext_vector_type(4))) float f32x4;

#define S_LEN 4096
#define CDIM  640
#define NPROJ 5760

// K=16 bf16 MFMA (v_mfma_f32_16x16x16_bf16, gfx950-valid per ISA §10).
__device__ __forceinline__ f32x4 mfma16(bf16x4 a, bf16x4 b, f32x4 c){
#if defined(__HIP_DEVICE_COMPILE__) && __HIP_DEVICE_COMPILE__
  return __builtin_amdgcn_mfma_f32_16x16x16bf16_1k(a, b, c, 0, 0, 0);
#else
  (void)a; (void)b;
  return c;
#endif
}

// async global->LDS, 16B per lane; LDS dest must be wave-uniform base + lane*16
__device__ __forceinline__ void gload_lds(const unsigned short* g, unsigned short* l){
#if defined(__HIP_DEVICE_COMPILE__) && __HIP_DEVICE_COMPILE__
  __builtin_amdgcn_global_load_lds((const __attribute__((address_space(1))) unsigned int*)g,
                                   (__attribute__((address_space(3))) unsigned int*)l, 16, 0, 0);
#else
  (void)g; (void)l;
#endif
}

__device__ __forceinline__ unsigned short f2bf(float f){
  union { float f; uint32_t u; } v; v.f = f;
  uint32_t u = v.u;
  return (unsigned short)((u + 0x7fffu + ((u >> 16) & 1u)) >> 16);
}
__device__ __forceinline__ float b2f(unsigned short h){
  union { uint32_t u; float f; } v; v.u = ((uint32_t)h) << 16;
  return v.f;
}

// T1 XCD-chunked remap: HW assigns dispatch index d to XCD d%8 round-robin;
// remap so each XCD executes a CONTIGUOUS chunk of original tile ids
// (L2 reuse of shared operand panels). Requires nwg % 8 == 0 (all our grids).
__device__ __forceinline__ int xcd_chunk(int d, int nwg){
  return (d & 7) * (nwg >> 3) + (d >> 3);
}

// ---------------- R21: fused prologue (was k_labels/k_hist/k_perm/k_tiles).
__global__ __launch_bounds__(1024) void k_prep(const int* __restrict__ mask,
                                               const int* __restrict__ inp,
                                               int* __restrict__ labels,
                                               int* __restrict__ perm,
                                               int* __restrict__ inv,
                                               int* __restrict__ labP,
                                               int4* __restrict__ qtinfo,
                                               float* __restrict__ rowsum){
  __shared__ int h[4], base[5], cnt4[4], nkt[32];
  int t = threadIdx.x;
  if (t < 4){ h[t] = 0; cnt4[t] = 0; }
  __syncthreads();
  // labels + histogram
  for (int s = t; s < S_LEN; s += 1024){
    int y = s >> 6, x = s & 63;
    int off = (y * 8) * 512 + x * 8;
    int m = mask[off] & 0xff;
    int o = (inp[off] == 0) ? 0x100 : 0;
    labels[s] = m | o;
    atomicAdd(&h[m & 3], 1);
  }
  __syncthreads();
  if (t == 0){
    int a = 0;
    for (int c = 0; c < 4; c++){ base[c] = a; a += h[c]; }
    base[4] = a;
  }
  __syncthreads();
  // bucket-sort permutation (arrival order within bucket, same as before)
  for (int s = t; s < S_LEN; s += 1024){
    int lab = labels[s];
    int c = lab & 3;
    int pos = base[c] + atomicAdd(&cnt4[c], 1);
    perm[pos] = s; inv[s] = pos; labP[pos] = lab;
  }
  __syncthreads();   // labP globally visible within block
  // per-128-tile key ranges
  if (t < 32){
    int c0 = labP[t * 128] & 3, c1 = labP[t * 128 + 127] & 3;
    int lo = base[c0] & ~127, hi = (base[c1 + 1] + 127) & ~127;
    qtinfo[t].x = lo; qtinfo[t].y = hi; qtinfo[t].w = 0;
    nkt[t] = (hi - lo) >> 7;
  }
  __syncthreads();
  if (t == 0){
    int a = 0;
    for (int i = 0; i < 32; i++){ qtinfo[i].z = a; a += nkt[i]; }
  }
  for (int s = t; s < S_LEN; s += 1024) rowsum[s] = 0.f;
}

// ---------------- f32 -> bf16 converts
__global__ void k_cvt_hs(const float* __restrict__ src, unsigned short* __restrict__ dst, int n){
  int idx = (blockIdx.x * 256 + threadIdx.x) * 4;
  if (idx >= n) return;
  float4 v = *(const float4*)(src + idx);
  ushort4 o;
  o.x = f2bf(v.x); o.y = f2bf(v.y); o.z = f2bf(v.z); o.w = f2bf(v.w);
  *(ushort4*)(dst + idx) = o;
}

struct WPtrs { const float* w[10]; };

__global__ void k_cvt_w(WPtrs p, unsigned short* __restrict__ dst){
  int e = (blockIdx.x * 256 + threadIdx.x) * 4;
  if (e >= 10 * 409600) return;
  int a = e / 409600, r = e % 409600;
  float sc = (a == 0 || a == 6) ? 0.11180339887498948f   // 1/sqrt(80)
           : (a == 3 ? 0.03952847075210474f : 1.0f);     // 1/sqrt(640)
  float4 v = *(const float4*)(p.w[a] + r);
  ushort4 o;
  o.x = f2bf(v.x * sc); o.y = f2bf(v.y * sc); o.z = f2bf(v.z * sc); o.w = f2bf(v.w * sc);
  *(ushort4*)(dst + e) = o;
}

// ---------------- 128x128 MFMA GEMM
// BK=64, pitch-64 LDS, gload_lds staging. R22: T1 XCD-chunked tile remap --
// consecutive tiles (sharing the A row-panel) land on the same XCD's L2.
template<int EPI>
__global__ __launch_bounds__(256) void k_gemm(const unsigned short* __restrict__ A,
                                              const unsigned short* __restrict__ B,
                                              int M, int N, int K, int ldc,
                                              const int* __restrict__ rowmap,
                                              unsigned short* __restrict__ Cb,
                                              float* __restrict__ Cf,
                                              const float* __restrict__ resid){
  __shared__ __align__(16) unsigned short As[128 * 64];
  __shared__ __align__(16) unsigned short Bs[128 * 64];
  int d = blockIdx.y * gridDim.x + blockIdx.x;
  int o = xcd_chunk(d, gridDim.x * gridDim.y);
  int m0 = (o / gridDim.x) * 128, n0 = (o % gridDim.x) * 128;
  int tid = threadIdx.x;
  int wid = tid >> 6, lane = tid & 63;
  int quad = lane >> 4, l16 = lane & 15;
  int wm = (wid >> 1) * 64, wn = (wid & 1) * 64;
  f32x4 acc[4][4];
#pragma unroll
  for (int i = 0; i < 4; i++)
#pragma unroll
    for (int j = 0; j < 4; j++) acc[i][j] = f32x4{0.f, 0.f, 0.f, 0.f};

  for (int k0 = 0; k0 < K; k0 += 64){
    __syncthreads();
#pragma unroll
    for (int u = 0; u < 4; u++){
      int c = tid + u * 256;
      int row = c >> 3, off = (c & 7) * 8;
      gload_lds(&A[(size_t)(m0 + row) * K + k0 + off], &As[c * 8]);
      gload_lds(&B[(size_t)(n0 + row) * K + k0 + off], &Bs[c * 8]);
    }
    __syncthreads();
#pragma unroll
    for (int ks = 0; ks < 2; ks++){
      bf16x8 af[4], bfr[4];
#pragma unroll
      for (int t = 0; t < 4; t++){
        af[t]  = *(const bf16x8*)(&As[(wm + t * 16 + l16) * 64 + ks * 32 + quad * 8]);
        bfr[t] = *(const bf16x8*)(&Bs[(wn + t * 16 + l16) * 64 + ks * 32 + quad * 8]);
      }
#pragma unroll
      for (int mt = 0; mt < 4; mt++)
#pragma unroll
        for (int nt = 0; nt < 4; nt++)
          acc[mt][nt] = __builtin_amdgcn_mfma_f32_16x16x32_bf16(af[mt], bfr[nt], acc[mt][nt], 0, 0, 0);
    }
  }
#pragma unroll
  for (int mt = 0; mt < 4; mt++)
#pragma unroll
    for (int nt = 0; nt < 4; nt++)
#pragma unroll
      for (int r = 0; r < 4; r++){
        int row = m0 + wm + mt * 16 + quad * 4 + r;
        int col = n0 + wn + nt * 16 + l16;
        float v = acc[mt][nt][r];
        if (EPI == 0){
          Cb[(size_t)rowmap[row] * ldc + col] = f2bf(v);
        } else {
          int ro = rowmap[row];
          Cf[(size_t)ro * ldc + col] = v + resid[(size_t)ro * ldc + col];
        }
      }
}

// ---------------- transpose the three V projections: vT[z][c][s]
// uint2-vectorized both sides (R21). Streaming, no inter-block reuse -> no swizzle.
__global__ void k_transpose_v(const unsigned short* __restrict__ proj, unsigned short* __restrict__ vT){
  __shared__ unsigned short T[64][68];
  int z = blockIdx.z;
  int s0 = blockIdx.x * 64, c0 = blockIdx.y * 64;
  int colbase = 1280 + z * 1920 + c0;   // v:1280  v_e:3200  v_o:5120
  unsigned short* dst = vT + (size_t)z * CDIM * S_LEN;
  int tid = threadIdx.x;
#pragma unroll
  for (int u = 0; u < 4; u++){
    int i = tid + u * 256;               // 1024 uint2 units: r = i>>4, c4 = (i&15)*4
    int r = i >> 4, c4 = (i & 15) * 4;
    uint2 v = *(const uint2*)&proj[(size_t)(s0 + r) * NPROJ + colbase + c4];
    *(uint2*)&T[r][c4] = v;
  }
  __syncthreads();
#pragma unroll
  for (int u = 0; u < 4; u++){
    int j = tid + u * 256;               // c = j>>4, r4 = (j&15)*4
    int c = j >> 4, r4 = (j & 15) * 4;
    ushort4 o;
    o.x = T[r4 + 0][c]; o.y = T[r4 + 1][c];
    o.z = T[r4 + 2][c]; o.w = T[r4 + 3][c];
    *(ushort4*)&dst[(size_t)(c0 + c) * S_LEN + s0 + r4] = o;
  }
}

// ---------------- flash attention, d=80, z=0: orig, z=1: outside
// R23: + T1 XCD-chunked remap of the flattened 768-block grid -- each XCD gets
// ~96 consecutive blocks (~2 heads' K/V panels, ~2.6 MB < 4 MB L2), converting
// HBM-latency staging misses into L2 hits for this latency-bound kernel.
// Otherwise R20 config: 3-way key split, 256-query 8-wave blocks.
#define KP 84
#define VP 76
__global__ __launch_bounds__(512, 2) void k_attn80(const unsigned short* __restrict__ proj,
                                                   const unsigned short* __restrict__ vT,
                                                   const int* __restrict__ labP,
                                                   const int4* __restrict__ qtinfo,
                                                   unsigned short* __restrict__ opart,
                                                   float* __restrict__ lpP){
  __shared__ __align__(16) unsigned short Ks[2][64 * KP];
  __shared__ __align__(16) unsigned short Vt[2][80 * VP];
  __shared__ __align__(16) int labk[2][64];
  int tid = threadIdx.x, wid = tid >> 6, lane = tid & 63;
  int quad = lane >> 4, l16 = lane & 15;
  // T1 remap over the flattened grid (x fastest in dispatch order)
  int d = (int)(blockIdx.z * gridDim.y + blockIdx.y) * gridDim.x + blockIdx.x;
  int og = xcd_chunk(d, (int)(gridDim.x * gridDim.y * gridDim.z));
  int bx = og % gridDim.x;
  int by = (og / gridDim.x) % gridDim.y;
  int bz = og / (gridDim.x * gridDim.y);
  int qt = bx / 3, third = bx % 3;
  int q0 = qt * 256;
  int h  = by;
  bool OUTSIDE = (bz == 1);
  int qc = (OUTSIDE ? 3840 : 0) + h * 80;
  int kc = (OUTSIDE ? 4480 : 640) + h * 80;
  const unsigned short* vTb = vT + (size_t)(OUTSIDE ? 2 : 0) * CDIM * S_LEN;
  int4 qa = qtinfo[qt * 2], qb = qtinfo[qt * 2 + 1];
  int lo = min(qa.x, qb.x), hi = max(qa.y, qb.y);
  int t0 = lo >> 6, t1 = hi >> 6;
  int nt = t1 - t0;
  int ta = t0 + (nt * third) / 3;
  int tb = t0 + (nt * (third + 1)) / 3;

  // two query sets per wave (B-operand layout: lane n=l16 is the query, k=quad*4+j)
  int qrow0 = q0 + wid * 32 + l16;
  int qrow1 = qrow0 + 16;
  bf16x4 qf0[5], qf1[5];
#pragma unroll
  for (int dc = 0; dc < 5; dc++){
    qf0[dc] = *(const bf16x4*)&proj[(size_t)qrow0 * NPROJ + qc + dc * 16 + quad * 4];
    qf1[dc] = *(const bf16x4*)&proj[(size_t)qrow1 * NPROJ + qc + dc * 16 + quad * 4];
  }
  int lq0 = labP[qrow0] & 0xff, lq1 = labP[qrow1] & 0xff;

  float lp0 = 0.f, lp1 = 0.f;
  f32x4 Oc0[5], Oc1[5];
#pragma unroll
  for (int t = 0; t < 5; t++){ Oc0[t] = f32x4{0.f,0.f,0.f,0.f}; Oc1[t] = f32x4{0.f,0.f,0.f,0.f}; }

  // staging roles: waves 0-3 stage the K tile (64 rows x 20 uint2), waves 4-7
  // stage the V tile (80 rows x 16 uint2). 1280 uint2 per role over 256
  // threads = 5 units/thread; unit c = t5 + u*256. All tile-invariant.
  const bool ISK = (tid < 256);
  const int t5 = ISK ? tid : (tid - 256);
  const unsigned short* gb = ISK ? proj : vTb;
  const int km = ISK ? NPROJ : 1;                    // per-tile offset multiplier
  int ga0, ga1, ga2, ga3, ga4, ls0, ls1, ls2, ls3, ls4;
  {
    const int c0_ = t5, c1_ = t5 + 256, c2_ = t5 + 512, c3_ = t5 + 768, c4_ = t5 + 1024;
    if (ISK){
      ga0 = (c0_ / 20) * NPROJ + kc + (c0_ % 20) * 4;
      ga1 = (c1_ / 20) * NPROJ + kc + (c1_ % 20) * 4;
      ga2 = (c2_ / 20) * NPROJ + kc + (c2_ % 20) * 4;
      ga3 = (c3_ / 20) * NPROJ + kc + (c3_ % 20) * 4;
      ga4 = (c4_ / 20) * NPROJ + kc + (c4_ % 20) * 4;
      ls0 = (c0_ / 20) * KP + (c0_ % 20) * 4;
      ls1 = (c1_ / 20) * KP + (c1_ % 20) * 4;
      ls2 = (c2_ / 20) * KP + (c2_ % 20) * 4;
      ls3 = (c3_ / 20) * KP + (c3_ % 20) * 4;
      ls4 = (c4_ / 20) * KP + (c4_ % 20) * 4;
    } else {
      ga0 = (h * 80 + (c0_ >> 4)) * S_LEN + (c0_ & 15) * 4;
      ga1 = (h * 80 + (c1_ >> 4)) * S_LEN + (c1_ & 15) * 4;
      ga2 = (h * 80 + (c2_ >> 4)) * S_LEN + (c2_ & 15) * 4;
      ga3 = (h * 80 + (c3_ >> 4)) * S_LEN + (c3_ & 15) * 4;
      ga4 = (h * 80 + (c4_ >> 4)) * S_LEN + (c4_ & 15) * 4;
      ls0 = (c0_ >> 4) * VP + (c0_ & 15) * 4;
      ls1 = (c1_ >> 4) * VP + (c1_ & 15) * 4;
      ls2 = (c2_ >> 4) * VP + (c2_ & 15) * 4;
      ls3 = (c3_ >> 4) * VP + (c3_ & 15) * 4;
      ls4 = (c4_ >> 4) * VP + (c4_ & 15) * 4;
    }
  }

  uint2 r0, r1, r2, r3, r4;
  int lreg = 0;

#define LOADT(kt_) do {                                              \
    size_t _ob = (size_t)((kt_) * 64) * (size_t)km;                  \
    r0 = *(const uint2*)&gb[_ob + ga0];                              \
    r1 = *(const uint2*)&gb[_ob + ga1];                              \
    r2 = *(const uint2*)&gb[_ob + ga2];                              \
    r3 = *(const uint2*)&gb[_ob + ga3];                              \
    r4 = *(const uint2*)&gb[_ob + ga4];                              \
    if (tid < 64) lreg = labP[(kt_) * 64 + tid];                     \
  } while (0)

#define WRITET(b) do {                                               \
    unsigned short* _lb = ISK ? Ks[b] : Vt[b];                       \
    *(uint2*)&_lb[ls0] = r0;                                         \
    *(uint2*)&_lb[ls1] = r1;                                         \
    *(uint2*)&_lb[ls2] = r2;                                         \
    *(uint2*)&_lb[ls3] = r3;                                         \
    *(uint2*)&_lb[ls4] = r4;                                         \
    if (tid < 64) labk[b][tid] = lreg;                               \
  } while (0)

  if (ta < tb){
    // prologue: stage tile ta into buf0, issue loads for ta+1
    LOADT(ta);
    WRITET(0);
    if (ta + 1 < tb) LOADT(ta + 1);
    __syncthreads();

    int cur = 0;
    for (int kt = ta; kt < tb; kt++){
      int nxt = cur ^ 1;
      // regs hold tile kt+1: write it to the other buffer (its readers finished
      // at the barrier that ended iteration kt-1), then issue loads for kt+2.
      if (kt + 1 < tb){
        WRITET(nxt);
        if (kt + 2 < tb) LOADT(kt + 2);
      }

#pragma unroll
      for (int kg = 0; kg < 4; kg++){
        // S^T(16 keys x 16 queries) = K * Q^T, two query sets share kf
        f32x4 sa0 = f32x4{0.f,0.f,0.f,0.f}, sa1 = f32x4{0.f,0.f,0.f,0.f};
#pragma unroll
        for (int dc = 0; dc < 5; dc++){
          bf16x4 kf = *(const bf16x4*)&Ks[cur][(kg * 16 + l16) * KP + dc * 16 + quad * 4];
          sa0 = mfma16(kf, qf0[dc], sa0);
          sa1 = mfma16(kf, qf1[dc], sa1);
        }
        int4 lk4 = *(const int4*)&labk[cur][kg * 16 + quad * 4];
        bool m0 = !OUTSIDE || (lk4.x & 0x100), m1 = !OUTSIDE || (lk4.y & 0x100);
        bool m2 = !OUTSIDE || (lk4.z & 0x100), m3 = !OUTSIDE || (lk4.w & 0x100);
        int k0l = lk4.x & 0xff, k1l = lk4.y & 0xff, k2l = lk4.z & 0xff, k3l = lk4.w & 0xff;
        bf16x4 pf0, pf1;
        {
          float p0 = (k0l == lq0 && m0) ? __expf(sa0[0]) : 0.f;
          float p1 = (k1l == lq0 && m1) ? __expf(sa0[1]) : 0.f;
          float p2 = (k2l == lq0 && m2) ? __expf(sa0[2]) : 0.f;
          float p3 = (k3l == lq0 && m3) ? __expf(sa0[3]) : 0.f;
          lp0 += (p0 + p1) + (p2 + p3);
          pf0[0] = (short)f2bf(p0); pf0[1] = (short)f2bf(p1);
          pf0[2] = (short)f2bf(p2); pf0[3] = (short)f2bf(p3);
        }
        {
          float p0 = (k0l == lq1 && m0) ? __expf(sa1[0]) : 0.f;
          float p1 = (k1l == lq1 && m1) ? __expf(sa1[1]) : 0.f;
          float p2 = (k2l == lq1 && m2) ? __expf(sa1[2]) : 0.f;
          float p3 = (k3l == lq1 && m3) ? __expf(sa1[3]) : 0.f;
          lp1 += (p0 + p1) + (p2 + p3);
          pf1[0] = (short)f2bf(p0); pf1[1] = (short)f2bf(p1);
          pf1[2] = (short)f2bf(p2); pf1[3] = (short)f2bf(p3);
        }
        // O^T += V^T * P^T, two query sets share vf
#pragma unroll
        for (int dt = 0; dt < 5; dt++){
          bf16x4 vf = *(const bf16x4*)&Vt[cur][(dt * 16 + l16) * VP + kg * 16 + quad * 4];
          Oc0[dt] = mfma16(vf, pf0, Oc0[dt]);
          Oc1[dt] = mfma16(vf, pf1, Oc1[dt]);
        }
      }
      __syncthreads();   // all reads of cur done; writes of nxt visible
      cur = nxt;
    }
  }
#undef LOADT
#undef WRITET
  // row-sums: reduce across quads (same l16); write UNNORMALIZED partials
  lp0 += __shfl_xor(lp0, 16); lp0 += __shfl_xor(lp0, 32);
  lp1 += __shfl_xor(lp1, 16); lp1 += __shfl_xor(lp1, 32);
  int hz = third * 2 + bz;
  if (quad == 0){
    lpP[(size_t)(hz * 8 + h) * S_LEN + qrow0] = lp0;
    lpP[(size_t)(hz * 8 + h) * S_LEN + qrow1] = lp1;
  }
  unsigned short* dst = opart + (size_t)hz * S_LEN * CDIM;
#pragma unroll
  for (int dt = 0; dt < 5; dt++){
    ushort4 o;
    o.x = f2bf(Oc0[dt][0]); o.y = f2bf(Oc0[dt][1]);
    o.z = f2bf(Oc0[dt][2]); o.w = f2bf(Oc0[dt][3]);
    *(ushort4*)&dst[(size_t)qrow0 * CDIM + h * 80 + dt * 16 + quad * 4] = o;
    o.x = f2bf(Oc1[dt][0]); o.y = f2bf(Oc1[dt][1]);
    o.z = f2bf(Oc1[dt][2]); o.w = f2bf(Oc1[dt][3]);
    *(ushort4*)&dst[(size_t)qrow1 * CDIM + h * 80 + dt * 16 + quad * 4] = o;
  }
}

// ---------------- combine: planes[z] = sum of 3 partial O / sum of 3 partial lp
__global__ __launch_bounds__(256) void k_comb(const unsigned short* __restrict__ opart,
                                              const float* __restrict__ lpP,
                                              unsigned short* __restrict__ planes){
  int i = blockIdx.x * 256 + threadIdx.x;          // 4096*160 items per z
  int z = blockIdx.y;
  int qrow = i / 160, c4 = (i % 160) * 4;
  int h = c4 / 80;                                  // 80 % 4 == 0: one h per ushort4
  size_t base = (size_t)qrow * CDIM + c4;
  size_t pz = (size_t)S_LEN * CDIM;
  float lp = lpP[(size_t)((z)     * 8 + h) * S_LEN + qrow]
           + lpP[(size_t)((z + 2) * 8 + h) * S_LEN + qrow]
           + lpP[(size_t)((z + 4) * 8 + h) * S_LEN + qrow];
  float iL = 1.f / lp;
  ushort4 a = *(const ushort4*)&opart[(size_t)(z)     * pz + base];
  ushort4 b = *(const ushort4*)&opart[(size_t)(z + 2) * pz + base];
  ushort4 c = *(const ushort4*)&opart[(size_t)(z + 4) * pz + base];
  ushort4 o;
  o.x = f2bf((b2f(a.x) + b2f(b.x) + b2f(c.x)) * iL);
  o.y = f2bf((b2f(a.y) + b2f(b.y) + b2f(c.y)) * iL);
  o.z = f2bf((b2f(a.z) + b2f(b.z) + b2f(c.z)) * iL);
  o.w = f2bf((b2f(a.w) + b2f(b.w) + b2f(c.w)) * iL);
  *(ushort4*)&planes[(size_t)z * pz + base] = o;
}

// ---------------- entity E1: P = exp(Q_e K_e^T) per (qtile, ktile), bf16, + rowsums
// BK=64 staging; T1 XCD-chunked remap (consecutive k-tiles of one qt share
// the Q_e panel -> same XCD L2).
__global__ __launch_bounds__(256) void k_ent_qk(const unsigned short* __restrict__ proj,
                                                const int* __restrict__ labP,
                                                const int4* __restrict__ qtinfo,
                                                unsigned short* __restrict__ Sbuf,
                                                float* __restrict__ rowsum){
  int d = blockIdx.y * gridDim.x + blockIdx.x;
  int o = xcd_chunk(d, gridDim.x * gridDim.y);
  int ktb = o % gridDim.x, qt = o / gridDim.x;
  int4 qi = qtinfo[qt];
  int nkt = (qi.y - qi.x) >> 7;
  if (ktb >= nkt) return;
  int m0 = qt * 128, n0 = qi.x + ktb * 128;
  __shared__ __align__(16) unsigned short As[128 * 64];
  __shared__ __align__(16) unsigned short Bs[128 * 64];
  __shared__ int lQ[128], lK[128];
  int tid = threadIdx.x, wid = tid >> 6, lane = tid & 63;
  int quad = lane >> 4, l16 = lane & 15;
  int wm = (wid >> 1) * 64, wn = (wid & 1) * 64;
  if (tid < 128) lQ[tid] = labP[m0 + tid] & 0xff;
  else           lK[tid - 128] = labP[n0 + tid - 128] & 0xff;
  f32x4 acc[4][4];
#pragma unroll
  for (int i = 0; i < 4; i++)
#pragma unroll
    for (int j = 0; j < 4; j++) acc[i][j] = f32x4{0.f, 0.f, 0.f, 0.f};

  for (int k0 = 0; k0 < 640; k0 += 64){
    __syncthreads();
#pragma unroll
    for (int u = 0; u < 4; u++){
      int c = tid + u * 256;
      int row = c >> 3, off = (c & 7) * 8;
      gload_lds(&proj[(size_t)(m0 + row) * NPROJ + 1920 + k0 + off], &As[c * 8]);
      gload_lds(&proj[(size_t)(n0 + row) * NPROJ + 2560 + k0 + off], &Bs[c * 8]);
    }
    __syncthreads();
#pragma unroll
    for (int ks = 0; ks < 2; ks++){
      bf16x8 af[4], bfr[4];
#pragma unroll
      for (int t = 0; t < 4; t++){
        af[t]  = *(const bf16x8*)(&As[(wm + t * 16 + l16) * 64 + ks * 32 + quad * 8]);
        bfr[t] = *(const bf16x8*)(&Bs[(wn + t * 16 + l16) * 64 + ks * 32 + quad * 8]);
      }
#pragma unroll
      for (int mt = 0; mt < 4; mt++)
#pragma unroll
        for (int nt = 0; nt < 4; nt++)
          acc[mt][nt] = __builtin_amdgcn_mfma_f32_16x16x32_bf16(af[mt], bfr[nt], acc[mt][nt], 0, 0, 0);
    }
  }
  unsigned short* St = Sbuf + ((size_t)(qi.z + ktb)) * 16384;
#pragma unroll
  for (int mt = 0; mt < 4; mt++)
#pragma unroll
    for (int r = 0; r < 4; r++){
      int lrow = wm + mt * 16 + quad * 4 + r;
      int myq = lQ[lrow];
      float psum = 0.f;
#pragma unroll
      for (int nt = 0; nt < 4; nt++){
        int lcol = wn + nt * 16 + l16;
        float p = (myq == lK[lcol]) ? __expf(acc[mt][nt][r]) : 0.f;
        St[lrow * 128 + lcol] = f2bf(p);
        psum += p;
      }
#pragma unroll
      for (int m = 1; m < 16; m <<= 1) psum += __shfl_xor(psum, m);
      if (l16 == 0) atomicAdd(&rowsum[m0 + lrow], psum);
    }
}

// ---------------- entity E2: attnS = bf16( P·V_e / rowsum + plane0 + plane1 )
// BK=64; T1 XCD-chunked remap (the 5 d-blocks of one qt share its P buffer).
__global__ __launch_bounds__(256) void k_ent_pv(const unsigned short* __restrict__ Sbuf,
                                                const unsigned short* __restrict__ veT,
                                                const int4* __restrict__ qtinfo,
                                                const float* __restrict__ rowsum,
                                                const unsigned short* __restrict__ planes,
                                                unsigned short* __restrict__ attnS){
  int d = blockIdx.y * gridDim.x + blockIdx.x;
  int o = xcd_chunk(d, gridDim.x * gridDim.y);
  int qt = o / gridDim.x, d0 = (o % gridDim.x) * 128;
  int4 qi = qtinfo[qt];
  int m0 = qt * 128;
  int nk = qi.y - qi.x;
  __shared__ __align__(16) unsigned short As[128 * 64];
  __shared__ __align__(16) unsigned short Bs[128 * 64];
  int tid = threadIdx.x, wid = tid >> 6, lane = tid & 63;
  int quad = lane >> 4, l16 = lane & 15;
  int wm = (wid >> 1) * 64, wn = (wid & 1) * 64;
  f32x4 acc[4][4];
#pragma unroll
  for (int i = 0; i < 4; i++)
#pragma unroll
    for (int j = 0; j < 4; j++) acc[i][j] = f32x4{0.f, 0.f, 0.f, 0.f};

  for (int kk = 0; kk < nk; kk += 64){
    const unsigned short* St = Sbuf + ((size_t)(qi.z + (kk >> 7))) * 16384;
    int kloc = kk & 127;
    __syncthreads();
#pragma unroll
    for (int u = 0; u < 4; u++){
      int c = tid + u * 256;
      int row = c >> 3, off = (c & 7) * 8;
      gload_lds(&St[row * 128 + kloc + off], &As[c * 8]);
      gload_lds(&veT[(size_t)(d0 + row) * S_LEN + qi.x + kk + off], &Bs[c * 8]);
    }
    __syncthreads();
#pragma unroll
    for (int ks = 0; ks < 2; ks++){
      bf16x8 af[4], bfr[4];
#pragma unroll
      for (int t = 0; t < 4; t++){
        af[t]  = *(const bf16x8*)(&As[(wm + t * 16 + l16) * 64 + ks * 32 + quad * 8]);
        bfr[t] = *(const bf16x8*)(&Bs[(wn + t * 16 + l16) * 64 + ks * 32 + quad * 8]);
      }
#pragma unroll
      for (int mt = 0; mt < 4; mt++)
#pragma unroll
        for (int nt = 0; nt < 4; nt++)
          acc[mt][nt] = __builtin_amdgcn_mfma_f32_16x16x32_bf16(af[mt], bfr[nt], acc[mt][nt], 0, 0, 0);
    }
  }
#pragma unroll
  for (int mt = 0; mt < 4; mt++)
#pragma unroll
    for (int r = 0; r < 4; r++){
      int row = m0 + wm + mt * 16 + quad * 4 + r;
      float invL = 1.f / rowsum[row];
#pragma unroll
      for (int nt = 0; nt < 4; nt++){
        int col = d0 + wn + nt * 16 + l16;
        size_t idx = (size_t)row * CDIM + col;
        float v = acc[mt][nt][r] * invL + b2f(planes[idx]) + b2f(planes[(size_t)S_LEN * CDIM + idx]);
        attnS[idx] = f2bf(v);
      }
    }
}

extern "C" void kernel_launch(void* const* d_in, const int* in_sizes, int n_in,
                              void* d_out, int out_size, void* d_ws, size_t ws_size,
                              hipStream_t stream){
  const float* hs  = (const float*)d_in[0];
  const int* mask  = (const int*)d_in[1];
  const int* inp   = (const int*)d_in[2];
  char* ws = (char*)d_ws;
  int*            labels  = (int*)(ws + 0);
  int*            perm    = (int*)(ws + 16896);
  int*            inv     = (int*)(ws + 33280);
  int*            labP    = (int*)(ws + 49664);
  int4*           qtinfo  = (int4*)(ws + 66560);
  float*          rowsum  = (float*)(ws + 67072);
  unsigned short* hsb     = (unsigned short*)(ws + 131072);
  unsigned short* Wall    = (unsigned short*)(ws + 5373952);
  unsigned short* proj    = (unsigned short*)(ws + 13565952);
  unsigned short* vT      = (unsigned short*)(ws + 60751872);
  unsigned short* planes  = (unsigned short*)(ws + 76480512);   // 2 bf16 planes = 10.5 MB
  unsigned short* Sbuf    = (unsigned short*)(ws + 86966272);   // up to 1024 tiles * 32 KB
  unsigned short* attnS   = (unsigned short*)(ws + 120520704);
  unsigned short* Wob     = Wall + 9 * 409600;
  // attn partials live in the Sbuf region (consumed by k_comb BEFORE k_ent_qk
  // overwrites Sbuf): opart = 6 x [4096][640] bf16 (31.5 MB), lpP = 6x8x4096 f32.
  unsigned short* opart   = Sbuf;
  float*          lpP     = (float*)(ws + 86966272 + 31457280);

  k_prep<<<1, 1024, 0, stream>>>(mask, inp, labels, perm, inv, labP, qtinfo, rowsum);
  k_cvt_hs<<<(S_LEN * CDIM / 4 + 255) / 256, 256, 0, stream>>>(hs, hsb, S_LEN * CDIM);
  WPtrs wp;
  for (int i = 0; i < 10; i++) wp.w[i] = (const float*)d_in[3 + i];
  k_cvt_w<<<(10 * 409600 / 4 + 255) / 256, 256, 0, stream>>>(wp, Wall);

  // all 9 projections in one GEMM, rows scattered into bucket-permuted order
  k_gemm<0><<<dim3(45, 32), 256, 0, stream>>>(hsb, Wall, S_LEN, NPROJ, CDIM, NPROJ,
                                              inv, proj, nullptr, nullptr);
  k_transpose_v<<<dim3(64, 10, 3), 256, 0, stream>>>(proj, vT);

  // branches 1+3: 256-query 8-wave blocks + 3-way key split; partials + combine
  k_attn80<<<dim3(48, 8, 2), 512, 0, stream>>>(proj, vT, labP, qtinfo, opart, lpP);
  k_comb<<<dim3(2560, 2), 256, 0, stream>>>(opart, lpP, planes);

  // branch 2 (entity, d=640): GEMM-ified, P materialized bf16 per bucket
  k_ent_qk<<<dim3(32, 32), 256, 0, stream>>>(proj, labP, qtinfo, Sbuf, rowsum);
  k_ent_pv<<<dim3(5, 32), 256, 0, stream>>>(Sbuf, vT + (size_t)1 * CDIM * S_LEN,
                                            qtinfo, rowsum, planes, attnS);

  // out = attnS @ Wo^T + residual, un-permuted via perm in the epilogue
  k_gemm<1><<<dim3(5, 32), 256, 0, stream>>>(attnS, Wob, S_LEN, CDIM, CDIM, CDIM,
                                             perm, nullptr, (float*)d_out, hs);
}